// Round 1
// baseline (1421.882 us; speedup 1.0000x reference)
//
#include <hip/hip_runtime.h>
#include <math.h>

typedef __bf16 bf16x8 __attribute__((ext_vector_type(8)));
typedef __bf16 bf16x4 __attribute__((ext_vector_type(4)));
typedef float f32x4 __attribute__((ext_vector_type(4)));

__device__ __forceinline__ void gload_lds16(const __bf16* g, __bf16* l) {
  __builtin_amdgcn_global_load_lds((const __attribute__((address_space(1))) void*)g,
                                   (__attribute__((address_space(3))) void*)l, 16, 0, 0);
}

__device__ __forceinline__ float gelu_exact(float v) {
  return 0.5f * v * (1.f + erff(v * 0.70710678118654752f));
}

// ---------------- f32 -> bf16 convert ----------------
__global__ __launch_bounds__(256) void cvt_kernel(const float* __restrict__ in,
                                                  __bf16* __restrict__ out, int n) {
  const int stride = gridDim.x * 256 * 4;
  for (int i = (blockIdx.x * 256 + threadIdx.x) * 4; i < n; i += stride) {
    float4 v = *(const float4*)(in + i);
    bf16x4 o = {(__bf16)v.x, (__bf16)v.y, (__bf16)v.z, (__bf16)v.w};
    *(bf16x4*)(out + i) = o;
  }
}

// ---------------- f32 [R][C] -> bf16 [C][R] transpose-convert ----------------
__global__ __launch_bounds__(256) void tcvt_kernel(const float* __restrict__ in,
                                                   __bf16* __restrict__ out, int R, int C) {
  __shared__ float t[32][33];
  const int c0 = blockIdx.x * 32, r0 = blockIdx.y * 32;
  for (int yy = threadIdx.y; yy < 32; yy += 8)
    t[yy][threadIdx.x] = in[(size_t)(r0 + yy) * C + c0 + threadIdx.x];
  __syncthreads();
  for (int yy = threadIdx.y; yy < 32; yy += 8)
    out[(size_t)(c0 + yy) * R + r0 + threadIdx.x] = (__bf16)t[threadIdx.x][yy];
}

// ---------------- bf16 MFMA GEMM: C[M,N] = A[M,K] * BT[N,K]^T ----------------
// MODE 0: f32 C.  MODE 1: bf16 C = gelu(acc + bias[col]).
template<int BM, int BN, int MODE>
__global__ __launch_bounds__(256)
void gemm_bt(const __bf16* __restrict__ A, const __bf16* __restrict__ BT,
             float* __restrict__ Cf, __bf16* __restrict__ Cb,
             const float* __restrict__ bias, int M, int N, int K) {
  constexpr int BK = 32;
  constexpr int ALOAD = (BM * BK) / 2048;
  constexpr int BLOAD = (BN * BK) / 2048;
  __shared__ __align__(16) __bf16 lA[BM * BK];
  __shared__ __align__(16) __bf16 lB[BN * BK];
  const int tid = threadIdx.x;
  const int w = tid >> 6, l = tid & 63;
  const int lr = l & 15, lk = l >> 4;
  const int mBase = blockIdx.y * BM, nBase = blockIdx.x * BN;
  constexpr int WM = BM / 2, WN = BN / 2;
  constexpr int MF = WM / 16, NF = WN / 16;
  const int wr = w >> 1, wc = w & 1;
  f32x4 acc[MF][NF] = {};
  const int srow = tid >> 2;
  const int scol = (tid & 3) * 8;

  for (int k0 = 0; k0 < K; k0 += BK) {
#pragma unroll
    for (int i = 0; i < ALOAD; ++i) {
      int grow = mBase + srow + i * 64;
      grow = grow < M ? grow : M - 1;
      gload_lds16(A + (size_t)grow * K + k0 + scol, lA + i * 2048 + w * 512);
    }
#pragma unroll
    for (int i = 0; i < BLOAD; ++i) {
      int grow = nBase + srow + i * 64;
      gload_lds16(BT + (size_t)grow * K + k0 + scol, lB + i * 2048 + w * 512);
    }
    __syncthreads();
    bf16x8 af[MF], bfr[NF];
#pragma unroll
    for (int mi = 0; mi < MF; ++mi)
      af[mi] = *(const bf16x8*)&lA[(wr * WM + mi * 16 + lr) * BK + lk * 8];
#pragma unroll
    for (int nj = 0; nj < NF; ++nj)
      bfr[nj] = *(const bf16x8*)&lB[(wc * WN + nj * 16 + lr) * BK + lk * 8];
#pragma unroll
    for (int mi = 0; mi < MF; ++mi)
#pragma unroll
      for (int nj = 0; nj < NF; ++nj)
        acc[mi][nj] = __builtin_amdgcn_mfma_f32_16x16x32_bf16(af[mi], bfr[nj], acc[mi][nj], 0, 0, 0);
    __syncthreads();
  }
#pragma unroll
  for (int mi = 0; mi < MF; ++mi) {
#pragma unroll
    for (int nj = 0; nj < NF; ++nj) {
      const int col = nBase + wc * WN + nj * 16 + lr;
      const int row0 = mBase + wr * WM + mi * 16 + lk * 4;
#pragma unroll
      for (int j = 0; j < 4; ++j) {
        const int row = row0 + j;
        if (row < M) {
          float v = acc[mi][nj][j];
          if constexpr (MODE == 1) {
            v = gelu_exact(v + bias[col]);
            Cb[(size_t)row * N + col] = (__bf16)v;
          } else {
            Cf[(size_t)row * N + col] = v;
          }
        }
      }
    }
  }
}

// ---------------- fused rel-pos attention (vector f32) ----------------
// qkv: [4096][3072] (q|k|v), kpos: [4100][1024], out av: bf16 [4096][1024]
// scores[i][j] = scale*( q[i].k[j] + rwb.k[j] + q[i'].kpos[idx] + rrb.kpos[idx] )
//   r = j - i ; idx = (r<=0) ? 1024+r : r-1 ; i' = i + (r>0)
__global__ __launch_bounds__(256)
void attn_fused(const float* __restrict__ qkv, const float* __restrict__ kpos,
                const float* __restrict__ rwbias, const float* __restrict__ rrbias,
                __bf16* __restrict__ av) {
  constexpr int TI = 32, TJ = 64, NR = TJ + TI - 1;  // 95 kpos band rows
  const int it = blockIdx.x, n = blockIdx.y, b = blockIdx.z;
  const int i0 = it * TI;
  const int tid = threadIdx.x;
  const int il = tid >> 3, q8 = tid & 7;

  __shared__ float Q[TI + 1][68];
  __shared__ float KT[TJ][68];
  __shared__ float KP[NR][65];
  __shared__ float P[TI][68];
  __shared__ float kb[TJ];
  __shared__ float kpb[NR + 1];
  __shared__ float rwb[64], rrb[64];

  for (int r = tid >> 3; r < TI + 1; r += 32) {
    int gi = i0 + r; gi = gi < 1024 ? gi : 1023;
    const float* s = qkv + (size_t)(gi * 4 + b) * 3072 + n * 64 + q8 * 8;
    *(float4*)&Q[r][q8 * 8] = *(const float4*)s;
    *(float4*)&Q[r][q8 * 8 + 4] = *(const float4*)(s + 4);
  }
  if (tid < 64) rwb[tid] = rwbias[n * 64 + tid];
  else if (tid < 128) rrb[tid - 64] = rrbias[n * 64 + tid - 64];

  float m = -INFINITY, Z = 0.f;
  float O[8] = {0.f, 0.f, 0.f, 0.f, 0.f, 0.f, 0.f, 0.f};

  for (int jt = 0; jt < 16; ++jt) {
    const int j0 = jt * 64;
    const int d0 = j0 - i0;
    __syncthreads();
    {
      const int r = tid >> 2, c = (tid & 3) * 16;
      const float* s = qkv + (size_t)((j0 + r) * 4 + b) * 3072 + 1024 + n * 64 + c;
#pragma unroll
      for (int u = 0; u < 4; ++u)
        *(float4*)&KT[r][c + u * 4] = *(const float4*)(s + u * 4);
    }
    for (int rr = tid >> 2; rr < NR; rr += 64) {
      const int rrel = rr - 31 + d0;
      const int idx = (rrel <= 0) ? (1024 + rrel) : (rrel - 1);
      const int c = (tid & 3) * 16;
      const float* s = kpos + (size_t)(idx * 4 + b) * 1024 + n * 64 + c;
#pragma unroll
      for (int u = 0; u < 4; ++u)
        *(float4*)&KP[rr][c + u * 4] = *(const float4*)(s + u * 4);
    }
    __syncthreads();
    if (tid < TJ) {
      float s = 0.f;
#pragma unroll 16
      for (int d = 0; d < 64; ++d) s += rwb[d] * KT[tid][d];
      kb[tid] = s;
    } else if (tid < TJ + NR) {
      const int rr = tid - TJ;
      float s = 0.f;
#pragma unroll 16
      for (int d = 0; d < 64; ++d) s += rrb[d] * KP[rr][d];
      kpb[rr] = s;
    }
    __syncthreads();

    float sc[8];
    bool hi[8];
#pragma unroll
    for (int si = 0; si < 8; ++si) {
      const int jl = si * 8 + q8;
      sc[si] = kb[jl] + kpb[jl - il + 31];
      hi[si] = (d0 + jl - il) > 0;
    }
    for (int dc = 0; dc < 64; dc += 4) {
      const float4 qa = *(const float4*)&Q[il][dc];
      const float4 qb = *(const float4*)&Q[il + 1][dc];
#pragma unroll
      for (int si = 0; si < 8; ++si) {
        const int jl = si * 8 + q8;
        const float4 kt = *(const float4*)&KT[jl][dc];
        const float* kp = &KP[jl - il + 31][dc];
        const float qx0 = hi[si] ? qb.x : qa.x;
        const float qx1 = hi[si] ? qb.y : qa.y;
        const float qx2 = hi[si] ? qb.z : qa.z;
        const float qx3 = hi[si] ? qb.w : qa.w;
        sc[si] += qa.x * kt.x + qa.y * kt.y + qa.z * kt.z + qa.w * kt.w
                + qx0 * kp[0] + qx1 * kp[1] + qx2 * kp[2] + qx3 * kp[3];
      }
    }
    float tmax = -INFINITY;
#pragma unroll
    for (int si = 0; si < 8; ++si) { sc[si] *= 0.125f; tmax = fmaxf(tmax, sc[si]); }
#pragma unroll
    for (int o = 1; o <= 4; o <<= 1) tmax = fmaxf(tmax, __shfl_xor(tmax, o, 64));
    const float nm = fmaxf(m, tmax);
    const float al = __expf(m - nm);
    float zl = 0.f;
    float ps[8];
#pragma unroll
    for (int si = 0; si < 8; ++si) { ps[si] = __expf(sc[si] - nm); zl += ps[si]; }
#pragma unroll
    for (int o = 1; o <= 4; o <<= 1) zl += __shfl_xor(zl, o, 64);
    Z = Z * al + zl;
    m = nm;
#pragma unroll
    for (int si = 0; si < 8; ++si) P[il][si * 8 + q8] = ps[si];
#pragma unroll
    for (int k = 0; k < 8; ++k) O[k] *= al;
    __syncthreads();
    for (int jl = 0; jl < 64; jl += 4) {
      const float4 p4 = *(const float4*)&P[il][jl];
#pragma unroll
      for (int u = 0; u < 4; ++u) {
        const float p = (u == 0) ? p4.x : (u == 1) ? p4.y : (u == 2) ? p4.z : p4.w;
        const float* vs = qkv + (size_t)((j0 + jl + u) * 4 + b) * 3072 + 2048 + n * 64 + q8 * 8;
        const float4 v0 = *(const float4*)vs;
        const float4 v1 = *(const float4*)(vs + 4);
        O[0] += p * v0.x; O[1] += p * v0.y; O[2] += p * v0.z; O[3] += p * v0.w;
        O[4] += p * v1.x; O[5] += p * v1.y; O[6] += p * v1.z; O[7] += p * v1.w;
      }
    }
  }
  const float rz = 1.f / Z;
  bf16x8 o;
#pragma unroll
  for (int k = 0; k < 8; ++k) o[k] = (__bf16)(O[k] * rz);
  *(bf16x8*)&av[(size_t)((i0 + il) * 4 + b) * 1024 + n * 64 + q8 * 8] = o;
}

// ---------------- fused residual + LayerNorm ----------------
// y = LN(A + Bv [+ cb]) * g + be ; writes f32 (oF) and optional bf16 (oB)
__global__ __launch_bounds__(256)
void ln_fuse(const float* __restrict__ A, const float* __restrict__ Bv,
             const float* __restrict__ cb, const float* __restrict__ g,
             const float* __restrict__ be, float* __restrict__ oF,
             __bf16* __restrict__ oB) {
  const int row = blockIdx.x, t = threadIdx.x;
  const size_t base = (size_t)row * 1024 + t * 4;
  const float4 a = *(const float4*)(A + base);
  const float4 bb = *(const float4*)(Bv + base);
  float x0 = a.x + bb.x, x1 = a.y + bb.y, x2 = a.z + bb.z, x3 = a.w + bb.w;
  if (cb) {
    const float4 c = *(const float4*)(cb + t * 4);
    x0 += c.x; x1 += c.y; x2 += c.z; x3 += c.w;
  }
  float s = x0 + x1 + x2 + x3;
  float q = x0 * x0 + x1 * x1 + x2 * x2 + x3 * x3;
#pragma unroll
  for (int o = 1; o < 64; o <<= 1) { s += __shfl_xor(s, o, 64); q += __shfl_xor(q, o, 64); }
  __shared__ float ss[4], qq[4];
  if ((t & 63) == 0) { ss[t >> 6] = s; qq[t >> 6] = q; }
  __syncthreads();
  s = ss[0] + ss[1] + ss[2] + ss[3];
  q = qq[0] + qq[1] + qq[2] + qq[3];
  const float mean = s * (1.f / 1024.f);
  const float var = q * (1.f / 1024.f) - mean * mean;
  const float rstd = rsqrtf(var + 1e-5f);
  const float4 gv = *(const float4*)(g + t * 4);
  const float4 bev = *(const float4*)(be + t * 4);
  const float y0 = (x0 - mean) * rstd * gv.x + bev.x;
  const float y1 = (x1 - mean) * rstd * gv.y + bev.y;
  const float y2 = (x2 - mean) * rstd * gv.z + bev.z;
  const float y3 = (x3 - mean) * rstd * gv.w + bev.w;
  float4 r = {y0, y1, y2, y3};
  *(float4*)(oF + base) = r;
  if (oB) {
    bf16x4 o4 = {(__bf16)y0, (__bf16)y1, (__bf16)y2, (__bf16)y3};
    *(bf16x4*)(oB + base) = o4;
  }
}

extern "C" void kernel_launch(void* const* d_in, const int* in_sizes, int n_in,
                              void* d_out, int out_size, void* d_ws, size_t ws_size,
                              hipStream_t stream) {
  const float* src    = (const float*)d_in[0];
  const float* pos    = (const float*)d_in[1];
  // d_in[2] = src_mask: all zeros in this problem -> no-op, skipped
  const float* qw     = (const float*)d_in[3];
  const float* kw     = (const float*)d_in[4];
  const float* vw     = (const float*)d_in[5];
  const float* rw     = (const float*)d_in[6];
  const float* ow     = (const float*)d_in[7];
  const float* rwbias = (const float*)d_in[8];
  const float* rrbias = (const float*)d_in[9];
  const float* w1     = (const float*)d_in[10];
  const float* b1     = (const float*)d_in[11];
  const float* w2     = (const float*)d_in[12];
  const float* b2     = (const float*)d_in[13];
  const float* g1     = (const float*)d_in[14];
  const float* be1    = (const float*)d_in[15];
  const float* g2     = (const float*)d_in[16];
  const float* be2    = (const float*)d_in[17];
  float* out = (float*)d_out;

  char* p = (char*)d_ws;
  auto alloc = [&](size_t bytes) { char* r = p; p += (bytes + 255) & ~(size_t)255; return r; };
  __bf16* srcB = (__bf16*)alloc(4096ull * 1024 * 2);   // free after QKV gemm
  __bf16* posB = (__bf16*)alloc(4100ull * 1024 * 2);   // free after kpos gemm
  __bf16* qkvT = (__bf16*)alloc(3072ull * 1024 * 2);
  __bf16* rwT  = (__bf16*)alloc(1024ull * 1024 * 2);
  __bf16* owB  = (__bf16*)alloc(1024ull * 1024 * 2);
  __bf16* w1B  = (__bf16*)alloc(4096ull * 1024 * 2);
  __bf16* w2B  = (__bf16*)alloc(1024ull * 4096 * 2);
  float* qkvF  = (float*)alloc(4096ull * 3072 * 4);    // free after attn
  float* kposF = (float*)alloc(4100ull * 1024 * 4);    // free after attn
  __bf16* avB  = (__bf16*)alloc(4096ull * 1024 * 2);
  float* xF    = (float*)alloc(4096ull * 1024 * 4);
  __bf16* xB   = (__bf16*)alloc(4096ull * 1024 * 2);
  // aliased buffers (lifetimes disjoint with their hosts):
  float* aoF  = (float*)srcB;    // attn_out f32 [4096][1024] (16 MB <= srcB+posB)
  __bf16* gB  = (__bf16*)qkvF;   // gelu bf16 [4096][4096] (32 MB <= 48 MB)
  float* ffF  = (float*)kposF;   // ffn2 out f32 [4096][1024] (16 MB <= 16.79 MB)

  // 1. converts
  cvt_kernel<<<2048, 256, 0, stream>>>(src, srcB, 4096 * 1024);
  cvt_kernel<<<2048, 256, 0, stream>>>(pos, posB, 4100 * 1024);
  cvt_kernel<<<1024, 256, 0, stream>>>(ow, owB, 1024 * 1024);
  cvt_kernel<<<2048, 256, 0, stream>>>(w1, w1B, 4096 * 1024);
  cvt_kernel<<<2048, 256, 0, stream>>>(w2, w2B, 4096 * 1024);
  dim3 tb(32, 8);
  tcvt_kernel<<<dim3(32, 32), tb, 0, stream>>>(qw, qkvT, 1024, 1024);
  tcvt_kernel<<<dim3(32, 32), tb, 0, stream>>>(kw, qkvT + 1024 * 1024, 1024, 1024);
  tcvt_kernel<<<dim3(32, 32), tb, 0, stream>>>(vw, qkvT + 2048 * 1024, 1024, 1024);
  tcvt_kernel<<<dim3(32, 32), tb, 0, stream>>>(rw, rwT, 1024, 1024);
  // 2. projections
  gemm_bt<128, 128, 0><<<dim3(24, 32), 256, 0, stream>>>(srcB, qkvT, qkvF, nullptr, nullptr, 4096, 3072, 1024);
  gemm_bt<64, 128, 0><<<dim3(8, 65), 256, 0, stream>>>(posB, rwT, kposF, nullptr, nullptr, 4100, 1024, 1024);
  // 3. attention
  attn_fused<<<dim3(32, 16, 4), 256, 0, stream>>>(qkvF, kposF, rwbias, rrbias, avB);
  gemm_bt<64, 128, 0><<<dim3(8, 64), 256, 0, stream>>>(avB, owB, aoF, nullptr, nullptr, 4096, 1024, 1024);
  // 4. LN1
  ln_fuse<<<4096, 256, 0, stream>>>(src, aoF, nullptr, g1, be1, xF, xB);
  // 5. FFN
  gemm_bt<128, 128, 1><<<dim3(32, 32), 256, 0, stream>>>(xB, w1B, nullptr, gB, b1, 4096, 4096, 1024);
  gemm_bt<64, 128, 0><<<dim3(8, 64), 256, 0, stream>>>(gB, w2B, ffF, nullptr, nullptr, 4096, 1024, 4096);
  // 6. LN2 -> out
  ln_fuse<<<4096, 256, 0, stream>>>(xF, ffF, b2, g2, be2, out, nullptr);
  (void)in_sizes; (void)n_in; (void)out_size; (void)ws_size;
}

// Round 2
// 465.961 us; speedup vs baseline: 3.0515x; 3.0515x over previous
//
#include <hip/hip_runtime.h>
#include <math.h>

typedef __bf16 bf16x8 __attribute__((ext_vector_type(8)));
typedef __bf16 bf16x4 __attribute__((ext_vector_type(4)));
typedef float f32x4 __attribute__((ext_vector_type(4)));

__device__ __forceinline__ void gload_lds16(const __bf16* g, __bf16* l) {
  __builtin_amdgcn_global_load_lds((const __attribute__((address_space(1))) void*)g,
                                   (__attribute__((address_space(3))) void*)l, 16, 0, 0);
}

__device__ __forceinline__ float gelu_exact(float v) {
  return 0.5f * v * (1.f + erff(v * 0.70710678118654752f));
}

// ---------------- f32 -> bf16 convert ----------------
__global__ __launch_bounds__(256) void cvt_kernel(const float* __restrict__ in,
                                                  __bf16* __restrict__ out, int n) {
  const int stride = gridDim.x * 256 * 4;
  for (int i = (blockIdx.x * 256 + threadIdx.x) * 4; i < n; i += stride) {
    float4 v = *(const float4*)(in + i);
    bf16x4 o = {(__bf16)v.x, (__bf16)v.y, (__bf16)v.z, (__bf16)v.w};
    *(bf16x4*)(out + i) = o;
  }
}

// ---------------- f32 [R][C] -> bf16 [C][R] transpose-convert ----------------
__global__ __launch_bounds__(256) void tcvt_kernel(const float* __restrict__ in,
                                                   __bf16* __restrict__ out, int R, int C) {
  __shared__ float t[32][33];
  const int c0 = blockIdx.x * 32, r0 = blockIdx.y * 32;
  for (int yy = threadIdx.y; yy < 32; yy += 8)
    t[yy][threadIdx.x] = in[(size_t)(r0 + yy) * C + c0 + threadIdx.x];
  __syncthreads();
  for (int yy = threadIdx.y; yy < 32; yy += 8)
    out[(size_t)(c0 + yy) * R + r0 + threadIdx.x] = (__bf16)t[threadIdx.x][yy];
}

// ---------------- bf16 MFMA GEMM: C[M,N] = A[M,K] * BT[N,K]^T ----------------
// MODE 0: f32 C.  MODE 1: bf16 C = gelu(acc + bias[col]).  MODE 2: bf16 C.
template<int BM, int BN, int MODE>
__global__ __launch_bounds__(256)
void gemm_bt(const __bf16* __restrict__ A, const __bf16* __restrict__ BT,
             float* __restrict__ Cf, __bf16* __restrict__ Cb,
             const float* __restrict__ bias, int M, int N, int K) {
  constexpr int BK = 32;
  constexpr int ALOAD = (BM * BK) / 2048;
  constexpr int BLOAD = (BN * BK) / 2048;
  __shared__ __align__(16) __bf16 lA[BM * BK];
  __shared__ __align__(16) __bf16 lB[BN * BK];
  const int tid = threadIdx.x;
  const int w = tid >> 6, l = tid & 63;
  const int lr = l & 15, lk = l >> 4;
  const int mBase = blockIdx.y * BM, nBase = blockIdx.x * BN;
  constexpr int WM = BM / 2, WN = BN / 2;
  constexpr int MF = WM / 16, NF = WN / 16;
  const int wr = w >> 1, wc = w & 1;
  f32x4 acc[MF][NF] = {};
  const int srow = tid >> 2;
  const int scol = (tid & 3) * 8;

  for (int k0 = 0; k0 < K; k0 += BK) {
#pragma unroll
    for (int i = 0; i < ALOAD; ++i) {
      int grow = mBase + srow + i * 64;
      grow = grow < M ? grow : M - 1;
      gload_lds16(A + (size_t)grow * K + k0 + scol, lA + i * 2048 + w * 512);
    }
#pragma unroll
    for (int i = 0; i < BLOAD; ++i) {
      int grow = nBase + srow + i * 64;
      gload_lds16(BT + (size_t)grow * K + k0 + scol, lB + i * 2048 + w * 512);
    }
    __syncthreads();
    bf16x8 af[MF], bfr[NF];
#pragma unroll
    for (int mi = 0; mi < MF; ++mi)
      af[mi] = *(const bf16x8*)&lA[(wr * WM + mi * 16 + lr) * BK + lk * 8];
#pragma unroll
    for (int nj = 0; nj < NF; ++nj)
      bfr[nj] = *(const bf16x8*)&lB[(wc * WN + nj * 16 + lr) * BK + lk * 8];
#pragma unroll
    for (int mi = 0; mi < MF; ++mi)
#pragma unroll
      for (int nj = 0; nj < NF; ++nj)
        acc[mi][nj] = __builtin_amdgcn_mfma_f32_16x16x32_bf16(af[mi], bfr[nj], acc[mi][nj], 0, 0, 0);
    __syncthreads();
  }
#pragma unroll
  for (int mi = 0; mi < MF; ++mi) {
#pragma unroll
    for (int nj = 0; nj < NF; ++nj) {
      const int col = nBase + wc * WN + nj * 16 + lr;
      const int row0 = mBase + wr * WM + mi * 16 + lk * 4;
#pragma unroll
      for (int j = 0; j < 4; ++j) {
        const int row = row0 + j;
        if (row < M) {
          float v = acc[mi][nj][j];
          if constexpr (MODE == 1) {
            v = gelu_exact(v + bias[col]);
            Cb[(size_t)row * N + col] = (__bf16)v;
          } else if constexpr (MODE == 2) {
            Cb[(size_t)row * N + col] = (__bf16)v;
          } else {
            Cf[(size_t)row * N + col] = v;
          }
        }
      }
    }
  }
}

// ---------------- MFMA rel-pos attention ----------------
// qkv bf16 [4096][3072] (q|k|v) rows (i*4+b); kpos bf16 [4100][1024] rows (idx*4+b)
// per block: 64 queries (i-tile) x one (n,b). 4 waves, each owns a 16-row strip.
// scores[i][j] = 0.125*( (q[i]+rwb).k[j] + (q[i+(r>0)]+rrb).kpos[idx(r)] ), r=j-i
// band trick: G[ii][rr] = (q[ii]+rrb).KP[rr], rr = j_loc-i_loc+63 in [0,127)
__global__ __launch_bounds__(256)
void attn_mfma(const __bf16* __restrict__ qkv, const __bf16* __restrict__ kpos,
               const float* __restrict__ rwbias, const float* __restrict__ rrbias,
               __bf16* __restrict__ av) {
  constexpr int PK = 72;    // bf16 row pitch (144B: 16B aligned, 2-way-free banks)
  constexpr int PG = 129;   // f32 row pitch for G
  __shared__ __align__(16) char smem[79760];
  __bf16* sK  = (__bf16*)(smem);            // [64][PK]
  __bf16* sVT = (__bf16*)(smem + 9216);     // [64][PK]  rows=d, cols=j
  __bf16* sKP = (__bf16*)(smem + 18432);    // [128][PK]
  __bf16* sP  = (__bf16*)(smem + 36864);    // [64][PK]  (also V row-staging)
  float*  sG  = (float*) (smem + 46080);    // [65][PG]  (also Q staging at start)
  __bf16* sQ64= (__bf16*)(smem + 79620);    // [64]

  const int it = blockIdx.x, n = blockIdx.y, b = blockIdx.z;
  const int i0 = it * 64;
  const int tid = threadIdx.x;
  const int w = tid >> 6, l = tid & 63;
  const int lcol = l & 15, lk = l >> 4;
  const int strip = w * 16;

  // ---- stage Q (65 rows) into sG alias; build bias-folded A-frags ----
  __bf16* sQ = (__bf16*)sG;  // [65][PK]
  {
    const int r = tid >> 2, c0 = (tid & 3) * 16;
    for (int rr = r; rr < 65; rr += 64) {
      int gi = i0 + rr; gi = gi < 1023 ? gi : 1023;
      const __bf16* s = qkv + ((size_t)gi * 4 + b) * 3072 + n * 64 + c0;
      *(bf16x8*)&sQ[rr * PK + c0] = *(const bf16x8*)s;
      *(bf16x8*)&sQ[rr * PK + c0 + 8] = *(const bf16x8*)(s + 8);
    }
  }
  __syncthreads();
  bf16x8 qac[2], qg[2];
#pragma unroll
  for (int kk = 0; kk < 2; ++kk) {
    const int dbase = kk * 32 + lk * 8;
    bf16x8 qv = *(const bf16x8*)&sQ[(strip + lcol) * PK + dbase];
#pragma unroll
    for (int u = 0; u < 8; ++u) {
      float qf = (float)qv[u];
      qac[kk][u] = (__bf16)(qf + rwbias[n * 64 + dbase + u]);
      qg[kk][u]  = (__bf16)(qf + rrbias[n * 64 + dbase + u]);
    }
  }
  if (tid < 64)
    sQ64[tid] = (__bf16)((float)sQ[64 * PK + tid] + rrbias[n * 64 + tid]);

  float mrow[4], Zrow[4];
  f32x4 oacc[4] = {};
#pragma unroll
  for (int jj = 0; jj < 4; ++jj) { mrow[jj] = -1e30f; Zrow[jj] = 0.f; }

#pragma unroll 1
  for (int jt = 0; jt < 16; ++jt) {
    const int j0 = jt * 64;
    const int d0 = j0 - i0;
    __syncthreads();  // prev PV / sQ reads done before restage
    // stage K rows + V rows (into sP)
    {
      const int r = tid >> 2, c0 = (tid & 3) * 16;
      const __bf16* s = qkv + ((size_t)(j0 + r) * 4 + b) * 3072 + 1024 + n * 64 + c0;
      *(bf16x8*)&sK[r * PK + c0] = *(const bf16x8*)s;
      *(bf16x8*)&sK[r * PK + c0 + 8] = *(const bf16x8*)(s + 8);
      const __bf16* sv = qkv + ((size_t)(j0 + r) * 4 + b) * 3072 + 2048 + n * 64 + c0;
      *(bf16x8*)&sP[r * PK + c0] = *(const bf16x8*)sv;
      *(bf16x8*)&sP[r * PK + c0 + 8] = *(const bf16x8*)(sv + 8);
    }
    // stage KP band: 128 rows
    {
      const int rr = tid >> 1, c0 = (tid & 1) * 32;
      const int rrel = rr - 63 + d0;
      const int idx = (rrel <= 0) ? (1024 + rrel) : (rrel - 1);
      const __bf16* s = kpos + ((size_t)idx * 4 + b) * 1024 + n * 64 + c0;
#pragma unroll
      for (int u = 0; u < 4; ++u)
        *(bf16x8*)&sKP[rr * PK + c0 + u * 8] = *(const bf16x8*)(s + u * 8);
    }
    __syncthreads();
    // V transpose: sP rows -> sVT rows(d)
    {
      const int d = tid >> 2, jc = (tid & 3) * 16;
      bf16x8 v0, v1;
#pragma unroll
      for (int u = 0; u < 8; ++u) {
        v0[u] = sP[(jc + u) * PK + d];
        v1[u] = sP[(jc + 8 + u) * PK + d];
      }
      *(bf16x8*)&sVT[d * PK + jc] = v0;
      *(bf16x8*)&sVT[d * PK + jc + 8] = v1;
    }
    // G MFMA: rows [strip,strip+16), 8 col-frags over the band
#pragma unroll
    for (int fg = 0; fg < 8; ++fg) {
      f32x4 g = {};
#pragma unroll
      for (int kk = 0; kk < 2; ++kk) {
        bf16x8 bv = *(const bf16x8*)&sKP[(fg * 16 + lcol) * PK + kk * 32 + lk * 8];
        g = __builtin_amdgcn_mfma_f32_16x16x32_bf16(qg[kk], bv, g, 0, 0, 0);
      }
#pragma unroll
      for (int jj = 0; jj < 4; ++jj)
        sG[(strip + lk * 4 + jj) * PG + fg * 16 + lcol] = g[jj];
    }
    // G64 fixup: G[64][rr], rr = 0..63 (only these are ever read)
    if (tid < 64) {
      float a64 = 0.f;
#pragma unroll 16
      for (int d = 0; d < 64; ++d)
        a64 += (float)sQ64[d] * (float)sKP[tid * PK + d];
      sG[64 * PG + tid] = a64;
    }
    // ac MFMA: 4 col-frags
    f32x4 sc[4];
#pragma unroll
    for (int fj = 0; fj < 4; ++fj) {
      f32x4 a = {};
#pragma unroll
      for (int kk = 0; kk < 2; ++kk) {
        bf16x8 bv = *(const bf16x8*)&sK[(fj * 16 + lcol) * PK + kk * 32 + lk * 8];
        a = __builtin_amdgcn_mfma_f32_16x16x32_bf16(qac[kk], bv, a, 0, 0, 0);
      }
      sc[fj] = a;
    }
    __syncthreads();  // G + sVT visible
    // gather + online softmax
    float pe[4][4];
    float tmax[4] = {-1e30f, -1e30f, -1e30f, -1e30f};
#pragma unroll
    for (int fj = 0; fj < 4; ++fj) {
      const int j_loc = fj * 16 + lcol;
#pragma unroll
      for (int jj = 0; jj < 4; ++jj) {
        const int i_loc = strip + lk * 4 + jj;
        const int base = j_loc - i_loc;
        const int grow = i_loc + ((d0 + base) > 0 ? 1 : 0);
        float s = (sc[fj][jj] + sG[grow * PG + base + 63]) * 0.125f;
        pe[fj][jj] = s;
        tmax[jj] = fmaxf(tmax[jj], s);
      }
    }
#pragma unroll
    for (int o = 1; o <= 8; o <<= 1)
#pragma unroll
      for (int jj = 0; jj < 4; ++jj)
        tmax[jj] = fmaxf(tmax[jj], __shfl_xor(tmax[jj], o, 16));
    float al[4];
#pragma unroll
    for (int jj = 0; jj < 4; ++jj) {
      const float nm = fmaxf(mrow[jj], tmax[jj]);
      al[jj] = __expf(mrow[jj] - nm);
      mrow[jj] = nm;
    }
    float zl[4] = {0.f, 0.f, 0.f, 0.f};
#pragma unroll
    for (int fj = 0; fj < 4; ++fj)
#pragma unroll
      for (int jj = 0; jj < 4; ++jj) {
        const float e = __expf(pe[fj][jj] - mrow[jj]);
        zl[jj] += e;
        sP[(strip + lk * 4 + jj) * PK + fj * 16 + lcol] = (__bf16)e;
      }
#pragma unroll
    for (int o = 1; o <= 8; o <<= 1)
#pragma unroll
      for (int jj = 0; jj < 4; ++jj)
        zl[jj] += __shfl_xor(zl[jj], o, 16);
#pragma unroll
    for (int jj = 0; jj < 4; ++jj)
      Zrow[jj] = Zrow[jj] * al[jj] + zl[jj];
#pragma unroll
    for (int fd = 0; fd < 4; ++fd)
#pragma unroll
      for (int jj = 0; jj < 4; ++jj)
        oacc[fd][jj] *= al[jj];
    __syncthreads();  // P visible
    // PV MFMA
#pragma unroll
    for (int kk = 0; kk < 2; ++kk) {
      bf16x8 pa = *(const bf16x8*)&sP[(strip + lcol) * PK + kk * 32 + lk * 8];
#pragma unroll
      for (int fd = 0; fd < 4; ++fd) {
        bf16x8 bv = *(const bf16x8*)&sVT[(fd * 16 + lcol) * PK + kk * 32 + lk * 8];
        oacc[fd] = __builtin_amdgcn_mfma_f32_16x16x32_bf16(pa, bv, oacc[fd], 0, 0, 0);
      }
    }
  }
  // epilogue
#pragma unroll
  for (int jj = 0; jj < 4; ++jj) {
    const int ig = i0 + strip + lk * 4 + jj;
    const float rz = 1.f / Zrow[jj];
    __bf16* dst = av + ((size_t)ig * 4 + b) * 1024 + n * 64;
#pragma unroll
    for (int fd = 0; fd < 4; ++fd)
      dst[fd * 16 + lcol] = (__bf16)(oacc[fd][jj] * rz);
  }
}

// ---------------- fused residual + LayerNorm ----------------
__global__ __launch_bounds__(256)
void ln_fuse(const float* __restrict__ A, const float* __restrict__ Bv,
             const float* __restrict__ cb, const float* __restrict__ g,
             const float* __restrict__ be, float* __restrict__ oF,
             __bf16* __restrict__ oB) {
  const int row = blockIdx.x, t = threadIdx.x;
  const size_t base = (size_t)row * 1024 + t * 4;
  const float4 a = *(const float4*)(A + base);
  const float4 bb = *(const float4*)(Bv + base);
  float x0 = a.x + bb.x, x1 = a.y + bb.y, x2 = a.z + bb.z, x3 = a.w + bb.w;
  if (cb) {
    const float4 c = *(const float4*)(cb + t * 4);
    x0 += c.x; x1 += c.y; x2 += c.z; x3 += c.w;
  }
  float s = x0 + x1 + x2 + x3;
  float q = x0 * x0 + x1 * x1 + x2 * x2 + x3 * x3;
#pragma unroll
  for (int o = 1; o < 64; o <<= 1) { s += __shfl_xor(s, o, 64); q += __shfl_xor(q, o, 64); }
  __shared__ float ss[4], qq[4];
  if ((t & 63) == 0) { ss[t >> 6] = s; qq[t >> 6] = q; }
  __syncthreads();
  s = ss[0] + ss[1] + ss[2] + ss[3];
  q = qq[0] + qq[1] + qq[2] + qq[3];
  const float mean = s * (1.f / 1024.f);
  const float var = q * (1.f / 1024.f) - mean * mean;
  const float rstd = rsqrtf(var + 1e-5f);
  const float4 gv = *(const float4*)(g + t * 4);
  const float4 bev = *(const float4*)(be + t * 4);
  const float y0 = (x0 - mean) * rstd * gv.x + bev.x;
  const float y1 = (x1 - mean) * rstd * gv.y + bev.y;
  const float y2 = (x2 - mean) * rstd * gv.z + bev.z;
  const float y3 = (x3 - mean) * rstd * gv.w + bev.w;
  float4 r = {y0, y1, y2, y3};
  *(float4*)(oF + base) = r;
  if (oB) {
    bf16x4 o4 = {(__bf16)y0, (__bf16)y1, (__bf16)y2, (__bf16)y3};
    *(bf16x4*)(oB + base) = o4;
  }
}

extern "C" void kernel_launch(void* const* d_in, const int* in_sizes, int n_in,
                              void* d_out, int out_size, void* d_ws, size_t ws_size,
                              hipStream_t stream) {
  const float* src    = (const float*)d_in[0];
  const float* pos    = (const float*)d_in[1];
  const float* qw     = (const float*)d_in[3];
  const float* kw     = (const float*)d_in[4];
  const float* vw     = (const float*)d_in[5];
  const float* rw     = (const float*)d_in[6];
  const float* ow     = (const float*)d_in[7];
  const float* rwbias = (const float*)d_in[8];
  const float* rrbias = (const float*)d_in[9];
  const float* w1     = (const float*)d_in[10];
  const float* b1     = (const float*)d_in[11];
  const float* w2     = (const float*)d_in[12];
  const float* b2     = (const float*)d_in[13];
  const float* g1     = (const float*)d_in[14];
  const float* be1    = (const float*)d_in[15];
  const float* g2     = (const float*)d_in[16];
  const float* be2    = (const float*)d_in[17];
  float* out = (float*)d_out;

  char* p = (char*)d_ws;
  auto alloc = [&](size_t bytes) { char* r = p; p += (bytes + 255) & ~(size_t)255; return r; };
  __bf16* srcB = (__bf16*)alloc(4096ull * 1024 * 2);
  __bf16* posB = (__bf16*)alloc(4100ull * 1024 * 2);
  __bf16* qkvT = (__bf16*)alloc(3072ull * 1024 * 2);
  __bf16* rwT  = (__bf16*)alloc(1024ull * 1024 * 2);
  __bf16* owB  = (__bf16*)alloc(1024ull * 1024 * 2);
  __bf16* w1B  = (__bf16*)alloc(4096ull * 1024 * 2);
  __bf16* w2B  = (__bf16*)alloc(1024ull * 4096 * 2);
  __bf16* qkvB = (__bf16*)alloc(4096ull * 3072 * 2);   // dead after attn
  __bf16* kposB= (__bf16*)alloc(4100ull * 1024 * 2);   // dead after attn
  __bf16* avB  = (__bf16*)alloc(4096ull * 1024 * 2);
  float* xF    = (float*)alloc(4096ull * 1024 * 4);
  __bf16* xB   = (__bf16*)alloc(4096ull * 1024 * 2);
  // aliases (disjoint lifetimes):
  float* aoF  = (float*)srcB;    // attn-out f32 16MB over srcB+posB (16.4MB)
  __bf16* gB  = (__bf16*)qkvB;   // gelu bf16 32MB over qkvB+kposB (32.4MB)
  float* ffF  = (float*)srcB;    // ffn2 f32 16MB over srcB+posB (aoF dead after LN1)

  cvt_kernel<<<2048, 256, 0, stream>>>(src, srcB, 4096 * 1024);
  cvt_kernel<<<2048, 256, 0, stream>>>(pos, posB, 4100 * 1024);
  cvt_kernel<<<1024, 256, 0, stream>>>(ow, owB, 1024 * 1024);
  cvt_kernel<<<2048, 256, 0, stream>>>(w1, w1B, 4096 * 1024);
  cvt_kernel<<<2048, 256, 0, stream>>>(w2, w2B, 4096 * 1024);
  dim3 tb(32, 8);
  tcvt_kernel<<<dim3(32, 32), tb, 0, stream>>>(qw, qkvT, 1024, 1024);
  tcvt_kernel<<<dim3(32, 32), tb, 0, stream>>>(kw, qkvT + 1024 * 1024, 1024, 1024);
  tcvt_kernel<<<dim3(32, 32), tb, 0, stream>>>(vw, qkvT + 2048 * 1024, 1024, 1024);
  tcvt_kernel<<<dim3(32, 32), tb, 0, stream>>>(rw, rwT, 1024, 1024);
  gemm_bt<128, 128, 2><<<dim3(24, 32), 256, 0, stream>>>(srcB, qkvT, nullptr, qkvB, nullptr, 4096, 3072, 1024);
  gemm_bt<64, 128, 2><<<dim3(8, 65), 256, 0, stream>>>(posB, rwT, nullptr, kposB, nullptr, 4100, 1024, 1024);
  attn_mfma<<<dim3(16, 16, 4), 256, 0, stream>>>(qkvB, kposB, rwbias, rrbias, avB);
  gemm_bt<64, 128, 0><<<dim3(8, 64), 256, 0, stream>>>(avB, owB, aoF, nullptr, nullptr, 4096, 1024, 1024);
  ln_fuse<<<4096, 256, 0, stream>>>(src, aoF, nullptr, g1, be1, xF, xB);
  gemm_bt<128, 128, 1><<<dim3(32, 32), 256, 0, stream>>>(xB, w1B, nullptr, gB, b1, 4096, 4096, 1024);
  gemm_bt<64, 128, 0><<<dim3(8, 64), 256, 0, stream>>>(gB, w2B, ffF, nullptr, nullptr, 4096, 1024, 4096);
  ln_fuse<<<4096, 256, 0, stream>>>(xF, ffF, b2, g2, be2, out, nullptr);
  (void)in_sizes; (void)n_in; (void)out_size; (void)ws_size;
}

// Round 3
// 450.322 us; speedup vs baseline: 3.1575x; 1.0347x over previous
//
#include <hip/hip_runtime.h>
#include <math.h>

typedef __bf16 bf16x8 __attribute__((ext_vector_type(8)));
typedef __bf16 bf16x4 __attribute__((ext_vector_type(4)));
typedef float f32x4 __attribute__((ext_vector_type(4)));

__device__ __forceinline__ void gload_lds16(const __bf16* g, __bf16* l) {
  __builtin_amdgcn_global_load_lds((const __attribute__((address_space(1))) void*)g,
                                   (__attribute__((address_space(3))) void*)l, 16, 0, 0);
}

__device__ __forceinline__ float gelu_exact(float v) {
  return 0.5f * v * (1.f + erff(v * 0.70710678118654752f));
}

// ---------------- f32 -> bf16 convert ----------------
__global__ __launch_bounds__(256) void cvt_kernel(const float* __restrict__ in,
                                                  __bf16* __restrict__ out, int n) {
  const int stride = gridDim.x * 256 * 4;
  for (int i = (blockIdx.x * 256 + threadIdx.x) * 4; i < n; i += stride) {
    float4 v = *(const float4*)(in + i);
    bf16x4 o = {(__bf16)v.x, (__bf16)v.y, (__bf16)v.z, (__bf16)v.w};
    *(bf16x4*)(out + i) = o;
  }
}

// ---- src (i,b)-rows -> bf16 (b,i)-rows ----
__global__ __launch_bounds__(256) void cvt_perm_src(const float* __restrict__ in,
                                                    __bf16* __restrict__ out) {
  const int rp = blockIdx.x;            // b*1024 + i
  const int i = rp & 1023, b = rp >> 10;
  const float4 v = *(const float4*)(in + ((size_t)(i * 4 + b)) * 1024 + threadIdx.x * 4);
  bf16x4 o = {(__bf16)v.x, (__bf16)v.y, (__bf16)v.z, (__bf16)v.w};
  *(bf16x4*)(out + (size_t)rp * 1024 + threadIdx.x * 4) = o;
}

// ---------------- f32 [R][C] -> bf16 [C][R] transpose-convert ----------------
__global__ __launch_bounds__(256) void tcvt_kernel(const float* __restrict__ in,
                                                   __bf16* __restrict__ out, int R, int C) {
  __shared__ float t[32][33];
  const int c0 = blockIdx.x * 32, r0 = blockIdx.y * 32;
  for (int yy = threadIdx.y; yy < 32; yy += 8)
    t[yy][threadIdx.x] = in[(size_t)(r0 + yy) * C + c0 + threadIdx.x];
  __syncthreads();
  for (int yy = threadIdx.y; yy < 32; yy += 8)
    out[(size_t)(c0 + yy) * R + r0 + threadIdx.x] = (__bf16)t[threadIdx.x][yy];
}

// ---------------- bf16 MFMA GEMM: C[M,N] = A[M,K] * BT[N,K]^T ----------------
// MODE 0: f32 C.  MODE 1: bf16 C = gelu(acc + bias[col]).  MODE 2: bf16 C.
template<int BM, int BN, int MODE>
__global__ __launch_bounds__(256)
void gemm_bt(const __bf16* __restrict__ A, const __bf16* __restrict__ BT,
             float* __restrict__ Cf, __bf16* __restrict__ Cb,
             const float* __restrict__ bias, int M, int N, int K) {
  constexpr int BK = 32;
  constexpr int ALOAD = (BM * BK) / 2048;
  constexpr int BLOAD = (BN * BK) / 2048;
  __shared__ __align__(16) __bf16 lA[BM * BK];
  __shared__ __align__(16) __bf16 lB[BN * BK];
  const int tid = threadIdx.x;
  const int w = tid >> 6, l = tid & 63;
  const int lr = l & 15, lk = l >> 4;
  const int mBase = blockIdx.y * BM, nBase = blockIdx.x * BN;
  constexpr int WM = BM / 2, WN = BN / 2;
  constexpr int MF = WM / 16, NF = WN / 16;
  const int wr = w >> 1, wc = w & 1;
  f32x4 acc[MF][NF] = {};
  const int srow = tid >> 2;
  const int scol = (tid & 3) * 8;

  for (int k0 = 0; k0 < K; k0 += BK) {
#pragma unroll
    for (int i = 0; i < ALOAD; ++i) {
      int grow = mBase + srow + i * 64;
      grow = grow < M ? grow : M - 1;
      gload_lds16(A + (size_t)grow * K + k0 + scol, lA + i * 2048 + w * 512);
    }
#pragma unroll
    for (int i = 0; i < BLOAD; ++i) {
      int grow = nBase + srow + i * 64;
      gload_lds16(BT + (size_t)grow * K + k0 + scol, lB + i * 2048 + w * 512);
    }
    __syncthreads();
    bf16x8 af[MF], bfr[NF];
#pragma unroll
    for (int mi = 0; mi < MF; ++mi)
      af[mi] = *(const bf16x8*)&lA[(wr * WM + mi * 16 + lr) * BK + lk * 8];
#pragma unroll
    for (int nj = 0; nj < NF; ++nj)
      bfr[nj] = *(const bf16x8*)&lB[(wc * WN + nj * 16 + lr) * BK + lk * 8];
#pragma unroll
    for (int mi = 0; mi < MF; ++mi)
#pragma unroll
      for (int nj = 0; nj < NF; ++nj)
        acc[mi][nj] = __builtin_amdgcn_mfma_f32_16x16x32_bf16(af[mi], bfr[nj], acc[mi][nj], 0, 0, 0);
    __syncthreads();
  }
#pragma unroll
  for (int mi = 0; mi < MF; ++mi) {
#pragma unroll
    for (int nj = 0; nj < NF; ++nj) {
      const int col = nBase + wc * WN + nj * 16 + lr;
      const int row0 = mBase + wr * WM + mi * 16 + lk * 4;
#pragma unroll
      for (int j = 0; j < 4; ++j) {
        const int row = row0 + j;
        if (row < M) {
          float v = acc[mi][nj][j];
          if constexpr (MODE == 1) {
            v = gelu_exact(v + bias[col]);
            Cb[(size_t)row * N + col] = (__bf16)v;
          } else if constexpr (MODE == 2) {
            Cb[(size_t)row * N + col] = (__bf16)v;
          } else {
            Cf[(size_t)row * N + col] = v;
          }
        }
      }
    }
  }
}

// ---------------- MFMA rel-pos attention, ring-band + swizzled LDS ----------------
// qk  bf16 [4096 rows (b*1024+i)][2048] (q|k)
// vT  bf16 [1024 rows (n*64+d)][4096 cols (b*1024+j)]
// kpos bf16 [4100 rows (idx*4+b)][1024]
// out av bf16 rows (i*4+b)
// score[i][j] = 0.125*((q_i+rwb).k_j) + GT[rrel&127][i_loc + (rrel>0)],  rrel=j-i
// GT[c][ii] = 0.125*(q_{i0+ii}+rrb).kpos[idx(rrel)],  idx = rrel<=0 ? 1024+rrel : rrel-1
__global__ __launch_bounds__(256)
void attn3(const __bf16* __restrict__ qk, const __bf16* __restrict__ vT,
           const __bf16* __restrict__ kpos, const float* __restrict__ rwbias,
           const float* __restrict__ rrbias, __bf16* __restrict__ av) {
  __shared__ __align__(16) char smem[50816];
  __bf16* sK  = (__bf16*)(smem);           // [64][64] swizzled; P-alias after ac
  __bf16* sVT = (__bf16*)(smem + 8192);    // [64][64] swizzled (rows=d, cols=j)
  __bf16* sKP = (__bf16*)(smem + 16384);   // [128][64] swizzled ring (row = rrel&127)
  __bf16* sGT = (__bf16*)(smem + 32768);   // [128][70]  (Q-stage alias at start)
  __bf16* sQ64= (__bf16*)(smem + 50688);   // [64]

  const int it = blockIdx.x, n = blockIdx.y, b = blockIdx.z;
  const int i0 = it * 64;
  const int tid = threadIdx.x;
  const int l = tid & 63;
  const int lcol = l & 15, lk = l >> 4;
  const int strip = (tid >> 6) * 16;
  const int wbase = tid & 192;             // w*64
  const int nh64 = n * 64;

  // ---- stage Q (65 rows) into sGT alias, build scaled bias-folded frags ----
  __bf16* sQ = sGT;                        // [65][64] linear
  {
    const int r0 = tid >> 2, c0 = (tid & 3) * 16;
    for (int r = r0; r < 65; r += 64) {
      int gi = i0 + r; gi = gi < 1024 ? gi : 1023;
      const __bf16* s = qk + ((size_t)(b * 1024 + gi)) * 2048 + nh64 + c0;
      *(bf16x8*)&sQ[r * 64 + c0] = *(const bf16x8*)s;
      *(bf16x8*)&sQ[r * 64 + c0 + 8] = *(const bf16x8*)(s + 8);
    }
  }
  __syncthreads();
  bf16x8 qac[2], qg[2];
#pragma unroll
  for (int kk = 0; kk < 2; ++kk) {
    const int dbase = kk * 32 + lk * 8;
    bf16x8 qv = *(const bf16x8*)&sQ[(strip + lcol) * 64 + dbase];
#pragma unroll
    for (int u = 0; u < 8; ++u) {
      const float qf = (float)qv[u] * 0.125f;
      qac[kk][u] = (__bf16)(qf + rwbias[nh64 + dbase + u] * 0.125f);
      qg[kk][u]  = (__bf16)(qf + rrbias[nh64 + dbase + u] * 0.125f);
    }
  }
  if (tid < 64)
    sQ64[tid] = (__bf16)(((float)sQ[64 * 64 + tid] + rrbias[nh64 + tid]) * 0.125f);

  float mrow[4], Zrow[4];
  f32x4 oacc[4] = {};
#pragma unroll
  for (int jj = 0; jj < 4; ++jj) { mrow[jj] = -1e30f; Zrow[jj] = 0.f; }

  auto Gstep = [&](int rbase) {
    const int row = rbase + lcol;
    f32x4 g = {};
#pragma unroll
    for (int kk = 0; kk < 2; ++kk) {
      const int off = row * 64 + ((((kk * 64 + lk * 16)) ^ ((row & 7) << 4)) >> 1);
      bf16x8 bv = *(const bf16x8*)&sKP[off];
      g = __builtin_amdgcn_mfma_f32_16x16x32_bf16(qg[kk], bv, g, 0, 0, 0);
    }
#pragma unroll
    for (int jj = 0; jj < 4; ++jj)
      sGT[row * 70 + strip + lk * 4 + jj] = (__bf16)g[jj];
  };

#pragma unroll 1
  for (int jt = 0; jt < 16; ++jt) {
    const int j0 = jt * 64;
    const int d0 = j0 - i0;
    const int h = (jt ^ it) & 1;
    __syncthreads();   // prev PV done; q-frag reads done (jt=0)
    // ---- stage K rows (j) and VT rows (d), swizzled source chunks ----
#pragma unroll
    for (int kq = 0; kq < 2; ++kq) {
      const int q = kq * 256 + tid;
      const int r = q >> 3, cs = (q & 7) ^ (r & 7);
      gload_lds16(qk + ((size_t)(b * 1024 + j0 + r)) * 2048 + 1024 + nh64 + cs * 8,
                  sK + (kq * 256 + wbase) * 8);
      gload_lds16(vT + ((size_t)(nh64 + r)) * 4096 + b * 1024 + j0 + cs * 8,
                  sVT + (kq * 256 + wbase) * 8);
    }
    // ---- stage KP: new band rows ----
    if (jt == 0) {
#pragma unroll
      for (int kq = 0; kq < 4; ++kq) {
        const int q = kq * 256 + tid;
        const int r = q >> 3;                       // 0..127
        const int rrel = d0 - 64 + r;
        const int idx = (rrel <= 0) ? (1024 + rrel) : (rrel - 1);
        const int cs = (q & 7) ^ (r & 7);
        const int rowbase = (d0 - 64 + kq * 32 + (wbase >> 3) + 2048) & 127;
        gload_lds16(kpos + ((size_t)(idx * 4 + b)) * 1024 + nh64 + cs * 8,
                    sKP + rowbase * 64);
      }
    } else {
#pragma unroll
      for (int kq = 0; kq < 2; ++kq) {
        const int q = kq * 256 + tid;
        const int r = q >> 3;                       // 0..63
        const int rrel = d0 + r;
        const int idx = (rrel <= 0) ? (1024 + rrel) : (rrel - 1);
        const int cs = (q & 7) ^ (r & 7);
        gload_lds16(kpos + ((size_t)(idx * 4 + b)) * 1024 + nh64 + cs * 8,
                    sKP + h * 4096 + (kq * 256 + wbase) * 8);
      }
    }
    __syncthreads();
    // ---- G MFMA over new ring rows ----
    if (jt == 0) {
#pragma unroll
      for (int fg = 0; fg < 4; ++fg) Gstep(fg * 16);
#pragma unroll
      for (int fg = 0; fg < 4; ++fg) Gstep(64 + fg * 16);
    } else {
#pragma unroll
      for (int fg = 0; fg < 4; ++fg) Gstep(h * 64 + fg * 16);
    }
    // ---- ac MFMA ----
    f32x4 sc[4];
#pragma unroll
    for (int fj = 0; fj < 4; ++fj) {
      const int row = fj * 16 + lcol;
      f32x4 a = {};
#pragma unroll
      for (int kk = 0; kk < 2; ++kk) {
        const int off = row * 64 + (((kk * 64 + lk * 16) ^ ((row & 7) << 4)) >> 1);
        bf16x8 bv = *(const bf16x8*)&sK[off];
        a = __builtin_amdgcn_mfma_f32_16x16x32_bf16(qac[kk], bv, a, 0, 0, 0);
      }
      sc[fj] = a;
    }
    // ---- G64 row (grow=64), parallel: 4 lanes per new col ----
    {
      const int cl = tid >> 2, part = tid & 3;
      const int row = h * 64 + cl;
      const int sw = row & 7;
      bf16x8 kv0 = *(const bf16x8*)&sKP[row * 64 + (((2 * part) ^ sw) << 3)];
      bf16x8 kv1 = *(const bf16x8*)&sKP[row * 64 + (((2 * part + 1) ^ sw) << 3)];
      bf16x8 qv0 = *(const bf16x8*)&sQ64[part * 16];
      bf16x8 qv1 = *(const bf16x8*)&sQ64[part * 16 + 8];
      float s64 = 0.f;
#pragma unroll
      for (int u = 0; u < 8; ++u)
        s64 += (float)qv0[u] * (float)kv0[u] + (float)qv1[u] * (float)kv1[u];
      s64 += __shfl_xor(s64, 1, 64);
      s64 += __shfl_xor(s64, 2, 64);
      if (part == 0) sGT[row * 70 + 64] = (__bf16)s64;
    }
    __syncthreads();   // GT new cols + G64 visible; sK free for P
    // ---- gather + online softmax ----
    float pe[4][4];
    float tmax[4] = {-1e30f, -1e30f, -1e30f, -1e30f};
#pragma unroll
    for (int fj = 0; fj < 4; ++fj) {
#pragma unroll
      for (int jj = 0; jj < 4; ++jj) {
        const int iln = strip + lk * 4 + jj;
        const int rrel = d0 + fj * 16 + lcol - iln;
        const int col = (rrel + 2048) & 127;
        const int grow = iln + (rrel > 0 ? 1 : 0);
        const float s = sc[fj][jj] + (float)sGT[col * 70 + grow];
        pe[fj][jj] = s;
        tmax[jj] = fmaxf(tmax[jj], s);
      }
    }
#pragma unroll
    for (int o = 1; o <= 8; o <<= 1)
#pragma unroll
      for (int jj = 0; jj < 4; ++jj)
        tmax[jj] = fmaxf(tmax[jj], __shfl_xor(tmax[jj], o, 16));
    float al[4];
#pragma unroll
    for (int jj = 0; jj < 4; ++jj) {
      const float nm = fmaxf(mrow[jj], tmax[jj]);
      al[jj] = __expf(mrow[jj] - nm);
      mrow[jj] = nm;
    }
    float zl[4] = {0.f, 0.f, 0.f, 0.f};
#pragma unroll
    for (int fj = 0; fj < 4; ++fj)
#pragma unroll
      for (int jj = 0; jj < 4; ++jj) {
        const float e = __expf(pe[fj][jj] - mrow[jj]);
        zl[jj] += e;
        const int row = strip + lk * 4 + jj;
        const int boff = ((fj * 16 + lcol) * 2) ^ ((row & 7) << 4);
        sK[row * 64 + (boff >> 1)] = (__bf16)e;   // P over dead K
      }
#pragma unroll
    for (int o = 1; o <= 8; o <<= 1)
#pragma unroll
      for (int jj = 0; jj < 4; ++jj)
        zl[jj] += __shfl_xor(zl[jj], o, 16);
#pragma unroll
    for (int jj = 0; jj < 4; ++jj)
      Zrow[jj] = Zrow[jj] * al[jj] + zl[jj];
#pragma unroll
    for (int fd = 0; fd < 4; ++fd)
#pragma unroll
      for (int jj = 0; jj < 4; ++jj)
        oacc[fd][jj] *= al[jj];
    // ---- PV MFMA (own-wave P rows; in-order DS pipe, no barrier needed) ----
#pragma unroll
    for (int kk = 0; kk < 2; ++kk) {
      const int prow = strip + lcol;
      const int poff = prow * 64 + (((kk * 64 + lk * 16) ^ ((prow & 7) << 4)) >> 1);
      bf16x8 pa = *(const bf16x8*)&sK[poff];
#pragma unroll
      for (int fd = 0; fd < 4; ++fd) {
        const int vrow = fd * 16 + lcol;
        const int voff = vrow * 64 + (((kk * 64 + lk * 16) ^ ((vrow & 7) << 4)) >> 1);
        bf16x8 bv = *(const bf16x8*)&sVT[voff];
        oacc[fd] = __builtin_amdgcn_mfma_f32_16x16x32_bf16(pa, bv, oacc[fd], 0, 0, 0);
      }
    }
  }
  // ---- epilogue ----
#pragma unroll
  for (int jj = 0; jj < 4; ++jj) {
    const int ig = i0 + strip + lk * 4 + jj;
    const float rz = 1.f / Zrow[jj];
    __bf16* dst = av + ((size_t)(ig * 4 + b)) * 1024 + nh64;
#pragma unroll
    for (int fd = 0; fd < 4; ++fd)
      dst[fd * 16 + lcol] = (__bf16)(oacc[fd][jj] * rz);
  }
}

// ---------------- fused residual + LayerNorm ----------------
__global__ __launch_bounds__(256)
void ln_fuse(const float* __restrict__ A, const float* __restrict__ Bv,
             const float* __restrict__ cb, const float* __restrict__ g,
             const float* __restrict__ be, float* __restrict__ oF,
             __bf16* __restrict__ oB) {
  const int row = blockIdx.x, t = threadIdx.x;
  const size_t base = (size_t)row * 1024 + t * 4;
  const float4 a = *(const float4*)(A + base);
  const float4 bb = *(const float4*)(Bv + base);
  float x0 = a.x + bb.x, x1 = a.y + bb.y, x2 = a.z + bb.z, x3 = a.w + bb.w;
  if (cb) {
    const float4 c = *(const float4*)(cb + t * 4);
    x0 += c.x; x1 += c.y; x2 += c.z; x3 += c.w;
  }
  float s = x0 + x1 + x2 + x3;
  float q = x0 * x0 + x1 * x1 + x2 * x2 + x3 * x3;
#pragma unroll
  for (int o = 1; o < 64; o <<= 1) { s += __shfl_xor(s, o, 64); q += __shfl_xor(q, o, 64); }
  __shared__ float ss[4], qq[4];
  if ((t & 63) == 0) { ss[t >> 6] = s; qq[t >> 6] = q; }
  __syncthreads();
  s = ss[0] + ss[1] + ss[2] + ss[3];
  q = qq[0] + qq[1] + qq[2] + qq[3];
  const float mean = s * (1.f / 1024.f);
  const float var = q * (1.f / 1024.f) - mean * mean;
  const float rstd = rsqrtf(var + 1e-5f);
  const float4 gv = *(const float4*)(g + t * 4);
  const float4 bev = *(const float4*)(be + t * 4);
  const float y0 = (x0 - mean) * rstd * gv.x + bev.x;
  const float y1 = (x1 - mean) * rstd * gv.y + bev.y;
  const float y2 = (x2 - mean) * rstd * gv.z + bev.z;
  const float y3 = (x3 - mean) * rstd * gv.w + bev.w;
  float4 r = {y0, y1, y2, y3};
  *(float4*)(oF + base) = r;
  if (oB) {
    bf16x4 o4 = {(__bf16)y0, (__bf16)y1, (__bf16)y2, (__bf16)y3};
    *(bf16x4*)(oB + base) = o4;
  }
}

extern "C" void kernel_launch(void* const* d_in, const int* in_sizes, int n_in,
                              void* d_out, int out_size, void* d_ws, size_t ws_size,
                              hipStream_t stream) {
  const float* src    = (const float*)d_in[0];
  const float* pos    = (const float*)d_in[1];
  const float* qw     = (const float*)d_in[3];
  const float* kw     = (const float*)d_in[4];
  const float* vw     = (const float*)d_in[5];
  const float* rw     = (const float*)d_in[6];
  const float* ow     = (const float*)d_in[7];
  const float* rwbias = (const float*)d_in[8];
  const float* rrbias = (const float*)d_in[9];
  const float* w1     = (const float*)d_in[10];
  const float* b1     = (const float*)d_in[11];
  const float* w2     = (const float*)d_in[12];
  const float* b2     = (const float*)d_in[13];
  const float* g1     = (const float*)d_in[14];
  const float* be1    = (const float*)d_in[15];
  const float* g2     = (const float*)d_in[16];
  const float* be2    = (const float*)d_in[17];
  float* out = (float*)d_out;

  char* p = (char*)d_ws;
  auto alloc = [&](size_t bytes) { char* r = p; p += (bytes + 255) & ~(size_t)255; return r; };
  __bf16* srcB2 = (__bf16*)alloc(4096ull * 1024 * 2);   // (b,i)-rows
  __bf16* posB  = (__bf16*)alloc(4100ull * 1024 * 2);
  __bf16* qkvT  = (__bf16*)alloc(3072ull * 1024 * 2);   // qw^T|kw^T|vw^T
  __bf16* rwT   = (__bf16*)alloc(1024ull * 1024 * 2);
  __bf16* owB   = (__bf16*)alloc(1024ull * 1024 * 2);
  __bf16* w1B   = (__bf16*)alloc(4096ull * 1024 * 2);
  __bf16* w2B   = (__bf16*)alloc(4096ull * 1024 * 2);
  __bf16* qkB   = (__bf16*)alloc(4096ull * 2048 * 2);   // dead after attn
  __bf16* vTB   = (__bf16*)alloc(1024ull * 4096 * 2);   // dead after attn
  __bf16* kposB = (__bf16*)alloc(4100ull * 1024 * 2);   // dead after attn
  __bf16* avB   = (__bf16*)alloc(4096ull * 1024 * 2);
  float*  xF    = (float*)alloc(4096ull * 1024 * 4);
  __bf16* xB    = (__bf16*)alloc(4096ull * 1024 * 2);
  // aliases (disjoint lifetimes):
  float*  aoF = (float*)srcB2;   // attn-out f32 16MB over srcB2+posB
  __bf16* gB  = (__bf16*)qkB;    // gelu bf16 32MB over qkB+vTB+kposB
  float*  ffF = (float*)srcB2;   // ffn2 f32 (aoF dead after LN1)

  cvt_perm_src<<<4096, 256, 0, stream>>>(src, srcB2);
  cvt_kernel<<<2048, 256, 0, stream>>>(pos, posB, 4100 * 1024);
  cvt_kernel<<<1024, 256, 0, stream>>>(ow, owB, 1024 * 1024);
  cvt_kernel<<<2048, 256, 0, stream>>>(w1, w1B, 4096 * 1024);
  cvt_kernel<<<2048, 256, 0, stream>>>(w2, w2B, 4096 * 1024);
  dim3 tb(32, 8);
  tcvt_kernel<<<dim3(32, 32), tb, 0, stream>>>(qw, qkvT, 1024, 1024);
  tcvt_kernel<<<dim3(32, 32), tb, 0, stream>>>(kw, qkvT + 1024 * 1024, 1024, 1024);
  tcvt_kernel<<<dim3(32, 32), tb, 0, stream>>>(vw, qkvT + 2048 * 1024, 1024, 1024);
  tcvt_kernel<<<dim3(32, 32), tb, 0, stream>>>(rw, rwT, 1024, 1024);
  // projections: qk (M=4096,N=2048), vT (M=1024,N=4096), kpos (M=4100,N=1024)
  gemm_bt<128, 128, 2><<<dim3(16, 32), 256, 0, stream>>>(srcB2, qkvT, nullptr, qkB, nullptr, 4096, 2048, 1024);
  gemm_bt<128, 128, 2><<<dim3(32, 8), 256, 0, stream>>>(qkvT + 2048 * 1024, srcB2, nullptr, vTB, nullptr, 1024, 4096, 1024);
  gemm_bt<64, 128, 2><<<dim3(8, 65), 256, 0, stream>>>(posB, rwT, nullptr, kposB, nullptr, 4100, 1024, 1024);
  attn3<<<dim3(16, 16, 4), 256, 0, stream>>>(qkB, vTB, kposB, rwbias, rrbias, avB);
  gemm_bt<128, 128, 0><<<dim3(8, 32), 256, 0, stream>>>(avB, owB, aoF, nullptr, nullptr, 4096, 1024, 1024);
  ln_fuse<<<4096, 256, 0, stream>>>(src, aoF, nullptr, g1, be1, xF, xB);
  gemm_bt<128, 128, 1><<<dim3(32, 32), 256, 0, stream>>>(xB, w1B, nullptr, gB, b1, 4096, 4096, 1024);
  gemm_bt<128, 128, 0><<<dim3(8, 32), 256, 0, stream>>>(gB, w2B, ffF, nullptr, nullptr, 4096, 1024, 4096);
  ln_fuse<<<4096, 256, 0, stream>>>(xF, ffF, b2, g2, be2, out, nullptr);
  (void)in_sizes; (void)n_in; (void)out_size; (void)ws_size;
}

// Round 4
// 430.716 us; speedup vs baseline: 3.3012x; 1.0455x over previous
//
#include <hip/hip_runtime.h>
#include <math.h>

typedef __bf16 bf16x8 __attribute__((ext_vector_type(8)));
typedef __bf16 bf16x4 __attribute__((ext_vector_type(4)));
typedef float f32x4 __attribute__((ext_vector_type(4)));

__device__ __forceinline__ void gload_lds16(const __bf16* g, __bf16* l) {
  __builtin_amdgcn_global_load_lds((const __attribute__((address_space(1))) void*)g,
                                   (__attribute__((address_space(3))) void*)l, 16, 0, 0);
}

__device__ __forceinline__ float gelu_exact(float v) {
  return 0.5f * v * (1.f + erff(v * 0.70710678118654752f));
}

// ---------------- f32 -> bf16 convert ----------------
__global__ __launch_bounds__(256) void cvt_kernel(const float* __restrict__ in,
                                                  __bf16* __restrict__ out, int n) {
  const int stride = gridDim.x * 256 * 4;
  for (int i = (blockIdx.x * 256 + threadIdx.x) * 4; i < n; i += stride) {
    float4 v = *(const float4*)(in + i);
    bf16x4 o = {(__bf16)v.x, (__bf16)v.y, (__bf16)v.z, (__bf16)v.w};
    *(bf16x4*)(out + i) = o;
  }
}

// ---- src (i,b)-rows -> bf16 (b,i)-rows ----
__global__ __launch_bounds__(256) void cvt_perm_src(const float* __restrict__ in,
                                                    __bf16* __restrict__ out) {
  const int rp = blockIdx.x;            // b*1024 + i
  const int i = rp & 1023, b = rp >> 10;
  const float4 v = *(const float4*)(in + ((size_t)(i * 4 + b)) * 1024 + threadIdx.x * 4);
  bf16x4 o = {(__bf16)v.x, (__bf16)v.y, (__bf16)v.z, (__bf16)v.w};
  *(bf16x4*)(out + (size_t)rp * 1024 + threadIdx.x * 4) = o;
}

// ---------------- f32 [R][C] -> bf16 [C][R] transpose-convert ----------------
__global__ __launch_bounds__(256) void tcvt_kernel(const float* __restrict__ in,
                                                   __bf16* __restrict__ out, int R, int C) {
  __shared__ float t[32][33];
  const int c0 = blockIdx.x * 32, r0 = blockIdx.y * 32;
  for (int yy = threadIdx.y; yy < 32; yy += 8)
    t[yy][threadIdx.x] = in[(size_t)(r0 + yy) * C + c0 + threadIdx.x];
  __syncthreads();
  for (int yy = threadIdx.y; yy < 32; yy += 8)
    out[(size_t)(c0 + yy) * R + r0 + threadIdx.x] = (__bf16)t[threadIdx.x][yy];
}

// ---------------- bf16 MFMA GEMM: C[M,N] = A[M,K] * BT[N,K]^T ----------------
// MODE 0: f32 C.  MODE 1: bf16 C = gelu(acc + bias[col]).  MODE 2: bf16 C.
template<int BM, int BN, int MODE>
__global__ __launch_bounds__(256)
void gemm_bt(const __bf16* __restrict__ A, const __bf16* __restrict__ BT,
             float* __restrict__ Cf, __bf16* __restrict__ Cb,
             const float* __restrict__ bias, int M, int N, int K) {
  constexpr int BK = 32;
  constexpr int ALOAD = (BM * BK) / 2048;
  constexpr int BLOAD = (BN * BK) / 2048;
  __shared__ __align__(16) __bf16 lA[BM * BK];
  __shared__ __align__(16) __bf16 lB[BN * BK];
  const int tid = threadIdx.x;
  const int w = tid >> 6, l = tid & 63;
  const int lr = l & 15, lk = l >> 4;
  const int mBase = blockIdx.y * BM, nBase = blockIdx.x * BN;
  constexpr int WM = BM / 2, WN = BN / 2;
  constexpr int MF = WM / 16, NF = WN / 16;
  const int wr = w >> 1, wc = w & 1;
  f32x4 acc[MF][NF] = {};
  const int srow = tid >> 2;
  const int scol = (tid & 3) * 8;

  for (int k0 = 0; k0 < K; k0 += BK) {
#pragma unroll
    for (int i = 0; i < ALOAD; ++i) {
      int grow = mBase + srow + i * 64;
      grow = grow < M ? grow : M - 1;
      gload_lds16(A + (size_t)grow * K + k0 + scol, lA + i * 2048 + w * 512);
    }
#pragma unroll
    for (int i = 0; i < BLOAD; ++i) {
      int grow = nBase + srow + i * 64;
      gload_lds16(BT + (size_t)grow * K + k0 + scol, lB + i * 2048 + w * 512);
    }
    __syncthreads();
    bf16x8 af[MF], bfr[NF];
#pragma unroll
    for (int mi = 0; mi < MF; ++mi)
      af[mi] = *(const bf16x8*)&lA[(wr * WM + mi * 16 + lr) * BK + lk * 8];
#pragma unroll
    for (int nj = 0; nj < NF; ++nj)
      bfr[nj] = *(const bf16x8*)&lB[(wc * WN + nj * 16 + lr) * BK + lk * 8];
#pragma unroll
    for (int mi = 0; mi < MF; ++mi)
#pragma unroll
      for (int nj = 0; nj < NF; ++nj)
        acc[mi][nj] = __builtin_amdgcn_mfma_f32_16x16x32_bf16(af[mi], bfr[nj], acc[mi][nj], 0, 0, 0);
    __syncthreads();
  }
#pragma unroll
  for (int mi = 0; mi < MF; ++mi) {
#pragma unroll
    for (int nj = 0; nj < NF; ++nj) {
      const int col = nBase + wc * WN + nj * 16 + lr;
      const int row0 = mBase + wr * WM + mi * 16 + lk * 4;
#pragma unroll
      for (int j = 0; j < 4; ++j) {
        const int row = row0 + j;
        if (row < M) {
          float v = acc[mi][nj][j];
          if constexpr (MODE == 1) {
            v = gelu_exact(v + bias[col]);
            Cb[(size_t)row * N + col] = (__bf16)v;
          } else if constexpr (MODE == 2) {
            Cb[(size_t)row * N + col] = (__bf16)v;
          } else {
            Cf[(size_t)row * N + col] = v;
          }
        }
      }
    }
  }
}

// ---------------- MFMA rel-pos attention v4: no-max softmax, single KP buf ----------------
// qk  bf16 [4096 rows (b*1024+i)][2048] (q|k)
// vT  bf16 [1024 rows (n*64+d)][4096 cols (b*1024+j)]
// kpos bf16 [4100 rows (idx*4+b)][1024]
// av  bf16 rows (i*4+b)
// log2-domain scores: s = (q+rwb).k*A + GT[rrel&127][iln+(rrel>0)], A = 0.125*log2e
// P = exp2(s), Z deferred to epilogue.
__global__ __launch_bounds__(256)
void attn4(const __bf16* __restrict__ qk, const __bf16* __restrict__ vT,
           const __bf16* __restrict__ kpos, const float* __restrict__ rwbias,
           const float* __restrict__ rrbias, __bf16* __restrict__ av) {
  constexpr float ALPHA = 0.125f * 1.44269504088896f;
  __shared__ __align__(16) char smem[41216];
  __bf16* sK  = (__bf16*)(smem);          // [64][64] sw16; P-alias after ac
  __bf16* sVT = (__bf16*)(smem + 8192);   // [64][64] sw16 (rows=d, cols=j)
  __bf16* sKP = (__bf16*)(smem + 16384);  // [64][64] sw16 (this jt's new band rows)
  __bf16* sGT = (__bf16*)(smem + 24576);  // [128][65] ring: [col=rrel&127][grow 0..64]

  // XCD-chunked decode: all 16 it-blocks of one (b,n) on one XCD
  const int flat = blockIdx.x;
  const int xcd = flat & 7, rr_ = flat >> 3;
  const int bn = xcd * 8 + (rr_ >> 4);
  const int it = rr_ & 15;
  const int b = bn >> 4, n = bn & 15;
  const int i0 = it * 64;
  const int tid = threadIdx.x;
  const int l = tid & 63;
  const int lcol = l & 15, lk = l >> 4;
  const int strip = (tid >> 6) * 16;
  const int wbase = tid & 192;
  const int nh64 = n * 64;

  auto stageKP = [&](int rrel0) {
#pragma unroll
    for (int kq = 0; kq < 2; ++kq) {
      const int q = kq * 256 + tid;
      const int rL = q >> 3, cs = (q & 7) ^ (rL & 7);
      const int rrel = rrel0 + rL;
      const int idx = (rrel <= 0) ? (1024 + rrel) : (rrel - 1);
      gload_lds16(kpos + ((size_t)(idx * 4 + b)) * 1024 + nh64 + cs * 8,
                  sKP + (kq * 256 + wbase) * 8);
    }
  };
  bf16x8 qg[2];   // (q+rrb)*ALPHA frags (declared before lambda use)
  auto Gstep = [&](int rbase, int rrel0) {
    const int rowL = rbase + lcol;
    f32x4 g = {};
#pragma unroll
    for (int kk = 0; kk < 2; ++kk) {
      bf16x8 bv = *(const bf16x8*)&sKP[rowL * 64 + (((kk * 4 + lk) ^ (rowL & 7)) * 8)];
      g = __builtin_amdgcn_mfma_f32_16x16x32_bf16(qg[kk], bv, g, 0, 0, 0);
    }
    const int rc = (rrel0 + rowL + 2048) & 127;
#pragma unroll
    for (int jj = 0; jj < 4; ++jj)
      sGT[rc * 65 + strip + lk * 4 + jj] = (__bf16)g[jj];
  };

  // ---- prologue: stage Q (into sGT alias) + low KP half ----
  __bf16* qst = sGT;
  {
#pragma unroll
    for (int kq = 0; kq < 2; ++kq) {
      const int q = kq * 256 + tid;
      const int rL = q >> 3, cs = (q & 7) ^ (rL & 7);
      gload_lds16(qk + ((size_t)(b * 1024 + i0 + rL)) * 2048 + nh64 + cs * 8,
                  qst + (kq * 256 + wbase) * 8);
    }
  }
  stageKP(-i0 - 64);
  __syncthreads();
  bf16x8 qac[2];
#pragma unroll
  for (int kk = 0; kk < 2; ++kk) {
    const int rowq = strip + lcol;
    bf16x8 qv = *(const bf16x8*)&qst[rowq * 64 + (((kk * 4 + lk) ^ (rowq & 7)) * 8)];
    const int dbase = nh64 + kk * 32 + lk * 8;
#pragma unroll
    for (int u = 0; u < 8; ++u) {
      const float qf = (float)qv[u];
      qac[kk][u] = (__bf16)((qf + rwbias[dbase + u]) * ALPHA);
      qg[kk][u]  = (__bf16)((qf + rrbias[dbase + u]) * ALPHA);
    }
  }
  // q64 row in registers (16 elems per thread by part)
  const int part = tid & 3;
  bf16x8 q64a, q64b;
  {
    int gi64 = i0 + 64; gi64 = gi64 < 1024 ? gi64 : 1023;
    const __bf16* s = qk + ((size_t)(b * 1024 + gi64)) * 2048 + nh64 + part * 16;
#pragma unroll
    for (int u = 0; u < 8; ++u) {
      q64a[u] = (__bf16)(((float)s[u] + rrbias[nh64 + part * 16 + u]) * ALPHA);
      q64b[u] = (__bf16)(((float)s[u + 8] + rrbias[nh64 + part * 16 + 8 + u]) * ALPHA);
    }
  }
  __syncthreads();   // qst reads done -> sGT free
  // low half of the band: rrel in [-i0-64, -i0)
#pragma unroll
  for (int fg = 0; fg < 4; ++fg) Gstep(fg * 16, -i0 - 64);

  float zacc[4] = {0.f, 0.f, 0.f, 0.f};
  f32x4 oacc[4] = {};

#pragma unroll 1
  for (int jt = 0; jt < 16; ++jt) {
    const int j0 = jt * 64;
    const int d0 = j0 - i0;
    __syncthreads();   // B1: prev gather/PV reads + prologue G writes ordered
    // stage K, VT, new KP rows
#pragma unroll
    for (int kq = 0; kq < 2; ++kq) {
      const int q = kq * 256 + tid;
      const int r = q >> 3, cs = (q & 7) ^ (r & 7);
      gload_lds16(qk + ((size_t)(b * 1024 + j0 + r)) * 2048 + 1024 + nh64 + cs * 8,
                  sK + (kq * 256 + wbase) * 8);
      gload_lds16(vT + ((size_t)(nh64 + r)) * 4096 + b * 1024 + j0 + cs * 8,
                  sVT + (kq * 256 + wbase) * 8);
    }
    stageKP(d0);
    __syncthreads();   // B2: staged visible
    // G MFMA: new 64 band cols
#pragma unroll
    for (int fg = 0; fg < 4; ++fg) Gstep(fg * 16, d0);
    // ac MFMA
    f32x4 sc[4];
#pragma unroll
    for (int fj = 0; fj < 4; ++fj) {
      const int row = fj * 16 + lcol;
      f32x4 a = {};
#pragma unroll
      for (int kk = 0; kk < 2; ++kk) {
        bf16x8 bv = *(const bf16x8*)&sK[row * 64 + (((kk * 4 + lk) ^ (row & 7)) * 8)];
        a = __builtin_amdgcn_mfma_f32_16x16x32_bf16(qac[kk], bv, a, 0, 0, 0);
      }
      sc[fj] = a;
    }
    // G64: row i0+64, 4 lanes per col
    {
      const int cl = tid >> 2;
      const int sw = cl & 7;
      bf16x8 kv0 = *(const bf16x8*)&sKP[cl * 64 + (((2 * part) ^ sw) * 8)];
      bf16x8 kv1 = *(const bf16x8*)&sKP[cl * 64 + (((2 * part + 1) ^ sw) * 8)];
      float s64 = 0.f;
#pragma unroll
      for (int u = 0; u < 8; ++u)
        s64 += (float)q64a[u] * (float)kv0[u] + (float)q64b[u] * (float)kv1[u];
      s64 += __shfl_xor(s64, 1, 64);
      s64 += __shfl_xor(s64, 2, 64);
      if (part == 0) sGT[((d0 + cl + 2048) & 127) * 65 + 64] = (__bf16)s64;
    }
    __syncthreads();   // B3: G/G64 visible; sK free for P
    // gather + exp2 + P-store (no max, no rescale)
#pragma unroll
    for (int fj = 0; fj < 4; ++fj) {
      const int j_loc = fj * 16 + lcol;
#pragma unroll
      for (int jj = 0; jj < 4; ++jj) {
        const int iln = strip + lk * 4 + jj;
        const int rrel = d0 + j_loc - iln;
        const int col = (rrel + 2048) & 127;
        const int grow = iln + (rrel > 0 ? 1 : 0);
        const float e = exp2f(sc[fj][jj] + (float)sGT[col * 65 + grow]);
        zacc[jj] += e;
        sK[iln * 64 + ((((j_loc * 2) ^ ((iln & 7) << 4))) >> 1)] = (__bf16)e;
      }
    }
    // PV MFMA (own-wave P rows)
#pragma unroll
    for (int kk = 0; kk < 2; ++kk) {
      const int prow = strip + lcol;
      bf16x8 pa = *(const bf16x8*)&sK[prow * 64 + (((kk * 4 + lk) ^ (prow & 7)) * 8)];
#pragma unroll
      for (int fd = 0; fd < 4; ++fd) {
        const int vrow = fd * 16 + lcol;
        bf16x8 bv = *(const bf16x8*)&sVT[vrow * 64 + (((kk * 4 + lk) ^ (vrow & 7)) * 8)];
        oacc[fd] = __builtin_amdgcn_mfma_f32_16x16x32_bf16(pa, bv, oacc[fd], 0, 0, 0);
      }
    }
  }
  // ---- epilogue: reduce Z across the 16 lcol lanes, normalize, store ----
#pragma unroll
  for (int jj = 0; jj < 4; ++jj) {
    float z = zacc[jj];
#pragma unroll
    for (int o = 1; o <= 8; o <<= 1) z += __shfl_xor(z, o, 16);
    const float rz = 1.f / z;
    const int ig = i0 + strip + lk * 4 + jj;
    __bf16* dst = av + ((size_t)(ig * 4 + b)) * 1024 + nh64;
#pragma unroll
    for (int fd = 0; fd < 4; ++fd)
      dst[fd * 16 + lcol] = (__bf16)(oacc[fd][jj] * rz);
  }
}

// ---------------- fused residual + LayerNorm ----------------
__global__ __launch_bounds__(256)
void ln_fuse(const float* __restrict__ A, const float* __restrict__ Bv,
             const float* __restrict__ cb, const float* __restrict__ g,
             const float* __restrict__ be, float* __restrict__ oF,
             __bf16* __restrict__ oB) {
  const int row = blockIdx.x, t = threadIdx.x;
  const size_t base = (size_t)row * 1024 + t * 4;
  const float4 a = *(const float4*)(A + base);
  const float4 bb = *(const float4*)(Bv + base);
  float x0 = a.x + bb.x, x1 = a.y + bb.y, x2 = a.z + bb.z, x3 = a.w + bb.w;
  if (cb) {
    const float4 c = *(const float4*)(cb + t * 4);
    x0 += c.x; x1 += c.y; x2 += c.z; x3 += c.w;
  }
  float s = x0 + x1 + x2 + x3;
  float q = x0 * x0 + x1 * x1 + x2 * x2 + x3 * x3;
#pragma unroll
  for (int o = 1; o < 64; o <<= 1) { s += __shfl_xor(s, o, 64); q += __shfl_xor(q, o, 64); }
  __shared__ float ss[4], qq[4];
  if ((t & 63) == 0) { ss[t >> 6] = s; qq[t >> 6] = q; }
  __syncthreads();
  s = ss[0] + ss[1] + ss[2] + ss[3];
  q = qq[0] + qq[1] + qq[2] + qq[3];
  const float mean = s * (1.f / 1024.f);
  const float var = q * (1.f / 1024.f) - mean * mean;
  const float rstd = rsqrtf(var + 1e-5f);
  const float4 gv = *(const float4*)(g + t * 4);
  const float4 bev = *(const float4*)(be + t * 4);
  const float y0 = (x0 - mean) * rstd * gv.x + bev.x;
  const float y1 = (x1 - mean) * rstd * gv.y + bev.y;
  const float y2 = (x2 - mean) * rstd * gv.z + bev.z;
  const float y3 = (x3 - mean) * rstd * gv.w + bev.w;
  float4 r = {y0, y1, y2, y3};
  *(float4*)(oF + base) = r;
  if (oB) {
    bf16x4 o4 = {(__bf16)y0, (__bf16)y1, (__bf16)y2, (__bf16)y3};
    *(bf16x4*)(oB + base) = o4;
  }
}

extern "C" void kernel_launch(void* const* d_in, const int* in_sizes, int n_in,
                              void* d_out, int out_size, void* d_ws, size_t ws_size,
                              hipStream_t stream) {
  const float* src    = (const float*)d_in[0];
  const float* pos    = (const float*)d_in[1];
  const float* qw     = (const float*)d_in[3];
  const float* kw     = (const float*)d_in[4];
  const float* vw     = (const float*)d_in[5];
  const float* rw     = (const float*)d_in[6];
  const float* ow     = (const float*)d_in[7];
  const float* rwbias = (const float*)d_in[8];
  const float* rrbias = (const float*)d_in[9];
  const float* w1     = (const float*)d_in[10];
  const float* b1     = (const float*)d_in[11];
  const float* w2     = (const float*)d_in[12];
  const float* b2     = (const float*)d_in[13];
  const float* g1     = (const float*)d_in[14];
  const float* be1    = (const float*)d_in[15];
  const float* g2     = (const float*)d_in[16];
  const float* be2    = (const float*)d_in[17];
  float* out = (float*)d_out;

  char* p = (char*)d_ws;
  auto alloc = [&](size_t bytes) { char* r = p; p += (bytes + 255) & ~(size_t)255; return r; };
  __bf16* srcB2 = (__bf16*)alloc(4096ull * 1024 * 2);   // (b,i)-rows
  __bf16* posB  = (__bf16*)alloc(4100ull * 1024 * 2);
  __bf16* qkvT  = (__bf16*)alloc(3072ull * 1024 * 2);   // qw^T|kw^T|vw^T
  __bf16* rwT   = (__bf16*)alloc(1024ull * 1024 * 2);
  __bf16* owB   = (__bf16*)alloc(1024ull * 1024 * 2);
  __bf16* w1B   = (__bf16*)alloc(4096ull * 1024 * 2);
  __bf16* w2B   = (__bf16*)alloc(4096ull * 1024 * 2);
  __bf16* qkB   = (__bf16*)alloc(4096ull * 2048 * 2);   // dead after attn
  __bf16* vTB   = (__bf16*)alloc(1024ull * 4096 * 2);   // dead after attn
  __bf16* kposB = (__bf16*)alloc(4100ull * 1024 * 2);   // dead after attn
  __bf16* avB   = (__bf16*)alloc(4096ull * 1024 * 2);
  float*  xF    = (float*)alloc(4096ull * 1024 * 4);
  __bf16* xB    = (__bf16*)alloc(4096ull * 1024 * 2);
  // aliases (disjoint lifetimes):
  float*  aoF = (float*)srcB2;   // attn-out f32 16MB over srcB2+posB
  __bf16* gB  = (__bf16*)qkB;    // gelu bf16 32MB over qkB+vTB+kposB
  float*  ffF = (float*)srcB2;   // ffn2 f32 (aoF dead after LN1)

  cvt_perm_src<<<4096, 256, 0, stream>>>(src, srcB2);
  cvt_kernel<<<2048, 256, 0, stream>>>(pos, posB, 4100 * 1024);
  cvt_kernel<<<1024, 256, 0, stream>>>(ow, owB, 1024 * 1024);
  cvt_kernel<<<2048, 256, 0, stream>>>(w1, w1B, 4096 * 1024);
  cvt_kernel<<<2048, 256, 0, stream>>>(w2, w2B, 4096 * 1024);
  dim3 tb(32, 8);
  tcvt_kernel<<<dim3(32, 32), tb, 0, stream>>>(qw, qkvT, 1024, 1024);
  tcvt_kernel<<<dim3(32, 32), tb, 0, stream>>>(kw, qkvT + 1024 * 1024, 1024, 1024);
  tcvt_kernel<<<dim3(32, 32), tb, 0, stream>>>(vw, qkvT + 2048 * 1024, 1024, 1024);
  tcvt_kernel<<<dim3(32, 32), tb, 0, stream>>>(rw, rwT, 1024, 1024);
  // projections
  gemm_bt<128, 128, 2><<<dim3(16, 32), 256, 0, stream>>>(srcB2, qkvT, nullptr, qkB, nullptr, 4096, 2048, 1024);
  gemm_bt<128, 64, 2><<<dim3(64, 8), 256, 0, stream>>>(qkvT + 2048 * 1024, srcB2, nullptr, vTB, nullptr, 1024, 4096, 1024);
  gemm_bt<128, 64, 2><<<dim3(16, 33), 256, 0, stream>>>(posB, rwT, nullptr, kposB, nullptr, 4100, 1024, 1024);
  attn4<<<dim3(1024), 256, 0, stream>>>(qkB, vTB, kposB, rwbias, rrbias, avB);
  gemm_bt<128, 64, 0><<<dim3(16, 32), 256, 0, stream>>>(avB, owB, aoF, nullptr, nullptr, 4096, 1024, 1024);
  ln_fuse<<<4096, 256, 0, stream>>>(src, aoF, nullptr, g1, be1, xF, xB);
  gemm_bt<128, 128, 1><<<dim3(32, 32), 256, 0, stream>>>(xB, w1B, nullptr, gB, b1, 4096, 4096, 1024);
  gemm_bt<128, 64, 0><<<dim3(16, 32), 256, 0, stream>>>(gB, w2B, ffF, nullptr, nullptr, 4096, 1024, 4096);
  ln_fuse<<<4096, 256, 0, stream>>>(xF, ffF, b2, g2, be2, out, nullptr);
  (void)in_sizes; (void)n_in; (void)out_size; (void)ws_size;
}

// Round 5
// 390.730 us; speedup vs baseline: 3.6390x; 1.1023x over previous
//
#include <hip/hip_runtime.h>
#include <math.h>

typedef __bf16 bf16x8 __attribute__((ext_vector_type(8)));
typedef __bf16 bf16x4 __attribute__((ext_vector_type(4)));
typedef float f32x4 __attribute__((ext_vector_type(4)));

__device__ __forceinline__ void gload_lds16(const __bf16* g, __bf16* l) {
  __builtin_amdgcn_global_load_lds((const __attribute__((address_space(1))) void*)g,
                                   (__attribute__((address_space(3))) void*)l, 16, 0, 0);
}

__device__ __forceinline__ float gelu_exact(float v) {
  return 0.5f * v * (1.f + erff(v * 0.70710678118654752f));
}

// ---- src (i,b)-rows -> bf16 (b,i)-rows ----
__global__ __launch_bounds__(256) void cvt_perm_src(const float* __restrict__ in,
                                                    __bf16* __restrict__ out) {
  const int rp = blockIdx.x;            // b*1024 + i
  const int i = rp & 1023, b = rp >> 10;
  const float4 v = *(const float4*)(in + ((size_t)(i * 4 + b)) * 1024 + threadIdx.x * 4);
  bf16x4 o = {(__bf16)v.x, (__bf16)v.y, (__bf16)v.z, (__bf16)v.w};
  *(bf16x4*)(out + (size_t)rp * 1024 + threadIdx.x * 4) = o;
}

// ---- fused 4-segment f32->bf16 convert; each block = 4096 elems ----
__global__ __launch_bounds__(256) void cvt4_kernel(
    const float* __restrict__ i0, __bf16* __restrict__ o0, int b0,
    const float* __restrict__ i1, __bf16* __restrict__ o1, int b1,
    const float* __restrict__ i2, __bf16* __restrict__ o2, int b2,
    const float* __restrict__ i3, __bf16* __restrict__ o3) {
  int bid = blockIdx.x;
  const float* in; __bf16* out;
  if (bid < b0) { in = i0; out = o0; }
  else if ((bid -= b0) < b1) { in = i1; out = o1; }
  else if ((bid -= b1) < b2) { in = i2; out = o2; }
  else { bid -= b2; in = i3; out = o3; }
  const int base = bid * 4096 + threadIdx.x * 4;
#pragma unroll
  for (int k = 0; k < 4; ++k) {
    const int off = base + k * 1024;
    float4 v = *(const float4*)(in + off);
    bf16x4 o = {(__bf16)v.x, (__bf16)v.y, (__bf16)v.z, (__bf16)v.w};
    *(bf16x4*)(out + off) = o;
  }
}

// ---- fused transpose-convert for the 4 weight matrices (all 1024x1024) ----
__global__ __launch_bounds__(256) void tcvt4_kernel(
    const float* __restrict__ q, const float* __restrict__ k,
    const float* __restrict__ v, const float* __restrict__ r,
    __bf16* __restrict__ oq, __bf16* __restrict__ ok,
    __bf16* __restrict__ ov, __bf16* __restrict__ orr) {
  const float* in; __bf16* out;
  switch (blockIdx.z) {
    case 0: in = q; out = oq; break;
    case 1: in = k; out = ok; break;
    case 2: in = v; out = ov; break;
    default: in = r; out = orr; break;
  }
  __shared__ float t[32][33];
  const int c0 = blockIdx.x * 32, r0 = blockIdx.y * 32;
  for (int yy = threadIdx.y; yy < 32; yy += 8)
    t[yy][threadIdx.x] = in[(size_t)(r0 + yy) * 1024 + c0 + threadIdx.x];
  __syncthreads();
  for (int yy = threadIdx.y; yy < 32; yy += 8)
    out[(size_t)(c0 + yy) * 1024 + r0 + threadIdx.x] = (__bf16)t[threadIdx.x][yy];
}

// ---------------- bf16 MFMA GEMM: C[M,N] = A[M,K] * BT[N,K]^T ----------------
// MODE 0: f32 C.  MODE 1: bf16 C = gelu(acc + bias[col]).  MODE 2: bf16 C.
template<int BM, int BN, int MODE>
__global__ __launch_bounds__(256)
void gemm_bt(const __bf16* __restrict__ A, const __bf16* __restrict__ BT,
             float* __restrict__ Cf, __bf16* __restrict__ Cb,
             const float* __restrict__ bias, int M, int N, int K) {
  constexpr int BK = 32;
  constexpr int ALOAD = (BM * BK) / 2048;
  constexpr int BLOAD = (BN * BK) / 2048;
  __shared__ __align__(16) __bf16 lA[BM * BK];
  __shared__ __align__(16) __bf16 lB[BN * BK];
  const int tid = threadIdx.x;
  const int w = tid >> 6, l = tid & 63;
  const int lr = l & 15, lk = l >> 4;
  const int mBase = blockIdx.y * BM, nBase = blockIdx.x * BN;
  constexpr int WM = BM / 2, WN = BN / 2;
  constexpr int MF = WM / 16, NF = WN / 16;
  const int wr = w >> 1, wc = w & 1;
  f32x4 acc[MF][NF] = {};
  const int srow = tid >> 2;
  const int scol = (tid & 3) * 8;

  for (int k0 = 0; k0 < K; k0 += BK) {
#pragma unroll
    for (int i = 0; i < ALOAD; ++i) {
      int grow = mBase + srow + i * 64;
      grow = grow < M ? grow : M - 1;
      gload_lds16(A + (size_t)grow * K + k0 + scol, lA + i * 2048 + w * 512);
    }
#pragma unroll
    for (int i = 0; i < BLOAD; ++i) {
      int grow = nBase + srow + i * 64;
      gload_lds16(BT + (size_t)grow * K + k0 + scol, lB + i * 2048 + w * 512);
    }
    __syncthreads();
    bf16x8 af[MF], bfr[NF];
#pragma unroll
    for (int mi = 0; mi < MF; ++mi)
      af[mi] = *(const bf16x8*)&lA[(wr * WM + mi * 16 + lr) * BK + lk * 8];
#pragma unroll
    for (int nj = 0; nj < NF; ++nj)
      bfr[nj] = *(const bf16x8*)&lB[(wc * WN + nj * 16 + lr) * BK + lk * 8];
#pragma unroll
    for (int mi = 0; mi < MF; ++mi)
#pragma unroll
      for (int nj = 0; nj < NF; ++nj)
        acc[mi][nj] = __builtin_amdgcn_mfma_f32_16x16x32_bf16(af[mi], bfr[nj], acc[mi][nj], 0, 0, 0);
    __syncthreads();
  }
#pragma unroll
  for (int mi = 0; mi < MF; ++mi) {
#pragma unroll
    for (int nj = 0; nj < NF; ++nj) {
      const int col = nBase + wc * WN + nj * 16 + lr;
      const int row0 = mBase + wr * WM + mi * 16 + lk * 4;
#pragma unroll
      for (int j = 0; j < 4; ++j) {
        const int row = row0 + j;
        if (row < M) {
          float v = acc[mi][nj][j];
          if constexpr (MODE == 1) {
            v = gelu_exact(v + bias[col]);
            Cb[(size_t)row * N + col] = (__bf16)v;
          } else if constexpr (MODE == 2) {
            Cb[(size_t)row * N + col] = (__bf16)v;
          } else {
            Cf[(size_t)row * N + col] = v;
          }
        }
      }
    }
  }
}

// ---------------- MFMA rel-pos attention v5: scatter-G + pipelined staging ----------------
// qk  bf16 [4096 rows (b*1024+i)][2048] (q|k)
// vT  bf16 [1024 rows (n*64+d)][4096 cols (b*1024+j)]
// kpos bf16 [4100 rows (idx*4+b)][1024]
// av  bf16 rows (i*4+b)
// s = (q+rwb).k*A + bd, A = 0.125*log2e; P = exp2(s), Z deferred to epilogue.
// bd element (grow,rrel) scattered into slot (iln = grow-(rrel>0), jl = rrel-d0+iln)
// of the ping-pong sbd tile; slot row = jl ^ ((jt&1)<<6).
__global__ __launch_bounds__(256)
void attn5(const __bf16* __restrict__ qk, const __bf16* __restrict__ vT,
           const __bf16* __restrict__ kpos, const float* __restrict__ rwbias,
           const float* __restrict__ rrbias, __bf16* __restrict__ av) {
  constexpr float ALPHA = 0.125f * 1.44269504088896f;
  // layout: K dbuf 2x8K | KP dbuf 2x8K | VT 8K | sbd [128][72] 18KB
  __shared__ __align__(16) char smem[59392];
  __bf16* sVT = (__bf16*)(smem + 32768);
  __bf16* sbd = (__bf16*)(smem + 40960);

  const int flat = blockIdx.x;
  const int xcd = flat & 7, rr_ = flat >> 3;
  const int bn = xcd * 8 + (rr_ >> 4);
  const int it = rr_ & 15;
  const int b = bn >> 4, n = bn & 15;
  const int i0 = it * 64;
  const int tid = threadIdx.x;
  const int l = tid & 63;
  const int lcol = l & 15, lk = l >> 4;
  const int strip = (tid >> 6) * 16;
  const int wbase = tid & 192;
  const int nh64 = n * 64;
  const int part = tid & 3;

  // ---- q fragments direct from global, bias+scale folded ----
  bf16x8 qac[2], qg[2];
  {
    const __bf16* qrow = qk + ((size_t)(b * 1024 + i0 + strip + lcol)) * 2048 + nh64;
#pragma unroll
    for (int kk = 0; kk < 2; ++kk) {
      bf16x8 qv = *(const bf16x8*)(qrow + kk * 32 + lk * 8);
      const int dbase = nh64 + kk * 32 + lk * 8;
#pragma unroll
      for (int u = 0; u < 8; ++u) {
        const float qf = (float)qv[u];
        qac[kk][u] = (__bf16)((qf + rwbias[dbase + u]) * ALPHA);
        qg[kk][u]  = (__bf16)((qf + rrbias[dbase + u]) * ALPHA);
      }
    }
  }
  bf16x8 q64a, q64b;
  {
    int gi64 = i0 + 64; gi64 = gi64 < 1024 ? gi64 : 1023;
    const __bf16* s = qk + ((size_t)(b * 1024 + gi64)) * 2048 + nh64 + part * 16;
    bf16x8 v0 = *(const bf16x8*)s;
    bf16x8 v1 = *(const bf16x8*)(s + 8);
#pragma unroll
    for (int u = 0; u < 8; ++u) {
      q64a[u] = (__bf16)(((float)v0[u] + rrbias[nh64 + part * 16 + u]) * ALPHA);
      q64b[u] = (__bf16)(((float)v1[u] + rrbias[nh64 + part * 16 + 8 + u]) * ALPHA);
    }
  }

  // ---- prologue staging: low band -> sVT, jt0 K -> Kbuf0, jt0 band -> KPbuf0 ----
#pragma unroll
  for (int kq = 0; kq < 2; ++kq) {
    const int q = kq * 256 + tid;
    const int r = q >> 3, cs = (q & 7) ^ (r & 7);
    const int dst = (kq * 256 + wbase) * 8;
    // low band: rrel = -i0-64+r -> idx = 960-i0+r (always <=0 path)
    gload_lds16(kpos + ((size_t)((960 - i0 + r) * 4 + b)) * 1024 + nh64 + cs * 8, sVT + dst);
    gload_lds16(qk + ((size_t)(b * 1024 + r)) * 2048 + 1024 + nh64 + cs * 8,
                (__bf16*)(smem) + dst);
    const int rrel = r - i0;
    const int idx = (rrel <= 0) ? (1024 + rrel) : (rrel - 1);
    gload_lds16(kpos + ((size_t)(idx * 4 + b)) * 1024 + nh64 + cs * 8,
                (__bf16*)(smem + 16384) + dst);
  }
  __syncthreads();
  // prologue G on the low band (rrel in [-i0-64,-i0), all <=0): scatter jl in [0,64)
#pragma unroll
  for (int fg = 0; fg < 4; ++fg) {
    const int rowL = fg * 16 + lcol;
    f32x4 g = {};
#pragma unroll
    for (int kk = 0; kk < 2; ++kk) {
      bf16x8 bv = *(const bf16x8*)&sVT[rowL * 64 + (((kk * 4 + lk) ^ (rowL & 7)) * 8)];
      g = __builtin_amdgcn_mfma_f32_16x16x32_bf16(qg[kk], bv, g, 0, 0, 0);
    }
#pragma unroll
    for (int jj = 0; jj < 4; ++jj) {
      const int iln = strip + lk * 4 + jj;
      const int jl = rowL - 64 + iln;
      if (jl >= 0) sbd[jl * 72 + iln] = (__bf16)g[jj];
    }
  }
  __syncthreads();

  float zacc[4] = {0.f, 0.f, 0.f, 0.f};
  f32x4 oacc[4] = {};

#pragma unroll 1
  for (int jt = 0; jt < 16; ++jt) {
    const int cur = jt & 1, nxt = cur ^ 1;
    const int d0 = jt * 64 - i0;
    const int jxor = cur << 6;
    __bf16* sK   = (__bf16*)(smem + cur * 8192);
    __bf16* sKn  = (__bf16*)(smem + nxt * 8192);
    __bf16* sKP  = (__bf16*)(smem + 16384 + cur * 8192);
    __bf16* sKPn = (__bf16*)(smem + 16384 + nxt * 8192);
    // ---- issue staging: VT for THIS jt; K/KP for jt+1 ----
    {
      const int j0n = (jt + 1) * 64;
#pragma unroll
      for (int kq = 0; kq < 2; ++kq) {
        const int q = kq * 256 + tid;
        const int r = q >> 3, cs = (q & 7) ^ (r & 7);
        const int dst = (kq * 256 + wbase) * 8;
        gload_lds16(vT + ((size_t)(nh64 + r)) * 4096 + b * 1024 + jt * 64 + cs * 8, sVT + dst);
        int krow = j0n + r; krow = krow < 1024 ? krow : 1023;
        gload_lds16(qk + ((size_t)(b * 1024 + krow)) * 2048 + 1024 + nh64 + cs * 8, sKn + dst);
        const int rreln = j0n - i0 + r;
        int idx = (rreln <= 0) ? (1024 + rreln) : (rreln - 1);
        idx = idx < 1024 ? idx : 1024;
        gload_lds16(kpos + ((size_t)(idx * 4 + b)) * 1024 + nh64 + cs * 8, sKPn + dst);
      }
    }
    // ---- G MFMA on this jt's band + scatter ----
#pragma unroll
    for (int fg = 0; fg < 4; ++fg) {
      const int rowL = fg * 16 + lcol;
      f32x4 g = {};
#pragma unroll
      for (int kk = 0; kk < 2; ++kk) {
        bf16x8 bv = *(const bf16x8*)&sKP[rowL * 64 + (((kk * 4 + lk) ^ (rowL & 7)) * 8)];
        g = __builtin_amdgcn_mfma_f32_16x16x32_bf16(qg[kk], bv, g, 0, 0, 0);
      }
      const int pos = (d0 + rowL) > 0 ? 1 : 0;
#pragma unroll
      for (int jj = 0; jj < 4; ++jj) {
        const int iln = strip + lk * 4 + jj - pos;
        if (iln >= 0) {
          const int jl = rowL + iln;
          sbd[(jl ^ jxor) * 72 + iln] = (__bf16)g[jj];
        }
      }
    }
    // ---- G64 (q-row i0+64, rrel>0 slots at iln=63) ----
    {
      const int cl = tid >> 2;
      const int sw = cl & 7;
      bf16x8 kv0 = *(const bf16x8*)&sKP[cl * 64 + (((2 * part) ^ sw) * 8)];
      bf16x8 kv1 = *(const bf16x8*)&sKP[cl * 64 + (((2 * part + 1) ^ sw) * 8)];
      float s64 = 0.f;
#pragma unroll
      for (int u = 0; u < 8; ++u)
        s64 += (float)q64a[u] * (float)kv0[u] + (float)q64b[u] * (float)kv1[u];
      s64 += __shfl_xor(s64, 1, 64);
      s64 += __shfl_xor(s64, 2, 64);
      if (part == 0 && (d0 + cl) > 0) {
        const int jl = cl + 63;
        sbd[(jl ^ jxor) * 72 + 63] = (__bf16)s64;
      }
    }
    // ---- ac MFMA ----
    f32x4 sc[4];
#pragma unroll
    for (int fj = 0; fj < 4; ++fj) {
      const int row = fj * 16 + lcol;
      f32x4 a = {};
#pragma unroll
      for (int kk = 0; kk < 2; ++kk) {
        bf16x8 bv = *(const bf16x8*)&sK[row * 64 + (((kk * 4 + lk) ^ (row & 7)) * 8)];
        a = __builtin_amdgcn_mfma_f32_16x16x32_bf16(qac[kk], bv, a, 0, 0, 0);
      }
      sc[fj] = a;
    }
    __syncthreads();   // scatter + staged VT visible; sK free for P
    // ---- vector gather + exp2 + P store ----
#pragma unroll
    for (int fj = 0; fj < 4; ++fj) {
      const int jlr = fj * 16 + lcol;
      bf16x4 gg = *(const bf16x4*)&sbd[(jlr ^ jxor) * 72 + strip + lk * 4];
#pragma unroll
      for (int jj = 0; jj < 4; ++jj) {
        const int iln = strip + lk * 4 + jj;
        const float e = exp2f(sc[fj][jj] + (float)gg[jj]);
        zacc[jj] += e;
        sK[iln * 64 + ((((jlr * 2) ^ ((iln & 7) << 4))) >> 1)] = (__bf16)e;
      }
    }
    // ---- PV MFMA (own-wave P rows; same-wave DS ordering) ----
#pragma unroll
    for (int kk = 0; kk < 2; ++kk) {
      const int prow = strip + lcol;
      bf16x8 pa = *(const bf16x8*)&sK[prow * 64 + (((kk * 4 + lk) ^ (prow & 7)) * 8)];
#pragma unroll
      for (int fd = 0; fd < 4; ++fd) {
        const int vrow = fd * 16 + lcol;
        bf16x8 bv = *(const bf16x8*)&sVT[vrow * 64 + (((kk * 4 + lk) ^ (vrow & 7)) * 8)];
        oacc[fd] = __builtin_amdgcn_mfma_f32_16x16x32_bf16(pa, bv, oacc[fd], 0, 0, 0);
      }
    }
    __syncthreads();   // all reads of cur buffers done before next-iter staging
  }
  // ---- epilogue: reduce Z over the 16 lcol lanes, normalize, store ----
#pragma unroll
  for (int jj = 0; jj < 4; ++jj) {
    float z = zacc[jj];
#pragma unroll
    for (int o = 1; o <= 8; o <<= 1) z += __shfl_xor(z, o, 16);
    const float rz = 1.f / z;
    const int ig = i0 + strip + lk * 4 + jj;
    __bf16* dst = av + ((size_t)(ig * 4 + b)) * 1024 + nh64;
#pragma unroll
    for (int fd = 0; fd < 4; ++fd)
      dst[fd * 16 + lcol] = (__bf16)(oacc[fd][jj] * rz);
  }
}

// ---------------- fused residual + LayerNorm ----------------
__global__ __launch_bounds__(256)
void ln_fuse(const float* __restrict__ A, const float* __restrict__ Bv,
             const float* __restrict__ cb, const float* __restrict__ g,
             const float* __restrict__ be, float* __restrict__ oF,
             __bf16* __restrict__ oB) {
  const int row = blockIdx.x, t = threadIdx.x;
  const size_t base = (size_t)row * 1024 + t * 4;
  const float4 a = *(const float4*)(A + base);
  const float4 bb = *(const float4*)(Bv + base);
  float x0 = a.x + bb.x, x1 = a.y + bb.y, x2 = a.z + bb.z, x3 = a.w + bb.w;
  if (cb) {
    const float4 c = *(const float4*)(cb + t * 4);
    x0 += c.x; x1 += c.y; x2 += c.z; x3 += c.w;
  }
  float s = x0 + x1 + x2 + x3;
  float q = x0 * x0 + x1 * x1 + x2 * x2 + x3 * x3;
#pragma unroll
  for (int o = 1; o < 64; o <<= 1) { s += __shfl_xor(s, o, 64); q += __shfl_xor(q, o, 64); }
  __shared__ float ss[4], qq[4];
  if ((t & 63) == 0) { ss[t >> 6] = s; qq[t >> 6] = q; }
  __syncthreads();
  s = ss[0] + ss[1] + ss[2] + ss[3];
  q = qq[0] + qq[1] + qq[2] + qq[3];
  const float mean = s * (1.f / 1024.f);
  const float var = q * (1.f / 1024.f) - mean * mean;
  const float rstd = rsqrtf(var + 1e-5f);
  const float4 gv = *(const float4*)(g + t * 4);
  const float4 bev = *(const float4*)(be + t * 4);
  const float y0 = (x0 - mean) * rstd * gv.x + bev.x;
  const float y1 = (x1 - mean) * rstd * gv.y + bev.y;
  const float y2 = (x2 - mean) * rstd * gv.z + bev.z;
  const float y3 = (x3 - mean) * rstd * gv.w + bev.w;
  float4 r = {y0, y1, y2, y3};
  *(float4*)(oF + base) = r;
  if (oB) {
    bf16x4 o4 = {(__bf16)y0, (__bf16)y1, (__bf16)y2, (__bf16)y3};
    *(bf16x4*)(oB + base) = o4;
  }
}

extern "C" void kernel_launch(void* const* d_in, const int* in_sizes, int n_in,
                              void* d_out, int out_size, void* d_ws, size_t ws_size,
                              hipStream_t stream) {
  const float* src    = (const float*)d_in[0];
  const float* pos    = (const float*)d_in[1];
  const float* qw     = (const float*)d_in[3];
  const float* kw     = (const float*)d_in[4];
  const float* vw     = (const float*)d_in[5];
  const float* rw     = (const float*)d_in[6];
  const float* ow     = (const float*)d_in[7];
  const float* rwbias = (const float*)d_in[8];
  const float* rrbias = (const float*)d_in[9];
  const float* w1     = (const float*)d_in[10];
  const float* b1     = (const float*)d_in[11];
  const float* w2     = (const float*)d_in[12];
  const float* b2     = (const float*)d_in[13];
  const float* g1     = (const float*)d_in[14];
  const float* be1    = (const float*)d_in[15];
  const float* g2     = (const float*)d_in[16];
  const float* be2    = (const float*)d_in[17];
  float* out = (float*)d_out;

  char* p = (char*)d_ws;
  auto alloc = [&](size_t bytes) { char* r = p; p += (bytes + 255) & ~(size_t)255; return r; };
  __bf16* srcB2 = (__bf16*)alloc(4096ull * 1024 * 2);   // (b,i)-rows
  __bf16* posB  = (__bf16*)alloc(4100ull * 1024 * 2);
  __bf16* qkvT  = (__bf16*)alloc(3072ull * 1024 * 2);   // qw^T|kw^T|vw^T
  __bf16* rwT   = (__bf16*)alloc(1024ull * 1024 * 2);
  __bf16* owB   = (__bf16*)alloc(1024ull * 1024 * 2);
  __bf16* w1B   = (__bf16*)alloc(4096ull * 1024 * 2);
  __bf16* w2B   = (__bf16*)alloc(4096ull * 1024 * 2);
  __bf16* qkB   = (__bf16*)alloc(4096ull * 2048 * 2);   // dead after attn
  __bf16* vTB   = (__bf16*)alloc(1024ull * 4096 * 2);   // dead after attn
  __bf16* kposB = (__bf16*)alloc(4100ull * 1024 * 2);   // dead after attn
  __bf16* avB   = (__bf16*)alloc(4096ull * 1024 * 2);
  float*  xF    = (float*)alloc(4096ull * 1024 * 4);
  __bf16* xB    = (__bf16*)alloc(4096ull * 1024 * 2);
  // aliases (disjoint lifetimes):
  float*  aoF = (float*)srcB2;   // attn-out f32 16MB over srcB2+posB
  __bf16* gB  = (__bf16*)qkB;    // gelu bf16 32MB over qkB+vTB+kposB
  float*  ffF = (float*)srcB2;   // ffn2 f32 (aoF dead after LN1)

  cvt_perm_src<<<4096, 256, 0, stream>>>(src, srcB2);
  cvt4_kernel<<<3329, 256, 0, stream>>>(pos, posB, 1025, ow, owB, 256,
                                        w1, w1B, 1024, w2, w2B);
  tcvt4_kernel<<<dim3(32, 32, 4), dim3(32, 8), 0, stream>>>(
      qw, kw, vw, rw, qkvT, qkvT + 1024 * 1024, qkvT + 2048 * 1024, rwT);
  // projections
  gemm_bt<128, 128, 2><<<dim3(16, 32), 256, 0, stream>>>(srcB2, qkvT, nullptr, qkB, nullptr, 4096, 2048, 1024);
  gemm_bt<128, 64, 2><<<dim3(64, 8), 256, 0, stream>>>(qkvT + 2048 * 1024, srcB2, nullptr, vTB, nullptr, 1024, 4096, 1024);
  gemm_bt<128, 64, 2><<<dim3(16, 33), 256, 0, stream>>>(posB, rwT, nullptr, kposB, nullptr, 4100, 1024, 1024);
  attn5<<<dim3(1024), 256, 0, stream>>>(qkB, vTB, kposB, rwbias, rrbias, avB);
  gemm_bt<128, 64, 0><<<dim3(16, 32), 256, 0, stream>>>(avB, owB, aoF, nullptr, nullptr, 4096, 1024, 1024);
  ln_fuse<<<4096, 256, 0, stream>>>(src, aoF, nullptr, g1, be1, xF, xB);
  gemm_bt<128, 128, 1><<<dim3(32, 32), 256, 0, stream>>>(xB, w1B, nullptr, gB, b1, 4096, 4096, 1024);
  gemm_bt<128, 64, 0><<<dim3(16, 32), 256, 0, stream>>>(gB, w2B, ffF, nullptr, nullptr, 4096, 1024, 4096);
  ln_fuse<<<4096, 256, 0, stream>>>(xF, ffF, b2, g2, be2, out, nullptr);
  (void)in_sizes; (void)n_in; (void)out_size; (void)ws_size;
}

// Round 6
// 370.916 us; speedup vs baseline: 3.8334x; 1.0534x over previous
//
#include <hip/hip_runtime.h>
#include <math.h>

typedef __bf16 bf16x8 __attribute__((ext_vector_type(8)));
typedef __bf16 bf16x4 __attribute__((ext_vector_type(4)));
typedef float f32x4 __attribute__((ext_vector_type(4)));

__device__ __forceinline__ void gload_lds16(const __bf16* g, __bf16* l) {
  __builtin_amdgcn_global_load_lds((const __attribute__((address_space(1))) void*)g,
                                   (__attribute__((address_space(3))) void*)l, 16, 0, 0);
}

__device__ __forceinline__ float gelu_exact(float v) {
  return 0.5f * v * (1.f + erff(v * 0.70710678118654752f));
}

// ---- src (i,b)-rows -> bf16 (b,i)-rows ----
__global__ __launch_bounds__(256) void cvt_perm_src(const float* __restrict__ in,
                                                    __bf16* __restrict__ out) {
  const int rp = blockIdx.x;            // b*1024 + i
  const int i = rp & 1023, b = rp >> 10;
  const float4 v = *(const float4*)(in + ((size_t)(i * 4 + b)) * 1024 + threadIdx.x * 4);
  bf16x4 o = {(__bf16)v.x, (__bf16)v.y, (__bf16)v.z, (__bf16)v.w};
  *(bf16x4*)(out + (size_t)rp * 1024 + threadIdx.x * 4) = o;
}

// ---- fused 4-segment f32->bf16 convert; each block = 4096 elems ----
__global__ __launch_bounds__(256) void cvt4_kernel(
    const float* __restrict__ i0, __bf16* __restrict__ o0, int b0,
    const float* __restrict__ i1, __bf16* __restrict__ o1, int b1,
    const float* __restrict__ i2, __bf16* __restrict__ o2, int b2,
    const float* __restrict__ i3, __bf16* __restrict__ o3) {
  int bid = blockIdx.x;
  const float* in; __bf16* out;
  if (bid < b0) { in = i0; out = o0; }
  else if ((bid -= b0) < b1) { in = i1; out = o1; }
  else if ((bid -= b1) < b2) { in = i2; out = o2; }
  else { bid -= b2; in = i3; out = o3; }
  const int base = bid * 4096 + threadIdx.x * 4;
#pragma unroll
  for (int k = 0; k < 4; ++k) {
    const int off = base + k * 1024;
    float4 v = *(const float4*)(in + off);
    bf16x4 o = {(__bf16)v.x, (__bf16)v.y, (__bf16)v.z, (__bf16)v.w};
    *(bf16x4*)(out + off) = o;
  }
}

// ---- fused transpose-convert for the 4 weight matrices (all 1024x1024) ----
__global__ __launch_bounds__(256) void tcvt4_kernel(
    const float* __restrict__ q, const float* __restrict__ k,
    const float* __restrict__ v, const float* __restrict__ r,
    __bf16* __restrict__ oq, __bf16* __restrict__ ok,
    __bf16* __restrict__ ov, __bf16* __restrict__ orr) {
  const float* in; __bf16* out;
  switch (blockIdx.z) {
    case 0: in = q; out = oq; break;
    case 1: in = k; out = ok; break;
    case 2: in = v; out = ov; break;
    default: in = r; out = orr; break;
  }
  __shared__ float t[32][33];
  const int c0 = blockIdx.x * 32, r0 = blockIdx.y * 32;
  for (int yy = threadIdx.y; yy < 32; yy += 8)
    t[yy][threadIdx.x] = in[(size_t)(r0 + yy) * 1024 + c0 + threadIdx.x];
  __syncthreads();
  for (int yy = threadIdx.y; yy < 32; yy += 8)
    out[(size_t)(c0 + yy) * 1024 + r0 + threadIdx.x] = (__bf16)t[threadIdx.x][yy];
}

// ---------------- bf16 MFMA GEMM: C[M,N] = A[M,K] * BT[N,K]^T ----------------
// MODE 0: f32 C.  MODE 1: bf16 C = gelu(acc + bias[col]).  MODE 2: bf16 C.
// Split-K: gridDim.z=2, kChunk = K/2; z=1 writes Cf2.
template<int BM, int BN, int MODE>
__global__ __launch_bounds__(256)
void gemm_bt(const __bf16* __restrict__ A, const __bf16* __restrict__ BT,
             float* __restrict__ Cf, float* __restrict__ Cf2,
             __bf16* __restrict__ Cb, const float* __restrict__ bias,
             int M, int N, int K, int kChunk) {
  constexpr int BK = 32;
  constexpr int ALOAD = (BM * BK) / 2048;
  constexpr int BLOAD = (BN * BK) / 2048;
  __shared__ __align__(16) __bf16 lA[BM * BK];
  __shared__ __align__(16) __bf16 lB[BN * BK];
  const int tid = threadIdx.x;
  const int w = tid >> 6, l = tid & 63;
  const int lr = l & 15, lk = l >> 4;
  const int mBase = blockIdx.y * BM, nBase = blockIdx.x * BN;
  if (blockIdx.z == 1) Cf = Cf2;
  const int kStart = blockIdx.z * kChunk;
  const int kEnd = kStart + kChunk;
  constexpr int WM = BM / 2, WN = BN / 2;
  constexpr int MF = WM / 16, NF = WN / 16;
  const int wr = w >> 1, wc = w & 1;
  f32x4 acc[MF][NF] = {};
  const int srow = tid >> 2;
  const int scol = (tid & 3) * 8;

  for (int k0 = kStart; k0 < kEnd; k0 += BK) {
#pragma unroll
    for (int i = 0; i < ALOAD; ++i) {
      int grow = mBase + srow + i * 64;
      grow = grow < M ? grow : M - 1;
      gload_lds16(A + (size_t)grow * K + k0 + scol, lA + i * 2048 + w * 512);
    }
#pragma unroll
    for (int i = 0; i < BLOAD; ++i) {
      int grow = nBase + srow + i * 64;
      gload_lds16(BT + (size_t)grow * K + k0 + scol, lB + i * 2048 + w * 512);
    }
    __syncthreads();
    bf16x8 af[MF], bfr[NF];
#pragma unroll
    for (int mi = 0; mi < MF; ++mi)
      af[mi] = *(const bf16x8*)&lA[(wr * WM + mi * 16 + lr) * BK + lk * 8];
#pragma unroll
    for (int nj = 0; nj < NF; ++nj)
      bfr[nj] = *(const bf16x8*)&lB[(wc * WN + nj * 16 + lr) * BK + lk * 8];
#pragma unroll
    for (int mi = 0; mi < MF; ++mi)
#pragma unroll
      for (int nj = 0; nj < NF; ++nj)
        acc[mi][nj] = __builtin_amdgcn_mfma_f32_16x16x32_bf16(af[mi], bfr[nj], acc[mi][nj], 0, 0, 0);
    __syncthreads();
  }
#pragma unroll
  for (int mi = 0; mi < MF; ++mi) {
#pragma unroll
    for (int nj = 0; nj < NF; ++nj) {
      const int col = nBase + wc * WN + nj * 16 + lr;
      const int row0 = mBase + wr * WM + mi * 16 + lk * 4;
#pragma unroll
      for (int j = 0; j < 4; ++j) {
        const int row = row0 + j;
        if (row < M) {
          float v = acc[mi][nj][j];
          if constexpr (MODE == 1) {
            v = gelu_exact(v + bias[col]);
            Cb[(size_t)row * N + col] = (__bf16)v;
          } else if constexpr (MODE == 2) {
            Cb[(size_t)row * N + col] = (__bf16)v;
          } else {
            Cf[(size_t)row * N + col] = v;
          }
        }
      }
    }
  }
}

// ---------------- MFMA rel-pos attention v6: swapped operands, aligned LDS ----------------
// qk  bf16 [4096 rows (b*1024+i)][2048] (q|k); vT bf16 [1024 (n*64+d)][4096 (b*1024+j)]
// kpos bf16 [4100 rows (idx*4+b)][1024];  av bf16 rows (i*4+b)
// All score MFMAs SWAPPED: mfma(K/KP-frag, q-frag) -> thread holds S[jl][q=strip+lcol].
// bd stored in band-ring sbd[iln][rrel&127] with the rel-shift folded into the
// WRITE row (iln = q_w - (rrel>0)); consumer reads [q][(d0+jl-q)&127] scalar.
__global__ __launch_bounds__(256)
void attn6(const __bf16* __restrict__ qk, const __bf16* __restrict__ vT,
           const __bf16* __restrict__ kpos, const float* __restrict__ rwbias,
           const float* __restrict__ rrbias, __bf16* __restrict__ av) {
  constexpr float ALPHA = 0.125f * 1.44269504088896f;
  constexpr int PB = 132;                  // sbd pitch (bf16): 264B -> 2-bank row skew
  // 0:16384 K dbuf | 16384:32768 KP dbuf | 32768:49152 VT dbuf | 49152: sbd [64][132]
  __shared__ __align__(16) char smem[66048];
  __bf16* sbd = (__bf16*)(smem + 49152);

  const int flat = blockIdx.x;
  const int xcd = flat & 7, rr_ = flat >> 3;
  const int bn = xcd * 8 + (rr_ >> 4);
  const int it = rr_ & 15;
  const int b = bn >> 4, n = bn & 15;
  const int i0 = it * 64;
  const int tid = threadIdx.x;
  const int l = tid & 63;
  const int lcol = l & 15, lk = l >> 4;
  const int strip = (tid >> 6) * 16;
  const int wbase = tid & 192;
  const int nh64 = n * 64;
  const int part = tid & 3;
  const int q = strip + lcol;              // this thread's q-row for S/P/Z

  // staging source geometry (same for kq=0/1 up to +32 rows)
  const int rB = tid >> 3;                 // 0..31
  const int cs8 = (((tid & 7) ^ (rB & 7)) * 8);

  // ---- q fragments from global, bias+scale folded (dual use as A or B frag) ----
  bf16x8 qac[2], qg[2];
  {
    const __bf16* qrow = qk + ((size_t)(b * 1024 + i0 + q)) * 2048 + nh64;
#pragma unroll
    for (int kk = 0; kk < 2; ++kk) {
      bf16x8 qv = *(const bf16x8*)(qrow + kk * 32 + lk * 8);
      const int dbase = nh64 + kk * 32 + lk * 8;
#pragma unroll
      for (int u = 0; u < 8; ++u) {
        const float qf = (float)qv[u];
        qac[kk][u] = (__bf16)((qf + rwbias[dbase + u]) * ALPHA);
        qg[kk][u]  = (__bf16)((qf + rrbias[dbase + u]) * ALPHA);
      }
    }
  }
  bf16x8 q64a, q64b;
  {
    int gi64 = i0 + 64; gi64 = gi64 < 1024 ? gi64 : 1023;
    const __bf16* s = qk + ((size_t)(b * 1024 + gi64)) * 2048 + nh64 + part * 16;
    bf16x8 v0 = *(const bf16x8*)s;
    bf16x8 v1 = *(const bf16x8*)(s + 8);
#pragma unroll
    for (int u = 0; u < 8; ++u) {
      q64a[u] = (__bf16)(((float)v0[u] + rrbias[nh64 + part * 16 + u]) * ALPHA);
      q64b[u] = (__bf16)(((float)v1[u] + rrbias[nh64 + part * 16 + 8 + u]) * ALPHA);
    }
  }

  // ---- prologue stage: low band -> VTbuf1(temp), K0, KP0, VT0 ----
#pragma unroll
  for (int kq = 0; kq < 2; ++kq) {
    const int r = kq * 32 + rB;
    const int dst = (kq * 256 + wbase) * 8;
    gload_lds16(kpos + ((size_t)((960 - i0 + r) * 4 + b)) * 1024 + nh64 + cs8,
                (__bf16*)(smem + 40960) + dst);                       // low band (rrel<0)
    gload_lds16(qk + ((size_t)(b * 1024 + r)) * 2048 + 1024 + nh64 + cs8,
                (__bf16*)(smem) + dst);                               // K jt0
    const int rrel = r - i0;
    const int idx = (rrel <= 0) ? (1024 + rrel) : (rrel - 1);
    gload_lds16(kpos + ((size_t)(idx * 4 + b)) * 1024 + nh64 + cs8,
                (__bf16*)(smem + 16384) + dst);                       // KP jt0 batch
    gload_lds16(vT + ((size_t)(nh64 + r)) * 4096 + b * 1024 + cs8,
                (__bf16*)(smem + 32768) + dst);                       // VT jt0
  }
  __syncthreads();
  // ---- prologue G on low band (pos=0 uniform), cols = rrel&127 ----
  {
    __bf16* kpl = (__bf16*)(smem + 40960);
    const int colb0 = (-i0 - 64) & 127;
#pragma unroll
    for (int fb = 0; fb < 4; ++fb) {
      const int row = fb * 16 + lcol;
      f32x4 g = {};
#pragma unroll
      for (int kk = 0; kk < 2; ++kk) {
        bf16x8 a = *(const bf16x8*)&kpl[row * 64 + (((kk * 4 + lk) ^ (lcol & 7)) * 8)];
        g = __builtin_amdgcn_mfma_f32_16x16x32_bf16(a, qg[kk], g, 0, 0, 0);
      }
      bf16x4 gw = {(__bf16)g[0], (__bf16)g[1], (__bf16)g[2], (__bf16)g[3]};
      *(bf16x4*)&sbd[q * PB + ((colb0 + fb * 16 + lk * 4) & 127)] = gw;
    }
  }
  __syncthreads();   // VTbuf1 temp reads done before jt0 stages into it

  float zacc = 0.f;
  f32x4 oacc[4] = {};
  size_t kS = (size_t)(b * 1024 + 64 + rB) * 2048 + 1024 + nh64 + cs8;
  size_t vS = (size_t)(nh64 + rB) * 4096 + b * 1024 + 64 + cs8;

#pragma unroll 1
  for (int jt = 0; jt < 16; ++jt) {
    const int cur = jt & 1, nxt = cur ^ 1;
    const int d0 = jt * 64 - i0;
    __bf16* sK   = (__bf16*)(smem + cur * 8192);
    __bf16* sKn  = (__bf16*)(smem + nxt * 8192);
    __bf16* sKP  = (__bf16*)(smem + 16384 + cur * 8192);
    __bf16* sKPn = (__bf16*)(smem + 16384 + nxt * 8192);
    __bf16* sVT  = (__bf16*)(smem + 32768 + cur * 8192);
    __bf16* sVTn = (__bf16*)(smem + 32768 + nxt * 8192);
    // ---- stage jt+1 (K, KP, VT); OOB prefetch at jt=15 is never read ----
#pragma unroll
    for (int kq = 0; kq < 2; ++kq) {
      const int dst = (kq * 256 + wbase) * 8;
      gload_lds16(qk + kS + kq * 65536, sKn + dst);
      gload_lds16(vT + vS + kq * 131072, sVTn + dst);
      const int rreln = d0 + 64 + kq * 32 + rB;
      const int idx = (rreln <= 0) ? (1024 + rreln) : (rreln - 1);
      gload_lds16(kpos + ((size_t)(idx * 4 + b)) * 1024 + nh64 + cs8, sKPn + dst);
    }
    kS += 131072; vS += 64;
    // ---- G MFMA on current batch (rrel0 = d0), aligned b64 scatter ----
    {
      bf16x4 gw[4];
#pragma unroll
      for (int fb = 0; fb < 4; ++fb) {
        const int row = fb * 16 + lcol;
        f32x4 g = {};
#pragma unroll
        for (int kk = 0; kk < 2; ++kk) {
          bf16x8 a = *(const bf16x8*)&sKP[row * 64 + (((kk * 4 + lk) ^ (lcol & 7)) * 8)];
          g = __builtin_amdgcn_mfma_f32_16x16x32_bf16(a, qg[kk], g, 0, 0, 0);
        }
        gw[fb] = bf16x4{(__bf16)g[0], (__bf16)g[1], (__bf16)g[2], (__bf16)g[3]};
      }
      if (d0 > 0) {
        if (q > 0) {
          const int ro = (q - 1) * PB;
#pragma unroll
          for (int fb = 0; fb < 4; ++fb)
            *(bf16x4*)&sbd[ro + ((d0 + fb * 16 + lk * 4) & 127)] = gw[fb];
        }
      } else if (d0 < 0) {
        const int ro = q * PB;
#pragma unroll
        for (int fb = 0; fb < 4; ++fb)
          *(bf16x4*)&sbd[ro + ((d0 + fb * 16 + lk * 4) & 127)] = gw[fb];
      } else {
        if (lk == 0) {            // run containing rrel=0 (pos flips inside)
          sbd[q * PB] = gw[0][0];
          if (q > 0) {
            sbd[(q - 1) * PB + 1] = gw[0][1];
            sbd[(q - 1) * PB + 2] = gw[0][2];
            sbd[(q - 1) * PB + 3] = gw[0][3];
#pragma unroll
            for (int fb = 1; fb < 4; ++fb)
              *(bf16x4*)&sbd[(q - 1) * PB + fb * 16] = gw[fb];
          }
        } else if (q > 0) {
          const int ro = (q - 1) * PB;
#pragma unroll
          for (int fb = 0; fb < 4; ++fb)
            *(bf16x4*)&sbd[ro + fb * 16 + lk * 4] = gw[fb];
        }
      }
    }
    // ---- G64 (q-row i0+64 -> sbd row 63, rrel>0 cols) ----
    {
      const int cl = tid >> 2;
      const int sw = cl & 7;
      bf16x8 kv0 = *(const bf16x8*)&sKP[cl * 64 + (((2 * part) ^ sw) * 8)];
      bf16x8 kv1 = *(const bf16x8*)&sKP[cl * 64 + (((2 * part + 1) ^ sw) * 8)];
      float s64 = 0.f;
#pragma unroll
      for (int u = 0; u < 8; ++u)
        s64 += (float)q64a[u] * (float)kv0[u] + (float)q64b[u] * (float)kv1[u];
      s64 += __shfl_xor(s64, 1, 64);
      s64 += __shfl_xor(s64, 2, 64);
      if (part == 0 && (d0 + cl) > 0)
        sbd[63 * PB + ((d0 + cl) & 127)] = (__bf16)s64;
    }
    // ---- ac MFMA (swapped): sc[fk][jj] = S[jl=fk*16+lk*4+jj][q] ----
    f32x4 sc[4];
#pragma unroll
    for (int fk = 0; fk < 4; ++fk) {
      const int row = fk * 16 + lcol;
      f32x4 a = {};
#pragma unroll
      for (int kk = 0; kk < 2; ++kk) {
        bf16x8 kf = *(const bf16x8*)&sK[row * 64 + (((kk * 4 + lk) ^ (lcol & 7)) * 8)];
        a = __builtin_amdgcn_mfma_f32_16x16x32_bf16(kf, qac[kk], a, 0, 0, 0);
      }
      sc[fk] = a;
    }
    __syncthreads();   // sbd/G64 visible; all ac reads of sK done -> P may overwrite
    // ---- gather + exp2 + aligned P store + scalar Z ----
    {
      __bf16* pP = sK;
      const int rowb = q * PB;
      const int sb = d0 - q;
#pragma unroll
      for (int fk = 0; fk < 4; ++fk) {
        const int cb = sb + fk * 16 + lk * 4;
        float e0 = exp2f(sc[fk][0] + (float)sbd[rowb + ((cb) & 127)]);
        float e1 = exp2f(sc[fk][1] + (float)sbd[rowb + ((cb + 1) & 127)]);
        float e2 = exp2f(sc[fk][2] + (float)sbd[rowb + ((cb + 2) & 127)]);
        float e3 = exp2f(sc[fk][3] + (float)sbd[rowb + ((cb + 3) & 127)]);
        zacc += e0 + e1 + e2 + e3;
        bf16x4 pw = {(__bf16)e0, (__bf16)e1, (__bf16)e2, (__bf16)e3};
        *(bf16x4*)&pP[q * 64 + (((fk * 2 + (lk >> 1)) ^ (q & 7)) * 8) + (lk & 1) * 4] = pw;
      }
    }
    // ---- PV MFMA: O[q'][d] += P[q'][jl] * VT[d][jl] ----
#pragma unroll
    for (int kk = 0; kk < 2; ++kk) {
      bf16x8 pa = *(const bf16x8*)&sK[q * 64 + (((kk * 4 + lk) ^ (q & 7)) * 8)];
#pragma unroll
      for (int fd = 0; fd < 4; ++fd) {
        const int vrow = fd * 16 + lcol;
        bf16x8 bv = *(const bf16x8*)&sVT[vrow * 64 + (((kk * 4 + lk) ^ (lcol & 7)) * 8)];
        oacc[fd] = __builtin_amdgcn_mfma_f32_16x16x32_bf16(pa, bv, oacc[fd], 0, 0, 0);
      }
    }
    __syncthreads();   // all reads of cur buffers done before next-iter staging
  }
  // ---- epilogue: Z across lk lanes, redistribute, normalize, store ----
  float z = zacc;
  z += __shfl_xor(z, 16, 64);
  z += __shfl_xor(z, 32, 64);
#pragma unroll
  for (int jj = 0; jj < 4; ++jj) {
    const float rz = 1.f / __shfl(z, lk * 4 + jj, 16);
    const int ig = i0 + strip + lk * 4 + jj;
    __bf16* dst = av + ((size_t)(ig * 4 + b)) * 1024 + nh64;
#pragma unroll
    for (int fd = 0; fd < 4; ++fd)
      dst[fd * 16 + lcol] = (__bf16)(oacc[fd][jj] * rz);
  }
}

// ---------------- fused residual + LayerNorm (up to 2 partial addends) ----------------
__global__ __launch_bounds__(256)
void ln_fuse(const float* __restrict__ A, const float* __restrict__ Bv,
             const float* __restrict__ Bv2, const float* __restrict__ cb,
             const float* __restrict__ g, const float* __restrict__ be,
             float* __restrict__ oF, __bf16* __restrict__ oB) {
  const int row = blockIdx.x, t = threadIdx.x;
  const size_t base = (size_t)row * 1024 + t * 4;
  const float4 a = *(const float4*)(A + base);
  const float4 bb = *(const float4*)(Bv + base);
  float x0 = a.x + bb.x, x1 = a.y + bb.y, x2 = a.z + bb.z, x3 = a.w + bb.w;
  if (Bv2) {
    const float4 c = *(const float4*)(Bv2 + base);
    x0 += c.x; x1 += c.y; x2 += c.z; x3 += c.w;
  }
  if (cb) {
    const float4 c = *(const float4*)(cb + t * 4);
    x0 += c.x; x1 += c.y; x2 += c.z; x3 += c.w;
  }
  float s = x0 + x1 + x2 + x3;
  float qq = x0 * x0 + x1 * x1 + x2 * x2 + x3 * x3;
#pragma unroll
  for (int o = 1; o < 64; o <<= 1) { s += __shfl_xor(s, o, 64); qq += __shfl_xor(qq, o, 64); }
  __shared__ float ss[4], qs[4];
  if ((t & 63) == 0) { ss[t >> 6] = s; qs[t >> 6] = qq; }
  __syncthreads();
  s = ss[0] + ss[1] + ss[2] + ss[3];
  qq = qs[0] + qs[1] + qs[2] + qs[3];
  const float mean = s * (1.f / 1024.f);
  const float var = qq * (1.f / 1024.f) - mean * mean;
  const float rstd = rsqrtf(var + 1e-5f);
  const float4 gv = *(const float4*)(g + t * 4);
  const float4 bev = *(const float4*)(be + t * 4);
  const float y0 = (x0 - mean) * rstd * gv.x + bev.x;
  const float y1 = (x1 - mean) * rstd * gv.y + bev.y;
  const float y2 = (x2 - mean) * rstd * gv.z + bev.z;
  const float y3 = (x3 - mean) * rstd * gv.w + bev.w;
  float4 r = {y0, y1, y2, y3};
  *(float4*)(oF + base) = r;
  if (oB) {
    bf16x4 o4 = {(__bf16)y0, (__bf16)y1, (__bf16)y2, (__bf16)y3};
    *(bf16x4*)(oB + base) = o4;
  }
}

extern "C" void kernel_launch(void* const* d_in, const int* in_sizes, int n_in,
                              void* d_out, int out_size, void* d_ws, size_t ws_size,
                              hipStream_t stream) {
  const float* src    = (const float*)d_in[0];
  const float* pos    = (const float*)d_in[1];
  const float* qw     = (const float*)d_in[3];
  const float* kw     = (const float*)d_in[4];
  const float* vw     = (const float*)d_in[5];
  const float* rw     = (const float*)d_in[6];
  const float* ow     = (const float*)d_in[7];
  const float* rwbias = (const float*)d_in[8];
  const float* rrbias = (const float*)d_in[9];
  const float* w1     = (const float*)d_in[10];
  const float* b1     = (const float*)d_in[11];
  const float* w2     = (const float*)d_in[12];
  const float* b2     = (const float*)d_in[13];
  const float* g1     = (const float*)d_in[14];
  const float* be1    = (const float*)d_in[15];
  const float* g2     = (const float*)d_in[16];
  const float* be2    = (const float*)d_in[17];
  float* out = (float*)d_out;

  char* p = (char*)d_ws;
  auto alloc = [&](size_t bytes) { char* r = p; p += (bytes + 255) & ~(size_t)255; return r; };
  // order chosen so split-K partials alias dead, CONTIGUOUS regions
  __bf16* qkB   = (__bf16*)alloc(4096ull * 2048 * 2);   // dead after attn
  __bf16* vTB   = (__bf16*)alloc(1024ull * 4096 * 2);   // dead after attn
  __bf16* kposB = (__bf16*)alloc(4100ull * 1024 * 2);   // dead after attn
  __bf16* avB   = (__bf16*)alloc(4096ull * 1024 * 2);   // dead after attn-out
  __bf16* srcB2 = (__bf16*)alloc(4096ull * 1024 * 2);   // dead after vT gemm
  __bf16* posB  = (__bf16*)alloc(4100ull * 1024 * 2);   // dead after kpos gemm
  float*  xF    = (float*)alloc(4096ull * 1024 * 4);
  __bf16* w2B   = (__bf16*)alloc(4096ull * 1024 * 2);
  __bf16* qkvT  = (__bf16*)alloc(3072ull * 1024 * 2);
  __bf16* rwT   = (__bf16*)alloc(1024ull * 1024 * 2);
  __bf16* owB   = (__bf16*)alloc(1024ull * 1024 * 2);
  __bf16* w1B   = (__bf16*)alloc(4096ull * 1024 * 2);   // dead after FFN1
  __bf16* xB    = (__bf16*)alloc(4096ull * 1024 * 2);   // dead after FFN1
  // aliases (disjoint lifetimes):
  __bf16* gB  = qkB;             // gelu 32MB over qkB+vTB+kposB
  float* aoP0 = (float*)srcB2;   // attn-out partial0 16MB over srcB2+posB
  float* aoP1 = xF;              // partial1 over xF (ln_fuse reads then writes same addr)
  float* ffP0 = (float*)avB;     // ffn2 partial0 16MB over avB+srcB2
  float* ffP1 = (float*)w1B;     // ffn2 partial1 16MB over w1B+xB

  cvt_perm_src<<<4096, 256, 0, stream>>>(src, srcB2);
  cvt4_kernel<<<3329, 256, 0, stream>>>(pos, posB, 1025, ow, owB, 256,
                                        w1, w1B, 1024, w2, w2B);
  tcvt4_kernel<<<dim3(32, 32, 4), dim3(32, 8), 0, stream>>>(
      qw, kw, vw, rw, qkvT, qkvT + 1024 * 1024, qkvT + 2048 * 1024, rwT);
  // projections
  gemm_bt<128, 128, 2><<<dim3(16, 32), 256, 0, stream>>>(srcB2, qkvT, nullptr, nullptr, qkB, nullptr, 4096, 2048, 1024, 1024);
  gemm_bt<128, 64, 2><<<dim3(64, 8), 256, 0, stream>>>(qkvT + 2048 * 1024, srcB2, nullptr, nullptr, vTB, nullptr, 1024, 4096, 1024, 1024);
  gemm_bt<128, 64, 2><<<dim3(16, 33), 256, 0, stream>>>(posB, rwT, nullptr, nullptr, kposB, nullptr, 4100, 1024, 1024, 1024);
  attn6<<<dim3(1024), 256, 0, stream>>>(qkB, vTB, kposB, rwbias, rrbias, avB);
  // attn-out: split-K=2 over K=1024
  gemm_bt<128, 128, 0><<<dim3(8, 32, 2), 256, 0, stream>>>(avB, owB, aoP0, aoP1, nullptr, nullptr, 4096, 1024, 1024, 512);
  ln_fuse<<<4096, 256, 0, stream>>>(src, aoP0, aoP1, nullptr, g1, be1, xF, xB);
  gemm_bt<128, 128, 1><<<dim3(32, 32), 256, 0, stream>>>(xB, w1B, nullptr, nullptr, gB, b1, 4096, 4096, 1024, 1024);
  // FFN2: split-K=2 over K=4096
  gemm_bt<128, 128, 0><<<dim3(8, 32, 2), 256, 0, stream>>>(gB, w2B, ffP0, ffP1, nullptr, nullptr, 4096, 1024, 4096, 2048);
  ln_fuse<<<4096, 256, 0, stream>>>(xF, ffP0, ffP1, b2, g2, be2, out, nullptr);
  (void)in_sizes; (void)n_in; (void)out_size; (void)ws_size;
}

// Round 7
// 347.166 us; speedup vs baseline: 4.0957x; 1.0684x over previous
//
#include <hip/hip_runtime.h>
#include <math.h>

typedef __bf16 bf16x8 __attribute__((ext_vector_type(8)));
typedef __bf16 bf16x4 __attribute__((ext_vector_type(4)));
typedef float f32x4 __attribute__((ext_vector_type(4)));

__device__ __forceinline__ void gload_lds16(const __bf16* g, __bf16* l) {
  __builtin_amdgcn_global_load_lds((const __attribute__((address_space(1))) void*)g,
                                   (__attribute__((address_space(3))) void*)l, 16, 0, 0);
}

__device__ __forceinline__ float gelu_exact(float v) {
  return 0.5f * v * (1.f + erff(v * 0.70710678118654752f));
}

// ---- src (i,b)-rows -> bf16 (b,i)-rows ----
__global__ __launch_bounds__(256) void cvt_perm_src(const float* __restrict__ in,
                                                    __bf16* __restrict__ out) {
  const int rp = blockIdx.x;            // b*1024 + i
  const int i = rp & 1023, b = rp >> 10;
  const float4 v = *(const float4*)(in + ((size_t)(i * 4 + b)) * 1024 + threadIdx.x * 4);
  bf16x4 o = {(__bf16)v.x, (__bf16)v.y, (__bf16)v.z, (__bf16)v.w};
  *(bf16x4*)(out + (size_t)rp * 1024 + threadIdx.x * 4) = o;
}

// ---- fused 4-segment f32->bf16 convert; each block = 4096 elems ----
__global__ __launch_bounds__(256) void cvt4_kernel(
    const float* __restrict__ i0, __bf16* __restrict__ o0, int b0,
    const float* __restrict__ i1, __bf16* __restrict__ o1, int b1,
    const float* __restrict__ i2, __bf16* __restrict__ o2, int b2,
    const float* __restrict__ i3, __bf16* __restrict__ o3) {
  int bid = blockIdx.x;
  const float* in; __bf16* out;
  if (bid < b0) { in = i0; out = o0; }
  else if ((bid -= b0) < b1) { in = i1; out = o1; }
  else if ((bid -= b1) < b2) { in = i2; out = o2; }
  else { bid -= b2; in = i3; out = o3; }
  const int base = bid * 4096 + threadIdx.x * 4;
#pragma unroll
  for (int k = 0; k < 4; ++k) {
    const int off = base + k * 1024;
    float4 v = *(const float4*)(in + off);
    bf16x4 o = {(__bf16)v.x, (__bf16)v.y, (__bf16)v.z, (__bf16)v.w};
    *(bf16x4*)(out + off) = o;
  }
}

// ---- fused transpose-convert for the 4 weight matrices (all 1024x1024) ----
__global__ __launch_bounds__(256) void tcvt4_kernel(
    const float* __restrict__ q, const float* __restrict__ k,
    const float* __restrict__ v, const float* __restrict__ r,
    __bf16* __restrict__ oq, __bf16* __restrict__ ok,
    __bf16* __restrict__ ov, __bf16* __restrict__ orr) {
  const float* in; __bf16* out;
  switch (blockIdx.z) {
    case 0: in = q; out = oq; break;
    case 1: in = k; out = ok; break;
    case 2: in = v; out = ov; break;
    default: in = r; out = orr; break;
  }
  __shared__ float t[32][33];
  const int c0 = blockIdx.x * 32, r0 = blockIdx.y * 32;
  for (int yy = threadIdx.y; yy < 32; yy += 8)
    t[yy][threadIdx.x] = in[(size_t)(r0 + yy) * 1024 + c0 + threadIdx.x];
  __syncthreads();
  for (int yy = threadIdx.y; yy < 32; yy += 8)
    out[(size_t)(c0 + yy) * 1024 + r0 + threadIdx.x] = (__bf16)t[threadIdx.x][yy];
}

// ---------------- bf16 MFMA GEMM: C[M,N] = A[M,K] * BT[N,K]^T ----------------
// MODE 0: f32 C.  MODE 1: bf16 C = gelu(acc + bias[col]).  MODE 2: bf16 C.
// Split-K: gridDim.z=2, kChunk = K/2; z=1 writes Cf2.
// 2-phase double-buffered pipeline: one barrier/iter; stage(t+1) issued AFTER
// the barrier, so iter-t compute covers the load latency; buf X read at iter t,
// re-staged at iter t+1 (issue after the barrier that follows all t reads).
template<int BM, int BN, int MODE>
__global__ __launch_bounds__(256)
void gemm_bt(const __bf16* __restrict__ A, const __bf16* __restrict__ BT,
             float* __restrict__ Cf, float* __restrict__ Cf2,
             __bf16* __restrict__ Cb, const float* __restrict__ bias,
             int M, int N, int K, int kChunk) {
  constexpr int BK = 32;
  constexpr int ALOAD = (BM * BK) / 2048;
  constexpr int BLOAD = (BN * BK) / 2048;
  __shared__ __align__(16) __bf16 lA[2][BM * BK];
  __shared__ __align__(16) __bf16 lB[2][BN * BK];
  const int tid = threadIdx.x;
  const int w = tid >> 6, l = tid & 63;
  const int lr = l & 15, lk = l >> 4;
  const int mBase = blockIdx.y * BM, nBase = blockIdx.x * BN;
  if (blockIdx.z == 1) Cf = Cf2;
  const int kStart = blockIdx.z * kChunk;
  const int srow = tid >> 2;
  const int scol = (tid & 3) * 8;
  const int wbase = w * 512;

  // hoisted per-thread incremental source pointers (clamped once)
  const __bf16* aSrc[ALOAD];
  const __bf16* bSrc[BLOAD];
#pragma unroll
  for (int i = 0; i < ALOAD; ++i) {
    int grow = mBase + srow + i * 64;
    grow = grow < M ? grow : M - 1;
    aSrc[i] = A + (size_t)grow * K + kStart + scol;
  }
#pragma unroll
  for (int i = 0; i < BLOAD; ++i) {
    const int grow = nBase + srow + i * 64;
    bSrc[i] = BT + (size_t)grow * K + kStart + scol;
  }
  auto stage = [&](int buf) {
#pragma unroll
    for (int i = 0; i < ALOAD; ++i) {
      gload_lds16(aSrc[i], &lA[buf][i * 2048 + wbase]);
      aSrc[i] += BK;
    }
#pragma unroll
    for (int i = 0; i < BLOAD; ++i) {
      gload_lds16(bSrc[i], &lB[buf][i * 2048 + wbase]);
      bSrc[i] += BK;
    }
  };

  constexpr int WM = BM / 2, WN = BN / 2;
  constexpr int MF = WM / 16, NF = WN / 16;
  const int wr = w >> 1, wc = w & 1;
  f32x4 acc[MF][NF] = {};

  const int nIter = kChunk / BK;
  stage(0);
  int cur = 0;
#pragma unroll 1
  for (int t = 0; t < nIter; ++t) {
    __syncthreads();               // buf[cur] ready (loads issued last iter)
    if (t + 1 < nIter) stage(cur ^ 1);
    bf16x8 af[MF], bfr[NF];
#pragma unroll
    for (int mi = 0; mi < MF; ++mi)
      af[mi] = *(const bf16x8*)&lA[cur][(wr * WM + mi * 16 + lr) * BK + lk * 8];
#pragma unroll
    for (int nj = 0; nj < NF; ++nj)
      bfr[nj] = *(const bf16x8*)&lB[cur][(wc * WN + nj * 16 + lr) * BK + lk * 8];
#pragma unroll
    for (int mi = 0; mi < MF; ++mi)
#pragma unroll
      for (int nj = 0; nj < NF; ++nj)
        acc[mi][nj] = __builtin_amdgcn_mfma_f32_16x16x32_bf16(af[mi], bfr[nj], acc[mi][nj], 0, 0, 0);
    cur ^= 1;
  }
#pragma unroll
  for (int mi = 0; mi < MF; ++mi) {
#pragma unroll
    for (int nj = 0; nj < NF; ++nj) {
      const int col = nBase + wc * WN + nj * 16 + lr;
      const int row0 = mBase + wr * WM + mi * 16 + lk * 4;
#pragma unroll
      for (int j = 0; j < 4; ++j) {
        const int row = row0 + j;
        if (row < M) {
          float v = acc[mi][nj][j];
          if constexpr (MODE == 1) {
            v = gelu_exact(v + bias[col]);
            Cb[(size_t)row * N + col] = (__bf16)v;
          } else if constexpr (MODE == 2) {
            Cb[(size_t)row * N + col] = (__bf16)v;
          } else {
            Cf[(size_t)row * N + col] = v;
          }
        }
      }
    }
  }
}

// ---------------- MFMA rel-pos attention v6: swapped operands, aligned LDS ----------------
// qk  bf16 [4096 rows (b*1024+i)][2048] (q|k); vT bf16 [1024 (n*64+d)][4096 (b*1024+j)]
// kpos bf16 [4100 rows (idx*4+b)][1024];  av bf16 rows (i*4+b)
// All score MFMAs SWAPPED: mfma(K/KP-frag, q-frag) -> thread holds S[jl][q=strip+lcol].
// bd stored in band-ring sbd[iln][rrel&127] with the rel-shift folded into the
// WRITE row (iln = q_w - (rrel>0)); consumer reads [q][(d0+jl-q)&127] scalar.
__global__ __launch_bounds__(256)
void attn6(const __bf16* __restrict__ qk, const __bf16* __restrict__ vT,
           const __bf16* __restrict__ kpos, const float* __restrict__ rwbias,
           const float* __restrict__ rrbias, __bf16* __restrict__ av) {
  constexpr float ALPHA = 0.125f * 1.44269504088896f;
  constexpr int PB = 132;                  // sbd pitch (bf16): 264B -> 2-bank row skew
  // 0:16384 K dbuf | 16384:32768 KP dbuf | 32768:49152 VT dbuf | 49152: sbd [64][132]
  __shared__ __align__(16) char smem[66048];
  __bf16* sbd = (__bf16*)(smem + 49152);

  const int flat = blockIdx.x;
  const int xcd = flat & 7, rr_ = flat >> 3;
  const int bn = xcd * 8 + (rr_ >> 4);
  const int it = rr_ & 15;
  const int b = bn >> 4, n = bn & 15;
  const int i0 = it * 64;
  const int tid = threadIdx.x;
  const int l = tid & 63;
  const int lcol = l & 15, lk = l >> 4;
  const int strip = (tid >> 6) * 16;
  const int wbase = tid & 192;
  const int nh64 = n * 64;
  const int part = tid & 3;
  const int q = strip + lcol;              // this thread's q-row for S/P/Z

  // staging source geometry (same for kq=0/1 up to +32 rows)
  const int rB = tid >> 3;                 // 0..31
  const int cs8 = (((tid & 7) ^ (rB & 7)) * 8);

  // ---- q fragments from global, bias+scale folded (dual use as A or B frag) ----
  bf16x8 qac[2], qg[2];
  {
    const __bf16* qrow = qk + ((size_t)(b * 1024 + i0 + q)) * 2048 + nh64;
#pragma unroll
    for (int kk = 0; kk < 2; ++kk) {
      bf16x8 qv = *(const bf16x8*)(qrow + kk * 32 + lk * 8);
      const int dbase = nh64 + kk * 32 + lk * 8;
#pragma unroll
      for (int u = 0; u < 8; ++u) {
        const float qf = (float)qv[u];
        qac[kk][u] = (__bf16)((qf + rwbias[dbase + u]) * ALPHA);
        qg[kk][u]  = (__bf16)((qf + rrbias[dbase + u]) * ALPHA);
      }
    }
  }
  bf16x8 q64a, q64b;
  {
    int gi64 = i0 + 64; gi64 = gi64 < 1024 ? gi64 : 1023;
    const __bf16* s = qk + ((size_t)(b * 1024 + gi64)) * 2048 + nh64 + part * 16;
    bf16x8 v0 = *(const bf16x8*)s;
    bf16x8 v1 = *(const bf16x8*)(s + 8);
#pragma unroll
    for (int u = 0; u < 8; ++u) {
      q64a[u] = (__bf16)(((float)v0[u] + rrbias[nh64 + part * 16 + u]) * ALPHA);
      q64b[u] = (__bf16)(((float)v1[u] + rrbias[nh64 + part * 16 + 8 + u]) * ALPHA);
    }
  }

  // ---- prologue stage: low band -> VTbuf1(temp), K0, KP0, VT0 ----
#pragma unroll
  for (int kq = 0; kq < 2; ++kq) {
    const int r = kq * 32 + rB;
    const int dst = (kq * 256 + wbase) * 8;
    gload_lds16(kpos + ((size_t)((960 - i0 + r) * 4 + b)) * 1024 + nh64 + cs8,
                (__bf16*)(smem + 40960) + dst);                       // low band (rrel<0)
    gload_lds16(qk + ((size_t)(b * 1024 + r)) * 2048 + 1024 + nh64 + cs8,
                (__bf16*)(smem) + dst);                               // K jt0
    const int rrel = r - i0;
    const int idx = (rrel <= 0) ? (1024 + rrel) : (rrel - 1);
    gload_lds16(kpos + ((size_t)(idx * 4 + b)) * 1024 + nh64 + cs8,
                (__bf16*)(smem + 16384) + dst);                       // KP jt0 batch
    gload_lds16(vT + ((size_t)(nh64 + r)) * 4096 + b * 1024 + cs8,
                (__bf16*)(smem + 32768) + dst);                       // VT jt0
  }
  __syncthreads();
  // ---- prologue G on low band (pos=0 uniform), cols = rrel&127 ----
  {
    __bf16* kpl = (__bf16*)(smem + 40960);
    const int colb0 = (-i0 - 64) & 127;
#pragma unroll
    for (int fb = 0; fb < 4; ++fb) {
      const int row = fb * 16 + lcol;
      f32x4 g = {};
#pragma unroll
      for (int kk = 0; kk < 2; ++kk) {
        bf16x8 a = *(const bf16x8*)&kpl[row * 64 + (((kk * 4 + lk) ^ (lcol & 7)) * 8)];
        g = __builtin_amdgcn_mfma_f32_16x16x32_bf16(a, qg[kk], g, 0, 0, 0);
      }
      bf16x4 gw = {(__bf16)g[0], (__bf16)g[1], (__bf16)g[2], (__bf16)g[3]};
      *(bf16x4*)&sbd[q * PB + ((colb0 + fb * 16 + lk * 4) & 127)] = gw;
    }
  }
  __syncthreads();   // VTbuf1 temp reads done before jt0 stages into it

  float zacc = 0.f;
  f32x4 oacc[4] = {};
  size_t kS = (size_t)(b * 1024 + 64 + rB) * 2048 + 1024 + nh64 + cs8;
  size_t vS = (size_t)(nh64 + rB) * 4096 + b * 1024 + 64 + cs8;

#pragma unroll 1
  for (int jt = 0; jt < 16; ++jt) {
    const int cur = jt & 1, nxt = cur ^ 1;
    const int d0 = jt * 64 - i0;
    __bf16* sK   = (__bf16*)(smem + cur * 8192);
    __bf16* sKn  = (__bf16*)(smem + nxt * 8192);
    __bf16* sKP  = (__bf16*)(smem + 16384 + cur * 8192);
    __bf16* sKPn = (__bf16*)(smem + 16384 + nxt * 8192);
    __bf16* sVT  = (__bf16*)(smem + 32768 + cur * 8192);
    __bf16* sVTn = (__bf16*)(smem + 32768 + nxt * 8192);
    // ---- stage jt+1 (K, KP, VT); OOB prefetch at jt=15 is never read ----
#pragma unroll
    for (int kq = 0; kq < 2; ++kq) {
      const int dst = (kq * 256 + wbase) * 8;
      gload_lds16(qk + kS + kq * 65536, sKn + dst);
      gload_lds16(vT + vS + kq * 131072, sVTn + dst);
      const int rreln = d0 + 64 + kq * 32 + rB;
      const int idx = (rreln <= 0) ? (1024 + rreln) : (rreln - 1);
      gload_lds16(kpos + ((size_t)(idx * 4 + b)) * 1024 + nh64 + cs8, sKPn + dst);
    }
    kS += 131072; vS += 64;
    // ---- G MFMA on current batch (rrel0 = d0), aligned b64 scatter ----
    {
      bf16x4 gw[4];
#pragma unroll
      for (int fb = 0; fb < 4; ++fb) {
        const int row = fb * 16 + lcol;
        f32x4 g = {};
#pragma unroll
        for (int kk = 0; kk < 2; ++kk) {
          bf16x8 a = *(const bf16x8*)&sKP[row * 64 + (((kk * 4 + lk) ^ (lcol & 7)) * 8)];
          g = __builtin_amdgcn_mfma_f32_16x16x32_bf16(a, qg[kk], g, 0, 0, 0);
        }
        gw[fb] = bf16x4{(__bf16)g[0], (__bf16)g[1], (__bf16)g[2], (__bf16)g[3]};
      }
      if (d0 > 0) {
        if (q > 0) {
          const int ro = (q - 1) * PB;
#pragma unroll
          for (int fb = 0; fb < 4; ++fb)
            *(bf16x4*)&sbd[ro + ((d0 + fb * 16 + lk * 4) & 127)] = gw[fb];
        }
      } else if (d0 < 0) {
        const int ro = q * PB;
#pragma unroll
        for (int fb = 0; fb < 4; ++fb)
          *(bf16x4*)&sbd[ro + ((d0 + fb * 16 + lk * 4) & 127)] = gw[fb];
      } else {
        if (lk == 0) {            // run containing rrel=0 (pos flips inside)
          sbd[q * PB] = gw[0][0];
          if (q > 0) {
            sbd[(q - 1) * PB + 1] = gw[0][1];
            sbd[(q - 1) * PB + 2] = gw[0][2];
            sbd[(q - 1) * PB + 3] = gw[0][3];
#pragma unroll
            for (int fb = 1; fb < 4; ++fb)
              *(bf16x4*)&sbd[(q - 1) * PB + fb * 16] = gw[fb];
          }
        } else if (q > 0) {
          const int ro = (q - 1) * PB;
#pragma unroll
          for (int fb = 0; fb < 4; ++fb)
            *(bf16x4*)&sbd[ro + fb * 16 + lk * 4] = gw[fb];
        }
      }
    }
    // ---- G64 (q-row i0+64 -> sbd row 63, rrel>0 cols) ----
    {
      const int cl = tid >> 2;
      const int sw = cl & 7;
      bf16x8 kv0 = *(const bf16x8*)&sKP[cl * 64 + (((2 * part) ^ sw) * 8)];
      bf16x8 kv1 = *(const bf16x8*)&sKP[cl * 64 + (((2 * part + 1) ^ sw) * 8)];
      float s64 = 0.f;
#pragma unroll
      for (int u = 0; u < 8; ++u)
        s64 += (float)q64a[u] * (float)kv0[u] + (float)q64b[u] * (float)kv1[u];
      s64 += __shfl_xor(s64, 1, 64);
      s64 += __shfl_xor(s64, 2, 64);
      if (part == 0 && (d0 + cl) > 0)
        sbd[63 * PB + ((d0 + cl) & 127)] = (__bf16)s64;
    }
    // ---- ac MFMA (swapped): sc[fk][jj] = S[jl=fk*16+lk*4+jj][q] ----
    f32x4 sc[4];
#pragma unroll
    for (int fk = 0; fk < 4; ++fk) {
      const int row = fk * 16 + lcol;
      f32x4 a = {};
#pragma unroll
      for (int kk = 0; kk < 2; ++kk) {
        bf16x8 kf = *(const bf16x8*)&sK[row * 64 + (((kk * 4 + lk) ^ (lcol & 7)) * 8)];
        a = __builtin_amdgcn_mfma_f32_16x16x32_bf16(kf, qac[kk], a, 0, 0, 0);
      }
      sc[fk] = a;
    }
    __syncthreads();   // sbd/G64 visible; all ac reads of sK done -> P may overwrite
    // ---- gather + exp2 + aligned P store + scalar Z ----
    {
      __bf16* pP = sK;
      const int rowb = q * PB;
      const int sb = d0 - q;
#pragma unroll
      for (int fk = 0; fk < 4; ++fk) {
        const int cb = sb + fk * 16 + lk * 4;
        float e0 = exp2f(sc[fk][0] + (float)sbd[rowb + ((cb) & 127)]);
        float e1 = exp2f(sc[fk][1] + (float)sbd[rowb + ((cb + 1) & 127)]);
        float e2 = exp2f(sc[fk][2] + (float)sbd[rowb + ((cb + 2) & 127)]);
        float e3 = exp2f(sc[fk][3] + (float)sbd[rowb + ((cb + 3) & 127)]);
        zacc += e0 + e1 + e2 + e3;
        bf16x4 pw = {(__bf16)e0, (__bf16)e1, (__bf16)e2, (__bf16)e3};
        *(bf16x4*)&pP[q * 64 + (((fk * 2 + (lk >> 1)) ^ (q & 7)) * 8) + (lk & 1) * 4] = pw;
      }
    }
    // ---- PV MFMA: O[q'][d] += P[q'][jl] * VT[d][jl] ----
#pragma unroll
    for (int kk = 0; kk < 2; ++kk) {
      bf16x8 pa = *(const bf16x8*)&sK[q * 64 + (((kk * 4 + lk) ^ (q & 7)) * 8)];
#pragma unroll
      for (int fd = 0; fd < 4; ++fd) {
        const int vrow = fd * 16 + lcol;
        bf16x8 bv = *(const bf16x8*)&sVT[vrow * 64 + (((kk * 4 + lk) ^ (lcol & 7)) * 8)];
        oacc[fd] = __builtin_amdgcn_mfma_f32_16x16x32_bf16(pa, bv, oacc[fd], 0, 0, 0);
      }
    }
    __syncthreads();   // all reads of cur buffers done before next-iter staging
  }
  // ---- epilogue: Z across lk lanes, redistribute, normalize, store ----
  float z = zacc;
  z += __shfl_xor(z, 16, 64);
  z += __shfl_xor(z, 32, 64);
#pragma unroll
  for (int jj = 0; jj < 4; ++jj) {
    const float rz = 1.f / __shfl(z, lk * 4 + jj, 16);
    const int ig = i0 + strip + lk * 4 + jj;
    __bf16* dst = av + ((size_t)(ig * 4 + b)) * 1024 + nh64;
#pragma unroll
    for (int fd = 0; fd < 4; ++fd)
      dst[fd * 16 + lcol] = (__bf16)(oacc[fd][jj] * rz);
  }
}

// ---------------- fused residual + LayerNorm (up to 2 partial addends) ----------------
__global__ __launch_bounds__(256)
void ln_fuse(const float* __restrict__ A, const float* __restrict__ Bv,
             const float* __restrict__ Bv2, const float* __restrict__ cb,
             const float* __restrict__ g, const float* __restrict__ be,
             float* __restrict__ oF, __bf16* __restrict__ oB) {
  const int row = blockIdx.x, t = threadIdx.x;
  const size_t base = (size_t)row * 1024 + t * 4;
  const float4 a = *(const float4*)(A + base);
  const float4 bb = *(const float4*)(Bv + base);
  float x0 = a.x + bb.x, x1 = a.y + bb.y, x2 = a.z + bb.z, x3 = a.w + bb.w;
  if (Bv2) {
    const float4 c = *(const float4*)(Bv2 + base);
    x0 += c.x; x1 += c.y; x2 += c.z; x3 += c.w;
  }
  if (cb) {
    const float4 c = *(const float4*)(cb + t * 4);
    x0 += c.x; x1 += c.y; x2 += c.z; x3 += c.w;
  }
  float s = x0 + x1 + x2 + x3;
  float qq = x0 * x0 + x1 * x1 + x2 * x2 + x3 * x3;
#pragma unroll
  for (int o = 1; o < 64; o <<= 1) { s += __shfl_xor(s, o, 64); qq += __shfl_xor(qq, o, 64); }
  __shared__ float ss[4], qs[4];
  if ((t & 63) == 0) { ss[t >> 6] = s; qs[t >> 6] = qq; }
  __syncthreads();
  s = ss[0] + ss[1] + ss[2] + ss[3];
  qq = qs[0] + qs[1] + qs[2] + qs[3];
  const float mean = s * (1.f / 1024.f);
  const float var = qq * (1.f / 1024.f) - mean * mean;
  const float rstd = rsqrtf(var + 1e-5f);
  const float4 gv = *(const float4*)(g + t * 4);
  const float4 bev = *(const float4*)(be + t * 4);
  const float y0 = (x0 - mean) * rstd * gv.x + bev.x;
  const float y1 = (x1 - mean) * rstd * gv.y + bev.y;
  const float y2 = (x2 - mean) * rstd * gv.z + bev.z;
  const float y3 = (x3 - mean) * rstd * gv.w + bev.w;
  float4 r = {y0, y1, y2, y3};
  *(float4*)(oF + base) = r;
  if (oB) {
    bf16x4 o4 = {(__bf16)y0, (__bf16)y1, (__bf16)y2, (__bf16)y3};
    *(bf16x4*)(oB + base) = o4;
  }
}

extern "C" void kernel_launch(void* const* d_in, const int* in_sizes, int n_in,
                              void* d_out, int out_size, void* d_ws, size_t ws_size,
                              hipStream_t stream) {
  const float* src    = (const float*)d_in[0];
  const float* pos    = (const float*)d_in[1];
  const float* qw     = (const float*)d_in[3];
  const float* kw     = (const float*)d_in[4];
  const float* vw     = (const float*)d_in[5];
  const float* rw     = (const float*)d_in[6];
  const float* ow     = (const float*)d_in[7];
  const float* rwbias = (const float*)d_in[8];
  const float* rrbias = (const float*)d_in[9];
  const float* w1     = (const float*)d_in[10];
  const float* b1     = (const float*)d_in[11];
  const float* w2     = (const float*)d_in[12];
  const float* b2     = (const float*)d_in[13];
  const float* g1     = (const float*)d_in[14];
  const float* be1    = (const float*)d_in[15];
  const float* g2     = (const float*)d_in[16];
  const float* be2    = (const float*)d_in[17];
  float* out = (float*)d_out;

  char* p = (char*)d_ws;
  auto alloc = [&](size_t bytes) { char* r = p; p += (bytes + 255) & ~(size_t)255; return r; };
  // order chosen so split-K partials alias dead, CONTIGUOUS regions
  __bf16* qkB   = (__bf16*)alloc(4096ull * 2048 * 2);   // dead after attn
  __bf16* vTB   = (__bf16*)alloc(1024ull * 4096 * 2);   // dead after attn
  __bf16* kposB = (__bf16*)alloc(4100ull * 1024 * 2);   // dead after attn
  __bf16* avB   = (__bf16*)alloc(4096ull * 1024 * 2);   // dead after attn-out
  __bf16* srcB2 = (__bf16*)alloc(4096ull * 1024 * 2);   // dead after vT gemm
  __bf16* posB  = (__bf16*)alloc(4100ull * 1024 * 2);   // dead after kpos gemm
  float*  xF    = (float*)alloc(4096ull * 1024 * 4);
  __bf16* w2B   = (__bf16*)alloc(4096ull * 1024 * 2);
  __bf16* qkvT  = (__bf16*)alloc(3072ull * 1024 * 2);
  __bf16* rwT   = (__bf16*)alloc(1024ull * 1024 * 2);
  __bf16* owB   = (__bf16*)alloc(1024ull * 1024 * 2);
  __bf16* w1B   = (__bf16*)alloc(4096ull * 1024 * 2);   // dead after FFN1
  __bf16* xB    = (__bf16*)alloc(4096ull * 1024 * 2);   // dead after FFN1
  // aliases (disjoint lifetimes):
  __bf16* gB  = qkB;             // gelu 32MB over qkB+vTB+kposB
  float* aoP0 = (float*)srcB2;   // attn-out partial0 16MB over srcB2+posB
  float* aoP1 = xF;              // partial1 over xF (ln_fuse reads then writes same addr)
  float* ffP0 = (float*)avB;     // ffn2 partial0 16MB over avB+srcB2
  float* ffP1 = (float*)w1B;     // ffn2 partial1 16MB over w1B+xB

  cvt_perm_src<<<4096, 256, 0, stream>>>(src, srcB2);
  cvt4_kernel<<<3329, 256, 0, stream>>>(pos, posB, 1025, ow, owB, 256,
                                        w1, w1B, 1024, w2, w2B);
  tcvt4_kernel<<<dim3(32, 32, 4), dim3(32, 8), 0, stream>>>(
      qw, kw, vw, rw, qkvT, qkvT + 1024 * 1024, qkvT + 2048 * 1024, rwT);
  // projections
  gemm_bt<128, 128, 2><<<dim3(16, 32), 256, 0, stream>>>(srcB2, qkvT, nullptr, nullptr, qkB, nullptr, 4096, 2048, 1024, 1024);
  gemm_bt<128, 64, 2><<<dim3(64, 8), 256, 0, stream>>>(qkvT + 2048 * 1024, srcB2, nullptr, nullptr, vTB, nullptr, 1024, 4096, 1024, 1024);
  gemm_bt<128, 64, 2><<<dim3(16, 33), 256, 0, stream>>>(posB, rwT, nullptr, nullptr, kposB, nullptr, 4100, 1024, 1024, 1024);
  attn6<<<dim3(1024), 256, 0, stream>>>(qkB, vTB, kposB, rwbias, rrbias, avB);
  // attn-out: split-K=2 over K=1024
  gemm_bt<128, 128, 0><<<dim3(8, 32, 2), 256, 0, stream>>>(avB, owB, aoP0, aoP1, nullptr, nullptr, 4096, 1024, 1024, 512);
  ln_fuse<<<4096, 256, 0, stream>>>(src, aoP0, aoP1, nullptr, g1, be1, xF, xB);
  gemm_bt<128, 128, 1><<<dim3(32, 32), 256, 0, stream>>>(xB, w1B, nullptr, nullptr, gB, b1, 4096, 4096, 1024, 1024);
  // FFN2: split-K=2 over K=4096
  gemm_bt<128, 128, 0><<<dim3(8, 32, 2), 256, 0, stream>>>(gB, w2B, ffP0, ffP1, nullptr, nullptr, 4096, 1024, 4096, 2048);
  ln_fuse<<<4096, 256, 0, stream>>>(xF, ffP0, ffP1, b2, g2, be2, out, nullptr);
  (void)in_sizes; (void)n_in; (void)out_size; (void)ws_size;
}

// Round 8
// 346.920 us; speedup vs baseline: 4.0986x; 1.0007x over previous
//
#include <hip/hip_runtime.h>
#include <math.h>

typedef __bf16 bf16x8 __attribute__((ext_vector_type(8)));
typedef __bf16 bf16x4 __attribute__((ext_vector_type(4)));
typedef float f32x4 __attribute__((ext_vector_type(4)));

__device__ __forceinline__ void gload_lds16(const __bf16* g, __bf16* l) {
  __builtin_amdgcn_global_load_lds((const __attribute__((address_space(1))) void*)g,
                                   (__attribute__((address_space(3))) void*)l, 16, 0, 0);
}

__device__ __forceinline__ float gelu_exact(float v) {
  return 0.5f * v * (1.f + erff(v * 0.70710678118654752f));
}

// ---------------- fused prep: perm-src | 4x cvt | 4x transpose-cvt ----------------
__global__ __launch_bounds__(256) void prep_all(
    const float* __restrict__ src, __bf16* __restrict__ srcB2,
    const float* __restrict__ pos, __bf16* __restrict__ posB,
    const float* __restrict__ ow, __bf16* __restrict__ owB,
    const float* __restrict__ w1, __bf16* __restrict__ w1B,
    const float* __restrict__ w2, __bf16* __restrict__ w2B,
    const float* __restrict__ qw, const float* __restrict__ kw,
    const float* __restrict__ vw, const float* __restrict__ rw,
    __bf16* __restrict__ qkvT, __bf16* __restrict__ rwT) {
  __shared__ float t[32][33];
  int bid = blockIdx.x;
  const int tid = threadIdx.x;
  if (bid < 4096) {                       // src (i,b)-rows -> bf16 (b,i)-rows
    const int i = bid & 1023, b = bid >> 10;
    const float4 v = *(const float4*)(src + ((size_t)(i * 4 + b)) * 1024 + tid * 4);
    bf16x4 o = {(__bf16)v.x, (__bf16)v.y, (__bf16)v.z, (__bf16)v.w};
    *(bf16x4*)(srcB2 + (size_t)bid * 1024 + tid * 4) = o;
    return;
  }
  bid -= 4096;
  if (bid < 3329) {                       // straight converts
    const float* in; __bf16* out;
    if (bid < 1025) { in = pos; out = posB; }
    else if (bid < 1281) { bid -= 1025; in = ow; out = owB; }
    else if (bid < 2305) { bid -= 1281; in = w1; out = w1B; }
    else { bid -= 2305; in = w2; out = w2B; }
    const int base = bid * 4096 + tid * 4;
#pragma unroll
    for (int k2 = 0; k2 < 4; ++k2) {
      const int off = base + k2 * 1024;
      float4 v = *(const float4*)(in + off);
      bf16x4 o = {(__bf16)v.x, (__bf16)v.y, (__bf16)v.z, (__bf16)v.w};
      *(bf16x4*)(out + off) = o;
    }
    return;
  }
  bid -= 3329;                            // transpose-converts (4x 1024x1024)
  const int z = bid >> 10, rem = bid & 1023;
  const float* in; __bf16* out;
  switch (z) {
    case 0: in = qw; out = qkvT; break;
    case 1: in = kw; out = qkvT + 1024 * 1024; break;
    case 2: in = vw; out = qkvT + 2048 * 1024; break;
    default: in = rw; out = rwT; break;
  }
  const int c0 = (rem & 31) * 32, r0 = (rem >> 5) * 32;
  const int tx = tid & 31, ty = tid >> 5;
  for (int yy = ty; yy < 32; yy += 8)
    t[yy][tx] = in[(size_t)(r0 + yy) * 1024 + c0 + tx];
  __syncthreads();
  for (int yy = ty; yy < 32; yy += 8)
    out[(size_t)(c0 + yy) * 1024 + r0 + tx] = (__bf16)t[tx][yy];
}

// ---------------- bf16 MFMA GEMM body: C[M,N] = A[M,K] * BT[N,K]^T ----------------
// MODE 0: f32 C.  MODE 1: bf16 C = gelu(acc + bias[col]).  MODE 2: bf16 C.
// 2-phase double-buffered: one barrier/iter; stage(t+1) after the barrier.
template<int BM, int BN, int MODE>
__device__ __forceinline__ void gemm_body(
    const __bf16* __restrict__ A, const __bf16* __restrict__ BT,
    float* __restrict__ Cf, __bf16* __restrict__ Cb,
    const float* __restrict__ bias, int M, int N, int K,
    int kStart, int kChunk, int mBase, int nBase, char* smemRaw) {
  constexpr int BK = 32;
  constexpr int ALOAD = (BM * BK) / 2048;
  constexpr int BLOAD = (BN * BK) / 2048;
  __bf16* lA = (__bf16*)smemRaw;                       // [2][BM*BK]
  __bf16* lB = (__bf16*)(smemRaw + 4 * BM * BK);       // [2][BN*BK]
  const int tid = threadIdx.x;
  const int w = tid >> 6, l = tid & 63;
  const int lr = l & 15, lk = l >> 4;
  const int srow = tid >> 2;
  const int scol = (tid & 3) * 8;
  const int wbase = w * 512;

  const __bf16* aSrc[ALOAD];
  const __bf16* bSrc[BLOAD];
#pragma unroll
  for (int i = 0; i < ALOAD; ++i) {
    int grow = mBase + srow + i * 64;
    grow = grow < M ? grow : M - 1;
    aSrc[i] = A + (size_t)grow * K + kStart + scol;
  }
#pragma unroll
  for (int i = 0; i < BLOAD; ++i) {
    const int grow = nBase + srow + i * 64;
    bSrc[i] = BT + (size_t)grow * K + kStart + scol;
  }
  auto stage = [&](int buf) {
#pragma unroll
    for (int i = 0; i < ALOAD; ++i) {
      gload_lds16(aSrc[i], &lA[buf * BM * BK + i * 2048 + wbase]);
      aSrc[i] += BK;
    }
#pragma unroll
    for (int i = 0; i < BLOAD; ++i) {
      gload_lds16(bSrc[i], &lB[buf * BN * BK + i * 2048 + wbase]);
      bSrc[i] += BK;
    }
  };

  constexpr int WM = BM / 2, WN = BN / 2;
  constexpr int MF = WM / 16, NF = WN / 16;
  const int wr = w >> 1, wc = w & 1;
  f32x4 acc[MF][NF] = {};

  const int nIter = kChunk / BK;
  stage(0);
  int cur = 0;
#pragma unroll 1
  for (int t = 0; t < nIter; ++t) {
    __syncthreads();
    if (t + 1 < nIter) stage(cur ^ 1);
    bf16x8 af[MF], bfr[NF];
#pragma unroll
    for (int mi = 0; mi < MF; ++mi)
      af[mi] = *(const bf16x8*)&lA[cur * BM * BK + (wr * WM + mi * 16 + lr) * BK + lk * 8];
#pragma unroll
    for (int nj = 0; nj < NF; ++nj)
      bfr[nj] = *(const bf16x8*)&lB[cur * BN * BK + (wc * WN + nj * 16 + lr) * BK + lk * 8];
#pragma unroll
    for (int mi = 0; mi < MF; ++mi)
#pragma unroll
      for (int nj = 0; nj < NF; ++nj)
        acc[mi][nj] = __builtin_amdgcn_mfma_f32_16x16x32_bf16(af[mi], bfr[nj], acc[mi][nj], 0, 0, 0);
    cur ^= 1;
  }
#pragma unroll
  for (int mi = 0; mi < MF; ++mi) {
#pragma unroll
    for (int nj = 0; nj < NF; ++nj) {
      const int col = nBase + wc * WN + nj * 16 + lr;
      const int row0 = mBase + wr * WM + mi * 16 + lk * 4;
#pragma unroll
      for (int j = 0; j < 4; ++j) {
        const int row = row0 + j;
        if (row < M) {
          float v = acc[mi][nj][j];
          if constexpr (MODE == 1) {
            v = gelu_exact(v + bias[col]);
            Cb[(size_t)row * N + col] = (__bf16)v;
          } else if constexpr (MODE == 2) {
            Cb[(size_t)row * N + col] = (__bf16)v;
          } else {
            Cf[(size_t)row * N + col] = v;
          }
        }
      }
    }
  }
}

template<int BM, int BN, int MODE>
__global__ __launch_bounds__(256)
void gemm_bt(const __bf16* __restrict__ A, const __bf16* __restrict__ BT,
             float* __restrict__ Cf, float* __restrict__ Cf2,
             __bf16* __restrict__ Cb, const float* __restrict__ bias,
             int M, int N, int K, int kChunk) {
  __shared__ __align__(16) char smem[4 * (BM + BN) * 32];
  float* cf = (blockIdx.z == 1) ? Cf2 : Cf;
  gemm_body<BM, BN, MODE>(A, BT, cf, Cb, bias, M, N, K, blockIdx.z * kChunk,
                          kChunk, blockIdx.y * BM, blockIdx.x * BN, smem);
}

// ---- the three projection GEMMs in one launch (2064 blocks) ----
__global__ __launch_bounds__(256)
void proj3_kernel(const __bf16* __restrict__ srcB2, const __bf16* __restrict__ qkvT,
                  const __bf16* __restrict__ vwT, const __bf16* __restrict__ posB,
                  const __bf16* __restrict__ rwT, __bf16* __restrict__ qkB,
                  __bf16* __restrict__ vTB, __bf16* __restrict__ kposB) {
  __shared__ __align__(16) char smem[4 * (128 + 64) * 32];
  int bid = blockIdx.x;
  if (bid < 1024) {
    gemm_body<128, 64, 2>(srcB2, qkvT, nullptr, qkB, nullptr, 4096, 2048, 1024,
                          0, 1024, (bid >> 5) * 128, (bid & 31) * 64, smem);
  } else if (bid < 1536) {
    const int t = bid - 1024;
    gemm_body<128, 64, 2>(vwT, srcB2, nullptr, vTB, nullptr, 1024, 4096, 1024,
                          0, 1024, (t >> 6) * 128, (t & 63) * 64, smem);
  } else {
    const int t = bid - 1536;
    gemm_body<128, 64, 2>(posB, rwT, nullptr, kposB, nullptr, 4100, 1024, 1024,
                          0, 1024, (t >> 4) * 128, (t & 15) * 64, smem);
  }
}

// ---------------- MFMA rel-pos attention v7: 1 barrier/jt, dual q-frags ----------------
// qk bf16 [4096 (b*1024+i)][2048] (q|k); vT bf16 [1024 (n*64+d)][4096 (b*1024+j)]
// kpos bf16 [4100 (idx*4+b)][1024]; av bf16 rows (i*4+b)
// Swapped MFMAs -> thread owns q-row q=strip+lcol; sbd and P rows are wave-private
// (same-wave DS in-order), so only ONE barrier per jt (buffer rotation + vmcnt).
// Band G: rrel>0 batches use qhi (q rows i0+1..i0+64) so scatter row == q always;
// the single mixed tile (d0==0) gets a once-per-block col-0 fix pass.
__global__ __launch_bounds__(256)
void attn7(const __bf16* __restrict__ qk, const __bf16* __restrict__ vT,
           const __bf16* __restrict__ kpos, const float* __restrict__ rwbias,
           const float* __restrict__ rrbias, __bf16* __restrict__ av) {
  constexpr float ALPHA = 0.125f * 1.44269504088896f;
  constexpr int PB = 132;
  // 0:16K K dbuf | 16K:32K KP dbuf | 32K:48K VT dbuf | 48K:+8K P | then sbd [64][132]
  __shared__ __align__(16) char smem[74240];
  __bf16* sP  = (__bf16*)(smem + 49152);
  __bf16* sbd = (__bf16*)(smem + 57344);

  const int flat = blockIdx.x;
  const int xcd = flat & 7, rr_ = flat >> 3;
  const int bn = xcd * 8 + (rr_ >> 4);
  const int it = rr_ & 15;
  const int b = bn >> 4, n = bn & 15;
  const int i0 = it * 64;
  const int tid = threadIdx.x;
  const int l = tid & 63;
  const int lcol = l & 15, lk = l >> 4;
  const int strip = (tid >> 6) * 16;
  const int wbase = tid & 192;
  const int nh64 = n * 64;
  const int q = strip + lcol;

  const int rB = tid >> 3;
  const int cs8 = ((tid & 7) ^ (rB & 7)) * 8;

  // ---- q fragments: qac (rwb), qlo (rrb, rows i0+q), qhi (rrb, rows i0+q+1) ----
  bf16x8 qac[2], qlo[2], qhi[2];
  {
    const __bf16* qrow = qk + ((size_t)(b * 1024 + i0 + q)) * 2048 + nh64;
    int gH = i0 + q + 1; gH = gH < 1024 ? gH : 1023;
    const __bf16* qrowH = qk + ((size_t)(b * 1024 + gH)) * 2048 + nh64;
#pragma unroll
    for (int kk = 0; kk < 2; ++kk) {
      bf16x8 qv = *(const bf16x8*)(qrow + kk * 32 + lk * 8);
      bf16x8 qh = *(const bf16x8*)(qrowH + kk * 32 + lk * 8);
      const int dbase = nh64 + kk * 32 + lk * 8;
#pragma unroll
      for (int u = 0; u < 8; ++u) {
        const float rb = rrbias[dbase + u];
        qac[kk][u] = (__bf16)(((float)qv[u] + rwbias[dbase + u]) * ALPHA);
        qlo[kk][u] = (__bf16)(((float)qv[u] + rb) * ALPHA);
        qhi[kk][u] = (__bf16)(((float)qh[u] + rb) * ALPHA);
      }
    }
  }

  // ---- prologue stage: low band -> VTbuf1(temp), K0, KP0, VT0 ----
#pragma unroll
  for (int kq = 0; kq < 2; ++kq) {
    const int r = kq * 32 + rB;
    const int dst = (kq * 256 + wbase) * 8;
    gload_lds16(kpos + ((size_t)((960 - i0 + r) * 4 + b)) * 1024 + nh64 + cs8,
                (__bf16*)(smem + 40960) + dst);                       // low band (rrel<0)
    gload_lds16(qk + ((size_t)(b * 1024 + r)) * 2048 + 1024 + nh64 + cs8,
                (__bf16*)(smem) + dst);                               // K jt0
    const int rrel = r - i0;
    const int idx = (rrel <= 0) ? (1024 + rrel) : (rrel - 1);
    gload_lds16(kpos + ((size_t)(idx * 4 + b)) * 1024 + nh64 + cs8,
                (__bf16*)(smem + 16384) + dst);                       // KP jt0 batch
    gload_lds16(vT + ((size_t)(nh64 + r)) * 4096 + b * 1024 + cs8,
                (__bf16*)(smem + 32768) + dst);                       // VT jt0
  }
  __syncthreads();
  // ---- prologue G on low band (rrel in [-i0-64,-i0), all lo), rows q ----
  {
    __bf16* kpl = (__bf16*)(smem + 40960);
    const int colb0 = (-i0 - 64) & 127;
#pragma unroll
    for (int fb = 0; fb < 4; ++fb) {
      const int row = fb * 16 + lcol;
      f32x4 g = {};
#pragma unroll
      for (int kk = 0; kk < 2; ++kk) {
        bf16x8 a = *(const bf16x8*)&kpl[row * 64 + (((kk * 4 + lk) ^ (lcol & 7)) * 8)];
        g = __builtin_amdgcn_mfma_f32_16x16x32_bf16(a, qlo[kk], g, 0, 0, 0);
      }
      bf16x4 gw = {(__bf16)g[0], (__bf16)g[1], (__bf16)g[2], (__bf16)g[3]};
      *(bf16x4*)&sbd[q * PB + ((colb0 + fb * 16 + lk * 4) & 127)] = gw;
    }
  }
  __syncthreads();   // temp-band reads done before jt0 stages into VT buf1

  float zacc = 0.f;
  f32x4 oacc[4] = {};
  size_t kS = (size_t)(b * 1024 + 64 + rB) * 2048 + 1024 + nh64 + cs8;
  size_t vS = (size_t)(nh64 + rB) * 4096 + b * 1024 + 64 + cs8;

#pragma unroll 1
  for (int jt = 0; jt < 16; ++jt) {
    const int cur = jt & 1, nxt = cur ^ 1;
    const int d0 = jt * 64 - i0;
    __bf16* sK   = (__bf16*)(smem + cur * 8192);
    __bf16* sKn  = (__bf16*)(smem + nxt * 8192);
    __bf16* sKP  = (__bf16*)(smem + 16384 + cur * 8192);
    __bf16* sKPn = (__bf16*)(smem + 16384 + nxt * 8192);
    __bf16* sVT  = (__bf16*)(smem + 32768 + cur * 8192);
    __bf16* sVTn = (__bf16*)(smem + 32768 + nxt * 8192);
    // ---- stage jt+1 (K, KP, VT); OOB prefetch at jt=15 is never read ----
#pragma unroll
    for (int kq = 0; kq < 2; ++kq) {
      const int dst = (kq * 256 + wbase) * 8;
      gload_lds16(qk + kS + kq * 65536, sKn + dst);
      gload_lds16(vT + vS + kq * 131072, sVTn + dst);
      const int rreln = d0 + 64 + kq * 32 + rB;
      const int idx = (rreln <= 0) ? (1024 + rreln) : (rreln - 1);
      gload_lds16(kpos + ((size_t)(idx * 4 + b)) * 1024 + nh64 + cs8, sKPn + dst);
    }
    kS += 131072; vS += 64;
    // ---- G MFMA on current batch: hi frags for d0>=0, lo for d0<0; row = q ----
    {
      const bf16x8 qg0 = (d0 >= 0) ? qhi[0] : qlo[0];
      const bf16x8 qg1 = (d0 >= 0) ? qhi[1] : qlo[1];
#pragma unroll
      for (int fb = 0; fb < 4; ++fb) {
        const int row = fb * 16 + lcol;
        f32x4 g = {};
        g = __builtin_amdgcn_mfma_f32_16x16x32_bf16(
            *(const bf16x8*)&sKP[row * 64 + ((lk ^ (lcol & 7)) * 8)], qg0, g, 0, 0, 0);
        g = __builtin_amdgcn_mfma_f32_16x16x32_bf16(
            *(const bf16x8*)&sKP[row * 64 + (((4 + lk) ^ (lcol & 7)) * 8)], qg1, g, 0, 0, 0);
        bf16x4 gw = {(__bf16)g[0], (__bf16)g[1], (__bf16)g[2], (__bf16)g[3]};
        *(bf16x4*)&sbd[q * PB + ((d0 + fb * 16 + lk * 4) & 127)] = gw;
      }
      if (d0 == 0) {   // fix col rrel=0 (needs lo q-rows): once per block
        const int cl = tid >> 2, part = tid & 3;
        const __bf16* qs = qk + ((size_t)(b * 1024 + i0 + cl)) * 2048 + nh64 + part * 16;
        bf16x8 a0 = *(const bf16x8*)qs;
        bf16x8 a1 = *(const bf16x8*)(qs + 8);
        bf16x8 k0 = *(const bf16x8*)&sKP[(2 * part) * 8];       // row 0, swizzle 0
        bf16x8 k1 = *(const bf16x8*)&sKP[(2 * part + 1) * 8];
        float s64 = 0.f;
#pragma unroll
        for (int u = 0; u < 8; ++u)
          s64 += ((float)a0[u] + rrbias[nh64 + part * 16 + u]) * (float)k0[u]
               + ((float)a1[u] + rrbias[nh64 + part * 16 + 8 + u]) * (float)k1[u];
        s64 += __shfl_xor(s64, 1, 64);
        s64 += __shfl_xor(s64, 2, 64);
        if (part == 0) sbd[cl * PB] = (__bf16)(s64 * ALPHA);
      }
    }
    // ---- ac MFMA (swapped): sc[fk][jj] = S[jl=fk*16+lk*4+jj][q] ----
    f32x4 sc[4];
#pragma unroll
    for (int fk = 0; fk < 4; ++fk) {
      const int row = fk * 16 + lcol;
      f32x4 a = {};
#pragma unroll
      for (int kk = 0; kk < 2; ++kk) {
        bf16x8 kf = *(const bf16x8*)&sK[row * 64 + (((kk * 4 + lk) ^ (lcol & 7)) * 8)];
        a = __builtin_amdgcn_mfma_f32_16x16x32_bf16(kf, qac[kk], a, 0, 0, 0);
      }
      sc[fk] = a;
    }
    // ---- gather + exp2 + P store + Z (all wave-private rows; no barrier) ----
    {
      const int rowb = q * PB;
      const int sb = d0 - q;
#pragma unroll
      for (int fk = 0; fk < 4; ++fk) {
        const int cb = sb + fk * 16 + lk * 4;
        float e0 = exp2f(sc[fk][0] + (float)sbd[rowb + ((cb) & 127)]);
        float e1 = exp2f(sc[fk][1] + (float)sbd[rowb + ((cb + 1) & 127)]);
        float e2 = exp2f(sc[fk][2] + (float)sbd[rowb + ((cb + 2) & 127)]);
        float e3 = exp2f(sc[fk][3] + (float)sbd[rowb + ((cb + 3) & 127)]);
        zacc += e0 + e1 + e2 + e3;
        bf16x4 pw = {(__bf16)e0, (__bf16)e1, (__bf16)e2, (__bf16)e3};
        *(bf16x4*)&sP[q * 64 + (((fk * 2 + (lk >> 1)) ^ (q & 7)) * 8) + (lk & 1) * 4] = pw;
      }
    }
    // ---- PV MFMA: O[q'][d] += P[q'][jl] * VT[d][jl] ----
#pragma unroll
    for (int kk = 0; kk < 2; ++kk) {
      bf16x8 pa = *(const bf16x8*)&sP[q * 64 + (((kk * 4 + lk) ^ (q & 7)) * 8)];
#pragma unroll
      for (int fd = 0; fd < 4; ++fd) {
        const int vrow = fd * 16 + lcol;
        bf16x8 bv = *(const bf16x8*)&sVT[vrow * 64 + (((kk * 4 + lk) ^ (lcol & 7)) * 8)];
        oacc[fd] = __builtin_amdgcn_mfma_f32_16x16x32_bf16(pa, bv, oacc[fd], 0, 0, 0);
      }
    }
    __syncthreads();   // rotation: cur reads done; next-jt staging drained
  }
  // ---- epilogue ----
  float z = zacc;
  z += __shfl_xor(z, 16, 64);
  z += __shfl_xor(z, 32, 64);
#pragma unroll
  for (int jj = 0; jj < 4; ++jj) {
    const float rz = 1.f / __shfl(z, lk * 4 + jj, 16);
    const int ig = i0 + strip + lk * 4 + jj;
    __bf16* dst = av + ((size_t)(ig * 4 + b)) * 1024 + nh64;
#pragma unroll
    for (int fd = 0; fd < 4; ++fd)
      dst[fd * 16 + lcol] = (__bf16)(oacc[fd][jj] * rz);
  }
}

// ---------------- fused residual + LayerNorm (up to 2 partial addends) ----------------
__global__ __launch_bounds__(256)
void ln_fuse(const float* __restrict__ A, const float* __restrict__ Bv,
             const float* __restrict__ Bv2, const float* __restrict__ cb,
             const float* __restrict__ g, const float* __restrict__ be,
             float* __restrict__ oF, __bf16* __restrict__ oB) {
  const int row = blockIdx.x, t = threadIdx.x;
  const size_t base = (size_t)row * 1024 + t * 4;
  const float4 a = *(const float4*)(A + base);
  const float4 bb = *(const float4*)(Bv + base);
  float x0 = a.x + bb.x, x1 = a.y + bb.y, x2 = a.z + bb.z, x3 = a.w + bb.w;
  if (Bv2) {
    const float4 c = *(const float4*)(Bv2 + base);
    x0 += c.x; x1 += c.y; x2 += c.z; x3 += c.w;
  }
  if (cb) {
    const float4 c = *(const float4*)(cb + t * 4);
    x0 += c.x; x1 += c.y; x2 += c.z; x3 += c.w;
  }
  float s = x0 + x1 + x2 + x3;
  float qq = x0 * x0 + x1 * x1 + x2 * x2 + x3 * x3;
#pragma unroll
  for (int o = 1; o < 64; o <<= 1) { s += __shfl_xor(s, o, 64); qq += __shfl_xor(qq, o, 64); }
  __shared__ float ss[4], qs[4];
  if ((t & 63) == 0) { ss[t >> 6] = s; qs[t >> 6] = qq; }
  __syncthreads();
  s = ss[0] + ss[1] + ss[2] + ss[3];
  qq = qs[0] + qs[1] + qs[2] + qs[3];
  const float mean = s * (1.f / 1024.f);
  const float var = qq * (1.f / 1024.f) - mean * mean;
  const float rstd = rsqrtf(var + 1e-5f);
  const float4 gv = *(const float4*)(g + t * 4);
  const float4 bev = *(const float4*)(be + t * 4);
  const float y0 = (x0 - mean) * rstd * gv.x + bev.x;
  const float y1 = (x1 - mean) * rstd * gv.y + bev.y;
  const float y2 = (x2 - mean) * rstd * gv.z + bev.z;
  const float y3 = (x3 - mean) * rstd * gv.w + bev.w;
  float4 r = {y0, y1, y2, y3};
  *(float4*)(oF + base) = r;
  if (oB) {
    bf16x4 o4 = {(__bf16)y0, (__bf16)y1, (__bf16)y2, (__bf16)y3};
    *(bf16x4*)(oB + base) = o4;
  }
}

extern "C" void kernel_launch(void* const* d_in, const int* in_sizes, int n_in,
                              void* d_out, int out_size, void* d_ws, size_t ws_size,
                              hipStream_t stream) {
  const float* src    = (const float*)d_in[0];
  const float* pos    = (const float*)d_in[1];
  const float* qw     = (const float*)d_in[3];
  const float* kw     = (const float*)d_in[4];
  const float* vw     = (const float*)d_in[5];
  const float* rw     = (const float*)d_in[6];
  const float* ow     = (const float*)d_in[7];
  const float* rwbias = (const float*)d_in[8];
  const float* rrbias = (const float*)d_in[9];
  const float* w1     = (const float*)d_in[10];
  const float* b1     = (const float*)d_in[11];
  const float* w2     = (const float*)d_in[12];
  const float* b2     = (const float*)d_in[13];
  const float* g1     = (const float*)d_in[14];
  const float* be1    = (const float*)d_in[15];
  const float* g2     = (const float*)d_in[16];
  const float* be2    = (const float*)d_in[17];
  float* out = (float*)d_out;

  char* p = (char*)d_ws;
  auto alloc = [&](size_t bytes) { char* r = p; p += (bytes + 255) & ~(size_t)255; return r; };
  __bf16* qkB   = (__bf16*)alloc(4096ull * 2048 * 2);   // dead after attn
  __bf16* vTB   = (__bf16*)alloc(1024ull * 4096 * 2);   // dead after attn
  __bf16* kposB = (__bf16*)alloc(4100ull * 1024 * 2);   // dead after attn
  __bf16* avB   = (__bf16*)alloc(4096ull * 1024 * 2);   // dead after attn-out
  __bf16* srcB2 = (__bf16*)alloc(4096ull * 1024 * 2);   // dead after proj3
  __bf16* posB  = (__bf16*)alloc(4100ull * 1024 * 2);   // dead after proj3
  float*  xF    = (float*)alloc(4096ull * 1024 * 4);
  __bf16* w2B   = (__bf16*)alloc(4096ull * 1024 * 2);
  __bf16* qkvT  = (__bf16*)alloc(3072ull * 1024 * 2);
  __bf16* rwT   = (__bf16*)alloc(1024ull * 1024 * 2);
  __bf16* owB   = (__bf16*)alloc(1024ull * 1024 * 2);
  __bf16* w1B   = (__bf16*)alloc(4096ull * 1024 * 2);   // dead after FFN1
  __bf16* xB    = (__bf16*)alloc(4096ull * 1024 * 2);   // dead after FFN1
  // aliases (disjoint lifetimes):
  __bf16* gB  = qkB;             // gelu 32MB over qkB+vTB+kposB
  float* aoP0 = (float*)srcB2;   // attn-out partial0 16MB over srcB2+posB
  float* aoP1 = xF;              // partial1 over xF (ln reads then writes same addr)
  float* ffP0 = (float*)avB;     // ffn2 partial0 16MB over avB+srcB2
  float* ffP1 = (float*)w1B;     // ffn2 partial1 16MB over w1B+xB

  prep_all<<<11521, 256, 0, stream>>>(src, srcB2, pos, posB, ow, owB, w1, w1B,
                                      w2, w2B, qw, kw, vw, rw, qkvT, rwT);
  proj3_kernel<<<2064, 256, 0, stream>>>(srcB2, qkvT, qkvT + 2048 * 1024, posB,
                                         rwT, qkB, vTB, kposB);
  attn7<<<dim3(1024), 256, 0, stream>>>(qkB, vTB, kposB, rwbias, rrbias, avB);
  gemm_bt<128, 64, 0><<<dim3(16, 32, 2), 256, 0, stream>>>(avB, owB, aoP0, aoP1, nullptr, nullptr, 4096, 1024, 1024, 512);
  ln_fuse<<<4096, 256, 0, stream>>>(src, aoP0, aoP1, nullptr, g1, be1, xF, xB);
  gemm_bt<128, 128, 1><<<dim3(32, 32), 256, 0, stream>>>(xB, w1B, nullptr, nullptr, gB, b1, 4096, 4096, 1024, 1024);
  gemm_bt<128, 64, 0><<<dim3(16, 32, 2), 256, 0, stream>>>(gB, w2B, ffP0, ffP1, nullptr, nullptr, 4096, 1024, 4096, 2048);
  ln_fuse<<<4096, 256, 0, stream>>>(xF, ffP0, ffP1, b2, g2, be2, out, nullptr);
  (void)in_sizes; (void)n_in; (void)out_size; (void)ws_size;
}

// Round 9
// 330.117 us; speedup vs baseline: 4.3072x; 1.0509x over previous
//
#include <hip/hip_runtime.h>
#include <math.h>

typedef __bf16 bf16x8 __attribute__((ext_vector_type(8)));
typedef __bf16 bf16x4 __attribute__((ext_vector_type(4)));
typedef float f32x4 __attribute__((ext_vector_type(4)));

__device__ __forceinline__ void gload_lds16(const __bf16* g, __bf16* l) {
  __builtin_amdgcn_global_load_lds((const __attribute__((address_space(1))) void*)g,
                                   (__attribute__((address_space(3))) void*)l, 16, 0, 0);
}

__device__ __forceinline__ float gelu_exact(float v) {
  return 0.5f * v * (1.f + erff(v * 0.70710678118654752f));
}

// ---------------- fused prep: perm-src | 4x cvt | 4x transpose-cvt ----------------
__global__ __launch_bounds__(256) void prep_all(
    const float* __restrict__ src, __bf16* __restrict__ srcB2,
    const float* __restrict__ pos, __bf16* __restrict__ posB,
    const float* __restrict__ ow, __bf16* __restrict__ owB,
    const float* __restrict__ w1, __bf16* __restrict__ w1B,
    const float* __restrict__ w2, __bf16* __restrict__ w2B,
    const float* __restrict__ qw, const float* __restrict__ kw,
    const float* __restrict__ vw, const float* __restrict__ rw,
    __bf16* __restrict__ qkvT, __bf16* __restrict__ rwT) {
  __shared__ float t[32][33];
  int bid = blockIdx.x;
  const int tid = threadIdx.x;
  if (bid < 4096) {                       // src (i,b)-rows -> bf16 (b,i)-rows
    const int i = bid & 1023, b = bid >> 10;
    const float4 v = *(const float4*)(src + ((size_t)(i * 4 + b)) * 1024 + tid * 4);
    bf16x4 o = {(__bf16)v.x, (__bf16)v.y, (__bf16)v.z, (__bf16)v.w};
    *(bf16x4*)(srcB2 + (size_t)bid * 1024 + tid * 4) = o;
    return;
  }
  bid -= 4096;
  if (bid < 3329) {                       // straight converts
    const float* in; __bf16* out;
    if (bid < 1025) { in = pos; out = posB; }
    else if (bid < 1281) { bid -= 1025; in = ow; out = owB; }
    else if (bid < 2305) { bid -= 1281; in = w1; out = w1B; }
    else { bid -= 2305; in = w2; out = w2B; }
    const int base = bid * 4096 + tid * 4;
#pragma unroll
    for (int k2 = 0; k2 < 4; ++k2) {
      const int off = base + k2 * 1024;
      float4 v = *(const float4*)(in + off);
      bf16x4 o = {(__bf16)v.x, (__bf16)v.y, (__bf16)v.z, (__bf16)v.w};
      *(bf16x4*)(out + off) = o;
    }
    return;
  }
  bid -= 3329;                            // transpose-converts (4x 1024x1024)
  const int z = bid >> 10, rem = bid & 1023;
  const float* in; __bf16* out;
  switch (z) {
    case 0: in = qw; out = qkvT; break;
    case 1: in = kw; out = qkvT + 1024 * 1024; break;
    case 2: in = vw; out = qkvT + 2048 * 1024; break;
    default: in = rw; out = rwT; break;
  }
  const int c0 = (rem & 31) * 32, r0 = (rem >> 5) * 32;
  const int tx = tid & 31, ty = tid >> 5;
  for (int yy = ty; yy < 32; yy += 8)
    t[yy][tx] = in[(size_t)(r0 + yy) * 1024 + c0 + tx];
  __syncthreads();
  for (int yy = ty; yy < 32; yy += 8)
    out[(size_t)(c0 + yy) * 1024 + r0 + tx] = (__bf16)t[tx][yy];
}

// ---------------- bf16 MFMA GEMM body: C[M,N] = A[M,K] * BT[N,K]^T ----------------
// MODE 0: f32 C.  MODE 1: bf16 C = gelu(acc + bias[col]).  MODE 2: bf16 C.
// 2-phase double-buffered: one barrier/iter; stage(t+1) after the barrier.
template<int BM, int BN, int MODE>
__device__ __forceinline__ void gemm_body(
    const __bf16* __restrict__ A, const __bf16* __restrict__ BT,
    float* __restrict__ Cf, __bf16* __restrict__ Cb,
    const float* __restrict__ bias, int M, int N, int K,
    int kStart, int kChunk, int mBase, int nBase, char* smemRaw) {
  constexpr int BK = 32;
  constexpr int ALOAD = (BM * BK) / 2048;
  constexpr int BLOAD = (BN * BK) / 2048;
  __bf16* lA = (__bf16*)smemRaw;                       // [2][BM*BK]
  __bf16* lB = (__bf16*)(smemRaw + 4 * BM * BK);       // [2][BN*BK]
  const int tid = threadIdx.x;
  const int w = tid >> 6, l = tid & 63;
  const int lr = l & 15, lk = l >> 4;
  const int srow = tid >> 2;
  const int scol = (tid & 3) * 8;
  const int wbase = w * 512;

  const __bf16* aSrc[ALOAD];
  const __bf16* bSrc[BLOAD];
#pragma unroll
  for (int i = 0; i < ALOAD; ++i) {
    int grow = mBase + srow + i * 64;
    grow = grow < M ? grow : M - 1;
    aSrc[i] = A + (size_t)grow * K + kStart + scol;
  }
#pragma unroll
  for (int i = 0; i < BLOAD; ++i) {
    const int grow = nBase + srow + i * 64;
    bSrc[i] = BT + (size_t)grow * K + kStart + scol;
  }
  auto stage = [&](int buf) {
#pragma unroll
    for (int i = 0; i < ALOAD; ++i) {
      gload_lds16(aSrc[i], &lA[buf * BM * BK + i * 2048 + wbase]);
      aSrc[i] += BK;
    }
#pragma unroll
    for (int i = 0; i < BLOAD; ++i) {
      gload_lds16(bSrc[i], &lB[buf * BN * BK + i * 2048 + wbase]);
      bSrc[i] += BK;
    }
  };

  constexpr int WM = BM / 2, WN = BN / 2;
  constexpr int MF = WM / 16, NF = WN / 16;
  const int wr = w >> 1, wc = w & 1;
  f32x4 acc[MF][NF] = {};

  const int nIter = kChunk / BK;
  stage(0);
  int cur = 0;
#pragma unroll 1
  for (int t = 0; t < nIter; ++t) {
    __syncthreads();
    if (t + 1 < nIter) stage(cur ^ 1);
    bf16x8 af[MF], bfr[NF];
#pragma unroll
    for (int mi = 0; mi < MF; ++mi)
      af[mi] = *(const bf16x8*)&lA[cur * BM * BK + (wr * WM + mi * 16 + lr) * BK + lk * 8];
#pragma unroll
    for (int nj = 0; nj < NF; ++nj)
      bfr[nj] = *(const bf16x8*)&lB[cur * BN * BK + (wc * WN + nj * 16 + lr) * BK + lk * 8];
#pragma unroll
    for (int mi = 0; mi < MF; ++mi)
#pragma unroll
      for (int nj = 0; nj < NF; ++nj)
        acc[mi][nj] = __builtin_amdgcn_mfma_f32_16x16x32_bf16(af[mi], bfr[nj], acc[mi][nj], 0, 0, 0);
    cur ^= 1;
  }
#pragma unroll
  for (int mi = 0; mi < MF; ++mi) {
#pragma unroll
    for (int nj = 0; nj < NF; ++nj) {
      const int col = nBase + wc * WN + nj * 16 + lr;
      const int row0 = mBase + wr * WM + mi * 16 + lk * 4;
#pragma unroll
      for (int j = 0; j < 4; ++j) {
        const int row = row0 + j;
        if (row < M) {
          float v = acc[mi][nj][j];
          if constexpr (MODE == 1) {
            v = gelu_exact(v + bias[col]);
            Cb[(size_t)row * N + col] = (__bf16)v;
          } else if constexpr (MODE == 2) {
            Cb[(size_t)row * N + col] = (__bf16)v;
          } else {
            Cf[(size_t)row * N + col] = v;
          }
        }
      }
    }
  }
}

// XCD-chunked swizzle (bijective; grid.x*grid.y % 8 == 0): each XCD gets a
// contiguous band of tiles so panel reuse hits its own L2.
template<int BM, int BN, int MODE>
__global__ __launch_bounds__(256)
void gemm_bt(const __bf16* __restrict__ A, const __bf16* __restrict__ BT,
             float* __restrict__ Cf, float* __restrict__ Cf2,
             __bf16* __restrict__ Cb, const float* __restrict__ bias,
             int M, int N, int K, int kChunk) {
  __shared__ __align__(16) char smem[4 * (BM + BN) * 32];
  float* cf = (blockIdx.z == 1) ? Cf2 : Cf;
  const int gx = gridDim.x;
  const int G = gx * gridDim.y;
  const int flat = blockIdx.y * gx + blockIdx.x;
  const int swz = (flat & 7) * (G >> 3) + (flat >> 3);
  const int nx = swz % gx, ny = swz / gx;
  gemm_body<BM, BN, MODE>(A, BT, cf, Cb, bias, M, N, K, blockIdx.z * kChunk,
                          kChunk, ny * BM, nx * BN, smem);
}

// ---- the three projection GEMMs in one launch (2064 blocks, XCD-chunked) ----
__global__ __launch_bounds__(256)
void proj3_kernel(const __bf16* __restrict__ srcB2, const __bf16* __restrict__ qkvT,
                  const __bf16* __restrict__ vwT, const __bf16* __restrict__ posB,
                  const __bf16* __restrict__ rwT, __bf16* __restrict__ qkB,
                  __bf16* __restrict__ vTB, __bf16* __restrict__ kposB) {
  __shared__ __align__(16) char smem[4 * (128 + 64) * 32];
  const int raw = blockIdx.x;
  int bid = (raw & 7) * 258 + (raw >> 3);   // 2064/8 = 258 per XCD
  if (bid < 1024) {
    gemm_body<128, 64, 2>(srcB2, qkvT, nullptr, qkB, nullptr, 4096, 2048, 1024,
                          0, 1024, (bid >> 5) * 128, (bid & 31) * 64, smem);
  } else if (bid < 1536) {
    const int t = bid - 1024;
    gemm_body<128, 64, 2>(vwT, srcB2, nullptr, vTB, nullptr, 1024, 4096, 1024,
                          0, 1024, (t >> 6) * 128, (t & 63) * 64, smem);
  } else {
    const int t = bid - 1536;
    gemm_body<128, 64, 2>(posB, rwT, nullptr, kposB, nullptr, 4100, 1024, 1024,
                          0, 1024, (t >> 4) * 128, (t & 15) * 64, smem);
  }
}

// ---------------- MFMA rel-pos attention v8: Z via ones-MFMA ----------------
// qk bf16 [4096 (b*1024+i)][2048] (q|k); vT bf16 [1024 (n*64+d)][4096 (b*1024+j)]
// kpos bf16 [4100 (idx*4+b)][1024]; av bf16 rows (i*4+b)
// Swapped MFMAs -> thread owns q-row q=strip+lcol; sbd and P rows are wave-private,
// so ONE barrier per jt. Z computed as mfma(P, ones) on the idle matrix pipe;
// zq[jj] lands exactly on the q-row this thread stores.
__global__ __launch_bounds__(256)
void attn8(const __bf16* __restrict__ qk, const __bf16* __restrict__ vT,
           const __bf16* __restrict__ kpos, const float* __restrict__ rwbias,
           const float* __restrict__ rrbias, __bf16* __restrict__ av) {
  constexpr float ALPHA = 0.125f * 1.44269504088896f;
  constexpr int PB = 132;
  // 0:16K K dbuf | 16K:32K KP dbuf | 32K:48K VT dbuf | 48K:+8K P | then sbd [64][132]
  __shared__ __align__(16) char smem[74240];
  __bf16* sP  = (__bf16*)(smem + 49152);
  __bf16* sbd = (__bf16*)(smem + 57344);

  const int flat = blockIdx.x;
  const int xcd = flat & 7, rr_ = flat >> 3;
  const int bn = xcd * 8 + (rr_ >> 4);
  const int it = rr_ & 15;
  const int b = bn >> 4, n = bn & 15;
  const int i0 = it * 64;
  const int tid = threadIdx.x;
  const int l = tid & 63;
  const int lcol = l & 15, lk = l >> 4;
  const int strip = (tid >> 6) * 16;
  const int wbase = tid & 192;
  const int nh64 = n * 64;
  const int q = strip + lcol;

  const int rB = tid >> 3;
  const int cs8 = ((tid & 7) ^ (rB & 7)) * 8;

  bf16x8 onesf;
#pragma unroll
  for (int u = 0; u < 8; ++u) onesf[u] = (__bf16)1.0f;

  // ---- q fragments: qac (rwb), qlo (rrb, rows i0+q), qhi (rrb, rows i0+q+1) ----
  bf16x8 qac[2], qlo[2], qhi[2];
  {
    const __bf16* qrow = qk + ((size_t)(b * 1024 + i0 + q)) * 2048 + nh64;
    int gH = i0 + q + 1; gH = gH < 1024 ? gH : 1023;
    const __bf16* qrowH = qk + ((size_t)(b * 1024 + gH)) * 2048 + nh64;
#pragma unroll
    for (int kk = 0; kk < 2; ++kk) {
      bf16x8 qv = *(const bf16x8*)(qrow + kk * 32 + lk * 8);
      bf16x8 qh = *(const bf16x8*)(qrowH + kk * 32 + lk * 8);
      const int dbase = nh64 + kk * 32 + lk * 8;
#pragma unroll
      for (int u = 0; u < 8; ++u) {
        const float rb = rrbias[dbase + u];
        qac[kk][u] = (__bf16)(((float)qv[u] + rwbias[dbase + u]) * ALPHA);
        qlo[kk][u] = (__bf16)(((float)qv[u] + rb) * ALPHA);
        qhi[kk][u] = (__bf16)(((float)qh[u] + rb) * ALPHA);
      }
    }
  }

  // ---- prologue stage: low band -> VTbuf1(temp), K0, KP0, VT0 ----
#pragma unroll
  for (int kq = 0; kq < 2; ++kq) {
    const int r = kq * 32 + rB;
    const int dst = (kq * 256 + wbase) * 8;
    gload_lds16(kpos + ((size_t)((960 - i0 + r) * 4 + b)) * 1024 + nh64 + cs8,
                (__bf16*)(smem + 40960) + dst);                       // low band (rrel<0)
    gload_lds16(qk + ((size_t)(b * 1024 + r)) * 2048 + 1024 + nh64 + cs8,
                (__bf16*)(smem) + dst);                               // K jt0
    const int rrel = r - i0;
    const int idx = (rrel <= 0) ? (1024 + rrel) : (rrel - 1);
    gload_lds16(kpos + ((size_t)(idx * 4 + b)) * 1024 + nh64 + cs8,
                (__bf16*)(smem + 16384) + dst);                       // KP jt0 batch
    gload_lds16(vT + ((size_t)(nh64 + r)) * 4096 + b * 1024 + cs8,
                (__bf16*)(smem + 32768) + dst);                       // VT jt0
  }
  __syncthreads();
  // ---- prologue G on low band (rrel in [-i0-64,-i0), all lo), rows q ----
  {
    __bf16* kpl = (__bf16*)(smem + 40960);
    const int colb0 = (-i0 - 64) & 127;
#pragma unroll
    for (int fb = 0; fb < 4; ++fb) {
      const int row = fb * 16 + lcol;
      f32x4 g = {};
#pragma unroll
      for (int kk = 0; kk < 2; ++kk) {
        bf16x8 a = *(const bf16x8*)&kpl[row * 64 + (((kk * 4 + lk) ^ (lcol & 7)) * 8)];
        g = __builtin_amdgcn_mfma_f32_16x16x32_bf16(a, qlo[kk], g, 0, 0, 0);
      }
      bf16x4 gw = {(__bf16)g[0], (__bf16)g[1], (__bf16)g[2], (__bf16)g[3]};
      *(bf16x4*)&sbd[q * PB + ((colb0 + fb * 16 + lk * 4) & 127)] = gw;
    }
  }
  __syncthreads();   // temp-band reads done before jt0 stages into VT buf1

  f32x4 oacc[4] = {};
  f32x4 zq = {};
  size_t kS = (size_t)(b * 1024 + 64 + rB) * 2048 + 1024 + nh64 + cs8;
  size_t vS = (size_t)(nh64 + rB) * 4096 + b * 1024 + 64 + cs8;

#pragma unroll 1
  for (int jt = 0; jt < 16; ++jt) {
    const int cur = jt & 1, nxt = cur ^ 1;
    const int d0 = jt * 64 - i0;
    __bf16* sK   = (__bf16*)(smem + cur * 8192);
    __bf16* sKn  = (__bf16*)(smem + nxt * 8192);
    __bf16* sKP  = (__bf16*)(smem + 16384 + cur * 8192);
    __bf16* sKPn = (__bf16*)(smem + 16384 + nxt * 8192);
    __bf16* sVT  = (__bf16*)(smem + 32768 + cur * 8192);
    __bf16* sVTn = (__bf16*)(smem + 32768 + nxt * 8192);
    // ---- stage jt+1 (K, KP, VT); OOB prefetch at jt=15 is never read ----
#pragma unroll
    for (int kq = 0; kq < 2; ++kq) {
      const int dst = (kq * 256 + wbase) * 8;
      gload_lds16(qk + kS + kq * 65536, sKn + dst);
      gload_lds16(vT + vS + kq * 131072, sVTn + dst);
      const int rreln = d0 + 64 + kq * 32 + rB;
      const int idx = (rreln <= 0) ? (1024 + rreln) : (rreln - 1);
      gload_lds16(kpos + ((size_t)(idx * 4 + b)) * 1024 + nh64 + cs8, sKPn + dst);
    }
    kS += 131072; vS += 64;
    // ---- G MFMA on current batch: hi frags for d0>=0, lo for d0<0; row = q ----
    {
      const bf16x8 qg0 = (d0 >= 0) ? qhi[0] : qlo[0];
      const bf16x8 qg1 = (d0 >= 0) ? qhi[1] : qlo[1];
#pragma unroll
      for (int fb = 0; fb < 4; ++fb) {
        const int row = fb * 16 + lcol;
        f32x4 g = {};
        g = __builtin_amdgcn_mfma_f32_16x16x32_bf16(
            *(const bf16x8*)&sKP[row * 64 + ((lk ^ (lcol & 7)) * 8)], qg0, g, 0, 0, 0);
        g = __builtin_amdgcn_mfma_f32_16x16x32_bf16(
            *(const bf16x8*)&sKP[row * 64 + (((4 + lk) ^ (lcol & 7)) * 8)], qg1, g, 0, 0, 0);
        bf16x4 gw = {(__bf16)g[0], (__bf16)g[1], (__bf16)g[2], (__bf16)g[3]};
        *(bf16x4*)&sbd[q * PB + ((d0 + fb * 16 + lk * 4) & 127)] = gw;
      }
      if (d0 == 0) {   // fix col rrel=0 (needs lo q-rows): once per block
        const int cl = tid >> 2, part = tid & 3;
        const __bf16* qs = qk + ((size_t)(b * 1024 + i0 + cl)) * 2048 + nh64 + part * 16;
        bf16x8 a0 = *(const bf16x8*)qs;
        bf16x8 a1 = *(const bf16x8*)(qs + 8);
        bf16x8 k0 = *(const bf16x8*)&sKP[(2 * part) * 8];       // row 0, swizzle 0
        bf16x8 k1 = *(const bf16x8*)&sKP[(2 * part + 1) * 8];
        float s64 = 0.f;
#pragma unroll
        for (int u = 0; u < 8; ++u)
          s64 += ((float)a0[u] + rrbias[nh64 + part * 16 + u]) * (float)k0[u]
               + ((float)a1[u] + rrbias[nh64 + part * 16 + 8 + u]) * (float)k1[u];
        s64 += __shfl_xor(s64, 1, 64);
        s64 += __shfl_xor(s64, 2, 64);
        if (part == 0) sbd[cl * PB] = (__bf16)(s64 * ALPHA);
      }
    }
    // ---- ac MFMA (swapped): sc[fk][jj] = S[jl=fk*16+lk*4+jj][q] ----
    f32x4 sc[4];
#pragma unroll
    for (int fk = 0; fk < 4; ++fk) {
      const int row = fk * 16 + lcol;
      f32x4 a = {};
#pragma unroll
      for (int kk = 0; kk < 2; ++kk) {
        bf16x8 kf = *(const bf16x8*)&sK[row * 64 + (((kk * 4 + lk) ^ (lcol & 7)) * 8)];
        a = __builtin_amdgcn_mfma_f32_16x16x32_bf16(kf, qac[kk], a, 0, 0, 0);
      }
      sc[fk] = a;
    }
    // ---- gather + exp2 + P store (wave-private rows; no barrier) ----
    {
      const int rowb = q * PB;
      const int sb = d0 - q;
#pragma unroll
      for (int fk = 0; fk < 4; ++fk) {
        const int cb = sb + fk * 16 + lk * 4;
        float e0 = exp2f(sc[fk][0] + (float)sbd[rowb + ((cb) & 127)]);
        float e1 = exp2f(sc[fk][1] + (float)sbd[rowb + ((cb + 1) & 127)]);
        float e2 = exp2f(sc[fk][2] + (float)sbd[rowb + ((cb + 2) & 127)]);
        float e3 = exp2f(sc[fk][3] + (float)sbd[rowb + ((cb + 3) & 127)]);
        bf16x4 pw = {(__bf16)e0, (__bf16)e1, (__bf16)e2, (__bf16)e3};
        *(bf16x4*)&sP[q * 64 + (((fk * 2 + (lk >> 1)) ^ (q & 7)) * 8) + (lk & 1) * 4] = pw;
      }
    }
    // ---- PV MFMA + Z-ones MFMA ----
#pragma unroll
    for (int kk = 0; kk < 2; ++kk) {
      bf16x8 pa = *(const bf16x8*)&sP[q * 64 + (((kk * 4 + lk) ^ (q & 7)) * 8)];
      zq = __builtin_amdgcn_mfma_f32_16x16x32_bf16(pa, onesf, zq, 0, 0, 0);
#pragma unroll
      for (int fd = 0; fd < 4; ++fd) {
        const int vrow = fd * 16 + lcol;
        bf16x8 bv = *(const bf16x8*)&sVT[vrow * 64 + (((kk * 4 + lk) ^ (lcol & 7)) * 8)];
        oacc[fd] = __builtin_amdgcn_mfma_f32_16x16x32_bf16(pa, bv, oacc[fd], 0, 0, 0);
      }
    }
    __syncthreads();   // rotation: cur reads done; next-jt staging drained
  }
  // ---- epilogue: zq[jj] is Z for exactly the row this thread stores ----
#pragma unroll
  for (int jj = 0; jj < 4; ++jj) {
    const float rz = 1.f / zq[jj];
    const int ig = i0 + strip + lk * 4 + jj;
    __bf16* dst = av + ((size_t)(ig * 4 + b)) * 1024 + nh64;
#pragma unroll
    for (int fd = 0; fd < 4; ++fd)
      dst[fd * 16 + lcol] = (__bf16)(oacc[fd][jj] * rz);
  }
}

// ---------------- fused residual + LayerNorm (up to 2 partial addends) ----------------
__global__ __launch_bounds__(256)
void ln_fuse(const float* __restrict__ A, const float* __restrict__ Bv,
             const float* __restrict__ Bv2, const float* __restrict__ cb,
             const float* __restrict__ g, const float* __restrict__ be,
             float* __restrict__ oF, __bf16* __restrict__ oB) {
  const int row = blockIdx.x, t = threadIdx.x;
  const size_t base = (size_t)row * 1024 + t * 4;
  const float4 a = *(const float4*)(A + base);
  const float4 bb = *(const float4*)(Bv + base);
  float x0 = a.x + bb.x, x1 = a.y + bb.y, x2 = a.z + bb.z, x3 = a.w + bb.w;
  if (Bv2) {
    const float4 c = *(const float4*)(Bv2 + base);
    x0 += c.x; x1 += c.y; x2 += c.z; x3 += c.w;
  }
  if (cb) {
    const float4 c = *(const float4*)(cb + t * 4);
    x0 += c.x; x1 += c.y; x2 += c.z; x3 += c.w;
  }
  float s = x0 + x1 + x2 + x3;
  float qq = x0 * x0 + x1 * x1 + x2 * x2 + x3 * x3;
#pragma unroll
  for (int o = 1; o < 64; o <<= 1) { s += __shfl_xor(s, o, 64); qq += __shfl_xor(qq, o, 64); }
  __shared__ float ss[4], qs[4];
  if ((t & 63) == 0) { ss[t >> 6] = s; qs[t >> 6] = qq; }
  __syncthreads();
  s = ss[0] + ss[1] + ss[2] + ss[3];
  qq = qs[0] + qs[1] + qs[2] + qs[3];
  const float mean = s * (1.f / 1024.f);
  const float var = qq * (1.f / 1024.f) - mean * mean;
  const float rstd = rsqrtf(var + 1e-5f);
  const float4 gv = *(const float4*)(g + t * 4);
  const float4 bev = *(const float4*)(be + t * 4);
  const float y0 = (x0 - mean) * rstd * gv.x + bev.x;
  const float y1 = (x1 - mean) * rstd * gv.y + bev.y;
  const float y2 = (x2 - mean) * rstd * gv.z + bev.z;
  const float y3 = (x3 - mean) * rstd * gv.w + bev.w;
  float4 r = {y0, y1, y2, y3};
  *(float4*)(oF + base) = r;
  if (oB) {
    bf16x4 o4 = {(__bf16)y0, (__bf16)y1, (__bf16)y2, (__bf16)y3};
    *(bf16x4*)(oB + base) = o4;
  }
}

extern "C" void kernel_launch(void* const* d_in, const int* in_sizes, int n_in,
                              void* d_out, int out_size, void* d_ws, size_t ws_size,
                              hipStream_t stream) {
  const float* src    = (const float*)d_in[0];
  const float* pos    = (const float*)d_in[1];
  const float* qw     = (const float*)d_in[3];
  const float* kw     = (const float*)d_in[4];
  const float* vw     = (const float*)d_in[5];
  const float* rw     = (const float*)d_in[6];
  const float* ow     = (const float*)d_in[7];
  const float* rwbias = (const float*)d_in[8];
  const float* rrbias = (const float*)d_in[9];
  const float* w1     = (const float*)d_in[10];
  const float* b1     = (const float*)d_in[11];
  const float* w2     = (const float*)d_in[12];
  const float* b2     = (const float*)d_in[13];
  const float* g1     = (const float*)d_in[14];
  const float* be1    = (const float*)d_in[15];
  const float* g2     = (const float*)d_in[16];
  const float* be2    = (const float*)d_in[17];
  float* out = (float*)d_out;

  char* p = (char*)d_ws;
  auto alloc = [&](size_t bytes) { char* r = p; p += (bytes + 255) & ~(size_t)255; return r; };
  __bf16* qkB   = (__bf16*)alloc(4096ull * 2048 * 2);   // dead after attn
  __bf16* vTB   = (__bf16*)alloc(1024ull * 4096 * 2);   // dead after attn
  __bf16* kposB = (__bf16*)alloc(4100ull * 1024 * 2);   // dead after attn
  __bf16* avB   = (__bf16*)alloc(4096ull * 1024 * 2);   // dead after attn-out
  __bf16* srcB2 = (__bf16*)alloc(4096ull * 1024 * 2);   // dead after proj3
  __bf16* posB  = (__bf16*)alloc(4100ull * 1024 * 2);   // dead after proj3
  float*  xF    = (float*)alloc(4096ull * 1024 * 4);
  __bf16* w2B   = (__bf16*)alloc(4096ull * 1024 * 2);
  __bf16* qkvT  = (__bf16*)alloc(3072ull * 1024 * 2);
  __bf16* rwT   = (__bf16*)alloc(1024ull * 1024 * 2);
  __bf16* owB   = (__bf16*)alloc(1024ull * 1024 * 2);
  __bf16* w1B   = (__bf16*)alloc(4096ull * 1024 * 2);   // dead after FFN1
  __bf16* xB    = (__bf16*)alloc(4096ull * 1024 * 2);   // dead after FFN1
  // aliases (disjoint lifetimes):
  __bf16* gB  = qkB;             // gelu 32MB over qkB+vTB+kposB
  float* aoP0 = (float*)srcB2;   // attn-out partial0 16MB over srcB2+posB
  float* aoP1 = xF;              // partial1 over xF (ln reads then writes same addr)
  float* ffP0 = (float*)avB;     // ffn2 partial0 16MB over avB+srcB2
  float* ffP1 = (float*)w1B;     // ffn2 partial1 16MB over w1B+xB

  prep_all<<<11521, 256, 0, stream>>>(src, srcB2, pos, posB, ow, owB, w1, w1B,
                                      w2, w2B, qw, kw, vw, rw, qkvT, rwT);
  proj3_kernel<<<2064, 256, 0, stream>>>(srcB2, qkvT, qkvT + 2048 * 1024, posB,
                                         rwT, qkB, vTB, kposB);
  attn8<<<dim3(1024), 256, 0, stream>>>(qkB, vTB, kposB, rwbias, rrbias, avB);
  gemm_bt<128, 64, 0><<<dim3(16, 32, 2), 256, 0, stream>>>(avB, owB, aoP0, aoP1, nullptr, nullptr, 4096, 1024, 1024, 512);
  ln_fuse<<<4096, 256, 0, stream>>>(src, aoP0, aoP1, nullptr, g1, be1, xF, xB);
  gemm_bt<128, 64, 1><<<dim3(64, 32), 256, 0, stream>>>(xB, w1B, nullptr, nullptr, gB, b1, 4096, 4096, 1024, 1024);
  gemm_bt<128, 64, 0><<<dim3(16, 32, 2), 256, 0, stream>>>(gB, w2B, ffP0, ffP1, nullptr, nullptr, 4096, 1024, 4096, 2048);
  ln_fuse<<<4096, 256, 0, stream>>>(xF, ffP0, ffP1, b2, g2, be2, out, nullptr);
  (void)in_sizes; (void)n_in; (void)out_size; (void)ws_size;
}

// Round 10
// 318.197 us; speedup vs baseline: 4.4686x; 1.0375x over previous
//
#include <hip/hip_runtime.h>
#include <math.h>

typedef __bf16 bf16x8 __attribute__((ext_vector_type(8)));
typedef __bf16 bf16x4 __attribute__((ext_vector_type(4)));
typedef float f32x4 __attribute__((ext_vector_type(4)));

__device__ __forceinline__ void gload_lds16(const __bf16* g, __bf16* l) {
  __builtin_amdgcn_global_load_lds((const __attribute__((address_space(1))) void*)g,
                                   (__attribute__((address_space(3))) void*)l, 16, 0, 0);
}

__device__ __forceinline__ float gelu_exact(float v) {
  return 0.5f * v * (1.f + erff(v * 0.70710678118654752f));
}

// ---------------- fused prep: perm-src | 4x cvt | 4x transpose-cvt ----------------
__global__ __launch_bounds__(256) void prep_all(
    const float* __restrict__ src, __bf16* __restrict__ srcB2,
    const float* __restrict__ pos, __bf16* __restrict__ posB,
    const float* __restrict__ ow, __bf16* __restrict__ owB,
    const float* __restrict__ w1, __bf16* __restrict__ w1B,
    const float* __restrict__ w2, __bf16* __restrict__ w2B,
    const float* __restrict__ qw, const float* __restrict__ kw,
    const float* __restrict__ vw, const float* __restrict__ rw,
    __bf16* __restrict__ qkvT, __bf16* __restrict__ rwT) {
  __shared__ float t[32][33];
  int bid = blockIdx.x;
  const int tid = threadIdx.x;
  if (bid < 4096) {                       // src (i,b)-rows -> bf16 (b,i)-rows
    const int i = bid & 1023, b = bid >> 10;
    const float4 v = *(const float4*)(src + ((size_t)(i * 4 + b)) * 1024 + tid * 4);
    bf16x4 o = {(__bf16)v.x, (__bf16)v.y, (__bf16)v.z, (__bf16)v.w};
    *(bf16x4*)(srcB2 + (size_t)bid * 1024 + tid * 4) = o;
    return;
  }
  bid -= 4096;
  if (bid < 3329) {                       // straight converts
    const float* in; __bf16* out;
    if (bid < 1025) { in = pos; out = posB; }
    else if (bid < 1281) { bid -= 1025; in = ow; out = owB; }
    else if (bid < 2305) { bid -= 1281; in = w1; out = w1B; }
    else { bid -= 2305; in = w2; out = w2B; }
    const int base = bid * 4096 + tid * 4;
#pragma unroll
    for (int k2 = 0; k2 < 4; ++k2) {
      const int off = base + k2 * 1024;
      float4 v = *(const float4*)(in + off);
      bf16x4 o = {(__bf16)v.x, (__bf16)v.y, (__bf16)v.z, (__bf16)v.w};
      *(bf16x4*)(out + off) = o;
    }
    return;
  }
  bid -= 3329;                            // transpose-converts (4x 1024x1024)
  const int z = bid >> 10, rem = bid & 1023;
  const float* in; __bf16* out;
  switch (z) {
    case 0: in = qw; out = qkvT; break;
    case 1: in = kw; out = qkvT + 1024 * 1024; break;
    case 2: in = vw; out = qkvT + 2048 * 1024; break;
    default: in = rw; out = rwT; break;
  }
  const int c0 = (rem & 31) * 32, r0 = (rem >> 5) * 32;
  const int tx = tid & 31, ty = tid >> 5;
  for (int yy = ty; yy < 32; yy += 8)
    t[yy][tx] = in[(size_t)(r0 + yy) * 1024 + c0 + tx];
  __syncthreads();
  for (int yy = ty; yy < 32; yy += 8)
    out[(size_t)(c0 + yy) * 1024 + r0 + tx] = (__bf16)t[tx][yy];
}

// ---------------- bf16 MFMA GEMM body: C[M,N] = A[M,K] * BT[N,K]^T ----------------
// MODE 0: f32 C.  MODE 1: bf16 C = gelu(acc + bias[col]).  MODE 2: bf16 C.
// 2-phase double-buffered: one barrier/iter; stage(t+1) after the barrier.
template<int BM, int BN, int MODE>
__device__ __forceinline__ void gemm_body(
    const __bf16* __restrict__ A, const __bf16* __restrict__ BT,
    float* __restrict__ Cf, __bf16* __restrict__ Cb,
    const float* __restrict__ bias, int M, int N, int K,
    int kStart, int kChunk, int mBase, int nBase, char* smemRaw) {
  constexpr int BK = 32;
  constexpr int ALOAD = (BM * BK) / 2048;
  constexpr int BLOAD = (BN * BK) / 2048;
  __bf16* lA = (__bf16*)smemRaw;                       // [2][BM*BK]
  __bf16* lB = (__bf16*)(smemRaw + 4 * BM * BK);       // [2][BN*BK]
  const int tid = threadIdx.x;
  const int w = tid >> 6, l = tid & 63;
  const int lr = l & 15, lk = l >> 4;
  const int srow = tid >> 2;
  const int scol = (tid & 3) * 8;
  const int wbase = w * 512;

  const __bf16* aSrc[ALOAD];
  const __bf16* bSrc[BLOAD];
#pragma unroll
  for (int i = 0; i < ALOAD; ++i) {
    int grow = mBase + srow + i * 64;
    grow = grow < M ? grow : M - 1;
    aSrc[i] = A + (size_t)grow * K + kStart + scol;
  }
#pragma unroll
  for (int i = 0; i < BLOAD; ++i) {
    const int grow = nBase + srow + i * 64;
    bSrc[i] = BT + (size_t)grow * K + kStart + scol;
  }
  auto stage = [&](int buf) {
#pragma unroll
    for (int i = 0; i < ALOAD; ++i) {
      gload_lds16(aSrc[i], &lA[buf * BM * BK + i * 2048 + wbase]);
      aSrc[i] += BK;
    }
#pragma unroll
    for (int i = 0; i < BLOAD; ++i) {
      gload_lds16(bSrc[i], &lB[buf * BN * BK + i * 2048 + wbase]);
      bSrc[i] += BK;
    }
  };

  constexpr int WM = BM / 2, WN = BN / 2;
  constexpr int MF = WM / 16, NF = WN / 16;
  const int wr = w >> 1, wc = w & 1;
  f32x4 acc[MF][NF] = {};

  const int nIter = kChunk / BK;
  stage(0);
  int cur = 0;
#pragma unroll 1
  for (int t = 0; t < nIter; ++t) {
    __syncthreads();
    if (t + 1 < nIter) stage(cur ^ 1);
    bf16x8 af[MF], bfr[NF];
#pragma unroll
    for (int mi = 0; mi < MF; ++mi)
      af[mi] = *(const bf16x8*)&lA[cur * BM * BK + (wr * WM + mi * 16 + lr) * BK + lk * 8];
#pragma unroll
    for (int nj = 0; nj < NF; ++nj)
      bfr[nj] = *(const bf16x8*)&lB[cur * BN * BK + (wc * WN + nj * 16 + lr) * BK + lk * 8];
#pragma unroll
    for (int mi = 0; mi < MF; ++mi)
#pragma unroll
      for (int nj = 0; nj < NF; ++nj)
        acc[mi][nj] = __builtin_amdgcn_mfma_f32_16x16x32_bf16(af[mi], bfr[nj], acc[mi][nj], 0, 0, 0);
    cur ^= 1;
  }
#pragma unroll
  for (int mi = 0; mi < MF; ++mi) {
#pragma unroll
    for (int nj = 0; nj < NF; ++nj) {
      const int col = nBase + wc * WN + nj * 16 + lr;
      const int row0 = mBase + wr * WM + mi * 16 + lk * 4;
#pragma unroll
      for (int j = 0; j < 4; ++j) {
        const int row = row0 + j;
        if (row < M) {
          float v = acc[mi][nj][j];
          if constexpr (MODE == 1) {
            v = gelu_exact(v + bias[col]);
            Cb[(size_t)row * N + col] = (__bf16)v;
          } else if constexpr (MODE == 2) {
            Cb[(size_t)row * N + col] = (__bf16)v;
          } else {
            Cf[(size_t)row * N + col] = v;
          }
        }
      }
    }
  }
}

// XCD-chunked swizzle with COLUMN-MAJOR (ny-inner) traversal inside each band:
// each XCD owns a contiguous band of whole tile-rows; consecutive blocks on one
// XCD share the same B-panel (used rpb times back-to-back) while the band's few
// A-panels stay L2-resident.  Requires (G/8) % gridDim.x == 0 (all our grids).
template<int BM, int BN, int MODE>
__global__ __launch_bounds__(256)
void gemm_bt(const __bf16* __restrict__ A, const __bf16* __restrict__ BT,
             float* __restrict__ Cf, __bf16* __restrict__ Cb,
             __bf16* __restrict__ Cb2, const float* __restrict__ bias,
             int M, int N, int K, int kChunk) {
  __shared__ __align__(16) char smem[4 * (BM + BN) * 32];
  __bf16* cb = (blockIdx.z == 1) ? Cb2 : Cb;
  const int gx = gridDim.x;
  const int G = gx * gridDim.y;
  const int flat = blockIdx.y * gx + blockIdx.x;
  const int band = G >> 3;                  // tiles per XCD
  const int x8 = flat & 7, loc = flat >> 3; // XCD id, position in band
  const int rpb = band / gx;                // tile-rows per band
  const int ny = x8 * rpb + loc % rpb;      // ny-inner (column-major in band)
  const int nx = loc / rpb;
  gemm_body<BM, BN, MODE>(A, BT, Cf, cb, bias, M, N, K, blockIdx.z * kChunk,
                          kChunk, ny * BM, nx * BN, smem);
}

// ---- the three projection GEMMs in one launch (2064 blocks, XCD-chunked) ----
__global__ __launch_bounds__(256)
void proj3_kernel(const __bf16* __restrict__ srcB2, const __bf16* __restrict__ qkvT,
                  const __bf16* __restrict__ vwT, const __bf16* __restrict__ posB,
                  const __bf16* __restrict__ rwT, __bf16* __restrict__ qkB,
                  __bf16* __restrict__ vTB, __bf16* __restrict__ kposB) {
  __shared__ __align__(16) char smem[4 * (128 + 64) * 32];
  const int raw = blockIdx.x;
  int bid = (raw & 7) * 258 + (raw >> 3);   // 2064/8 = 258 per XCD
  if (bid < 1024) {
    gemm_body<128, 64, 2>(srcB2, qkvT, nullptr, qkB, nullptr, 4096, 2048, 1024,
                          0, 1024, (bid >> 5) * 128, (bid & 31) * 64, smem);
  } else if (bid < 1536) {
    const int t = bid - 1024;
    gemm_body<128, 64, 2>(vwT, srcB2, nullptr, vTB, nullptr, 1024, 4096, 1024,
                          0, 1024, (t >> 6) * 128, (t & 63) * 64, smem);
  } else {
    const int t = bid - 1536;
    gemm_body<128, 64, 2>(posB, rwT, nullptr, kposB, nullptr, 4100, 1024, 1024,
                          0, 1024, (t >> 4) * 128, (t & 15) * 64, smem);
  }
}

// ---------------- MFMA rel-pos attention v8: Z via ones-MFMA ----------------
__global__ __launch_bounds__(256)
void attn8(const __bf16* __restrict__ qk, const __bf16* __restrict__ vT,
           const __bf16* __restrict__ kpos, const float* __restrict__ rwbias,
           const float* __restrict__ rrbias, __bf16* __restrict__ av) {
  constexpr float ALPHA = 0.125f * 1.44269504088896f;
  constexpr int PB = 132;
  // 0:16K K dbuf | 16K:32K KP dbuf | 32K:48K VT dbuf | 48K:+8K P | then sbd [64][132]
  __shared__ __align__(16) char smem[74240];
  __bf16* sP  = (__bf16*)(smem + 49152);
  __bf16* sbd = (__bf16*)(smem + 57344);

  const int flat = blockIdx.x;
  const int xcd = flat & 7, rr_ = flat >> 3;
  const int bn = xcd * 8 + (rr_ >> 4);
  const int it = rr_ & 15;
  const int b = bn >> 4, n = bn & 15;
  const int i0 = it * 64;
  const int tid = threadIdx.x;
  const int l = tid & 63;
  const int lcol = l & 15, lk = l >> 4;
  const int strip = (tid >> 6) * 16;
  const int wbase = tid & 192;
  const int nh64 = n * 64;
  const int q = strip + lcol;

  const int rB = tid >> 3;
  const int cs8 = ((tid & 7) ^ (rB & 7)) * 8;

  bf16x8 onesf;
#pragma unroll
  for (int u = 0; u < 8; ++u) onesf[u] = (__bf16)1.0f;

  // ---- q fragments: qac (rwb), qlo (rrb, rows i0+q), qhi (rrb, rows i0+q+1) ----
  bf16x8 qac[2], qlo[2], qhi[2];
  {
    const __bf16* qrow = qk + ((size_t)(b * 1024 + i0 + q)) * 2048 + nh64;
    int gH = i0 + q + 1; gH = gH < 1024 ? gH : 1023;
    const __bf16* qrowH = qk + ((size_t)(b * 1024 + gH)) * 2048 + nh64;
#pragma unroll
    for (int kk = 0; kk < 2; ++kk) {
      bf16x8 qv = *(const bf16x8*)(qrow + kk * 32 + lk * 8);
      bf16x8 qh = *(const bf16x8*)(qrowH + kk * 32 + lk * 8);
      const int dbase = nh64 + kk * 32 + lk * 8;
#pragma unroll
      for (int u = 0; u < 8; ++u) {
        const float rb = rrbias[dbase + u];
        qac[kk][u] = (__bf16)(((float)qv[u] + rwbias[dbase + u]) * ALPHA);
        qlo[kk][u] = (__bf16)(((float)qv[u] + rb) * ALPHA);
        qhi[kk][u] = (__bf16)(((float)qh[u] + rb) * ALPHA);
      }
    }
  }

  // ---- prologue stage: low band -> VTbuf1(temp), K0, KP0, VT0 ----
#pragma unroll
  for (int kq = 0; kq < 2; ++kq) {
    const int r = kq * 32 + rB;
    const int dst = (kq * 256 + wbase) * 8;
    gload_lds16(kpos + ((size_t)((960 - i0 + r) * 4 + b)) * 1024 + nh64 + cs8,
                (__bf16*)(smem + 40960) + dst);                       // low band (rrel<0)
    gload_lds16(qk + ((size_t)(b * 1024 + r)) * 2048 + 1024 + nh64 + cs8,
                (__bf16*)(smem) + dst);                               // K jt0
    const int rrel = r - i0;
    const int idx = (rrel <= 0) ? (1024 + rrel) : (rrel - 1);
    gload_lds16(kpos + ((size_t)(idx * 4 + b)) * 1024 + nh64 + cs8,
                (__bf16*)(smem + 16384) + dst);                       // KP jt0 batch
    gload_lds16(vT + ((size_t)(nh64 + r)) * 4096 + b * 1024 + cs8,
                (__bf16*)(smem + 32768) + dst);                       // VT jt0
  }
  __syncthreads();
  // ---- prologue G on low band (rrel in [-i0-64,-i0), all lo), rows q ----
  {
    __bf16* kpl = (__bf16*)(smem + 40960);
    const int colb0 = (-i0 - 64) & 127;
#pragma unroll
    for (int fb = 0; fb < 4; ++fb) {
      const int row = fb * 16 + lcol;
      f32x4 g = {};
#pragma unroll
      for (int kk = 0; kk < 2; ++kk) {
        bf16x8 a = *(const bf16x8*)&kpl[row * 64 + (((kk * 4 + lk) ^ (lcol & 7)) * 8)];
        g = __builtin_amdgcn_mfma_f32_16x16x32_bf16(a, qlo[kk], g, 0, 0, 0);
      }
      bf16x4 gw = {(__bf16)g[0], (__bf16)g[1], (__bf16)g[2], (__bf16)g[3]};
      *(bf16x4*)&sbd[q * PB + ((colb0 + fb * 16 + lk * 4) & 127)] = gw;
    }
  }
  __syncthreads();   // temp-band reads done before jt0 stages into VT buf1

  f32x4 oacc[4] = {};
  f32x4 zq = {};
  size_t kS = (size_t)(b * 1024 + 64 + rB) * 2048 + 1024 + nh64 + cs8;
  size_t vS = (size_t)(nh64 + rB) * 4096 + b * 1024 + 64 + cs8;

#pragma unroll 1
  for (int jt = 0; jt < 16; ++jt) {
    const int cur = jt & 1, nxt = cur ^ 1;
    const int d0 = jt * 64 - i0;
    __bf16* sK   = (__bf16*)(smem + cur * 8192);
    __bf16* sKn  = (__bf16*)(smem + nxt * 8192);
    __bf16* sKP  = (__bf16*)(smem + 16384 + cur * 8192);
    __bf16* sKPn = (__bf16*)(smem + 16384 + nxt * 8192);
    __bf16* sVT  = (__bf16*)(smem + 32768 + cur * 8192);
    __bf16* sVTn = (__bf16*)(smem + 32768 + nxt * 8192);
    // ---- stage jt+1 (K, KP, VT); OOB prefetch at jt=15 is never read ----
#pragma unroll
    for (int kq = 0; kq < 2; ++kq) {
      const int dst = (kq * 256 + wbase) * 8;
      gload_lds16(qk + kS + kq * 65536, sKn + dst);
      gload_lds16(vT + vS + kq * 131072, sVTn + dst);
      const int rreln = d0 + 64 + kq * 32 + rB;
      const int idx = (rreln <= 0) ? (1024 + rreln) : (rreln - 1);
      gload_lds16(kpos + ((size_t)(idx * 4 + b)) * 1024 + nh64 + cs8, sKPn + dst);
    }
    kS += 131072; vS += 64;
    // ---- G MFMA on current batch: hi frags for d0>=0, lo for d0<0; row = q ----
    {
      const bf16x8 qg0 = (d0 >= 0) ? qhi[0] : qlo[0];
      const bf16x8 qg1 = (d0 >= 0) ? qhi[1] : qlo[1];
#pragma unroll
      for (int fb = 0; fb < 4; ++fb) {
        const int row = fb * 16 + lcol;
        f32x4 g = {};
        g = __builtin_amdgcn_mfma_f32_16x16x32_bf16(
            *(const bf16x8*)&sKP[row * 64 + ((lk ^ (lcol & 7)) * 8)], qg0, g, 0, 0, 0);
        g = __builtin_amdgcn_mfma_f32_16x16x32_bf16(
            *(const bf16x8*)&sKP[row * 64 + (((4 + lk) ^ (lcol & 7)) * 8)], qg1, g, 0, 0, 0);
        bf16x4 gw = {(__bf16)g[0], (__bf16)g[1], (__bf16)g[2], (__bf16)g[3]};
        *(bf16x4*)&sbd[q * PB + ((d0 + fb * 16 + lk * 4) & 127)] = gw;
      }
      if (d0 == 0) {   // fix col rrel=0 (needs lo q-rows): once per block
        const int cl = tid >> 2, part = tid & 3;
        const __bf16* qs = qk + ((size_t)(b * 1024 + i0 + cl)) * 2048 + nh64 + part * 16;
        bf16x8 a0 = *(const bf16x8*)qs;
        bf16x8 a1 = *(const bf16x8*)(qs + 8);
        bf16x8 k0 = *(const bf16x8*)&sKP[(2 * part) * 8];       // row 0, swizzle 0
        bf16x8 k1 = *(const bf16x8*)&sKP[(2 * part + 1) * 8];
        float s64 = 0.f;
#pragma unroll
        for (int u = 0; u < 8; ++u)
          s64 += ((float)a0[u] + rrbias[nh64 + part * 16 + u]) * (float)k0[u]
               + ((float)a1[u] + rrbias[nh64 + part * 16 + 8 + u]) * (float)k1[u];
        s64 += __shfl_xor(s64, 1, 64);
        s64 += __shfl_xor(s64, 2, 64);
        if (part == 0) sbd[cl * PB] = (__bf16)(s64 * ALPHA);
      }
    }
    // ---- ac MFMA (swapped): sc[fk][jj] = S[jl=fk*16+lk*4+jj][q] ----
    f32x4 sc[4];
#pragma unroll
    for (int fk = 0; fk < 4; ++fk) {
      const int row = fk * 16 + lcol;
      f32x4 a = {};
#pragma unroll
      for (int kk = 0; kk < 2; ++kk) {
        bf16x8 kf = *(const bf16x8*)&sK[row * 64 + (((kk * 4 + lk) ^ (lcol & 7)) * 8)];
        a = __builtin_amdgcn_mfma_f32_16x16x32_bf16(kf, qac[kk], a, 0, 0, 0);
      }
      sc[fk] = a;
    }
    // ---- gather + exp2 + P store (wave-private rows; no barrier) ----
    {
      const int rowb = q * PB;
      const int sb = d0 - q;
#pragma unroll
      for (int fk = 0; fk < 4; ++fk) {
        const int cb = sb + fk * 16 + lk * 4;
        float e0 = exp2f(sc[fk][0] + (float)sbd[rowb + ((cb) & 127)]);
        float e1 = exp2f(sc[fk][1] + (float)sbd[rowb + ((cb + 1) & 127)]);
        float e2 = exp2f(sc[fk][2] + (float)sbd[rowb + ((cb + 2) & 127)]);
        float e3 = exp2f(sc[fk][3] + (float)sbd[rowb + ((cb + 3) & 127)]);
        bf16x4 pw = {(__bf16)e0, (__bf16)e1, (__bf16)e2, (__bf16)e3};
        *(bf16x4*)&sP[q * 64 + (((fk * 2 + (lk >> 1)) ^ (q & 7)) * 8) + (lk & 1) * 4] = pw;
      }
    }
    // ---- PV MFMA + Z-ones MFMA ----
#pragma unroll
    for (int kk = 0; kk < 2; ++kk) {
      bf16x8 pa = *(const bf16x8*)&sP[q * 64 + (((kk * 4 + lk) ^ (q & 7)) * 8)];
      zq = __builtin_amdgcn_mfma_f32_16x16x32_bf16(pa, onesf, zq, 0, 0, 0);
#pragma unroll
      for (int fd = 0; fd < 4; ++fd) {
        const int vrow = fd * 16 + lcol;
        bf16x8 bv = *(const bf16x8*)&sVT[vrow * 64 + (((kk * 4 + lk) ^ (lcol & 7)) * 8)];
        oacc[fd] = __builtin_amdgcn_mfma_f32_16x16x32_bf16(pa, bv, oacc[fd], 0, 0, 0);
      }
    }
    __syncthreads();   // rotation: cur reads done; next-jt staging drained
  }
  // ---- epilogue: zq[jj] is Z for exactly the row this thread stores ----
#pragma unroll
  for (int jj = 0; jj < 4; ++jj) {
    const float rz = 1.f / zq[jj];
    const int ig = i0 + strip + lk * 4 + jj;
    __bf16* dst = av + ((size_t)(ig * 4 + b)) * 1024 + nh64;
#pragma unroll
    for (int fd = 0; fd < 4; ++fd)
      dst[fd * 16 + lcol] = (__bf16)(oacc[fd][jj] * rz);
  }
}

// ---------------- fused residual + LayerNorm (two bf16 partial addends) ----------------
__global__ __launch_bounds__(256)
void ln_fuse(const float* __restrict__ A, const __bf16* __restrict__ P0,
             const __bf16* __restrict__ P1, const float* __restrict__ cb,
             const float* __restrict__ g, const float* __restrict__ be,
             float* __restrict__ oF, __bf16* __restrict__ oB) {
  const int row = blockIdx.x, t = threadIdx.x;
  const size_t base = (size_t)row * 1024 + t * 4;
  const float4 a = *(const float4*)(A + base);
  const bf16x4 p0 = *(const bf16x4*)(P0 + base);
  const bf16x4 p1 = *(const bf16x4*)(P1 + base);
  float x0 = a.x + (float)p0[0] + (float)p1[0];
  float x1 = a.y + (float)p0[1] + (float)p1[1];
  float x2 = a.z + (float)p0[2] + (float)p1[2];
  float x3 = a.w + (float)p0[3] + (float)p1[3];
  if (cb) {
    const float4 c = *(const float4*)(cb + t * 4);
    x0 += c.x; x1 += c.y; x2 += c.z; x3 += c.w;
  }
  float s = x0 + x1 + x2 + x3;
  float qq = x0 * x0 + x1 * x1 + x2 * x2 + x3 * x3;
#pragma unroll
  for (int o = 1; o < 64; o <<= 1) { s += __shfl_xor(s, o, 64); qq += __shfl_xor(qq, o, 64); }
  __shared__ float ss[4], qs[4];
  if ((t & 63) == 0) { ss[t >> 6] = s; qs[t >> 6] = qq; }
  __syncthreads();
  s = ss[0] + ss[1] + ss[2] + ss[3];
  qq = qs[0] + qs[1] + qs[2] + qs[3];
  const float mean = s * (1.f / 1024.f);
  const float var = qq * (1.f / 1024.f) - mean * mean;
  const float rstd = rsqrtf(var + 1e-5f);
  const float4 gv = *(const float4*)(g + t * 4);
  const float4 bev = *(const float4*)(be + t * 4);
  const float y0 = (x0 - mean) * rstd * gv.x + bev.x;
  const float y1 = (x1 - mean) * rstd * gv.y + bev.y;
  const float y2 = (x2 - mean) * rstd * gv.z + bev.z;
  const float y3 = (x3 - mean) * rstd * gv.w + bev.w;
  if (oF) {
    float4 r = {y0, y1, y2, y3};
    *(float4*)(oF + base) = r;
  }
  if (oB) {
    bf16x4 o4 = {(__bf16)y0, (__bf16)y1, (__bf16)y2, (__bf16)y3};
    *(bf16x4*)(oB + base) = o4;
  }
}

extern "C" void kernel_launch(void* const* d_in, const int* in_sizes, int n_in,
                              void* d_out, int out_size, void* d_ws, size_t ws_size,
                              hipStream_t stream) {
  const float* src    = (const float*)d_in[0];
  const float* pos    = (const float*)d_in[1];
  const float* qw     = (const float*)d_in[3];
  const float* kw     = (const float*)d_in[4];
  const float* vw     = (const float*)d_in[5];
  const float* rw     = (const float*)d_in[6];
  const float* ow     = (const float*)d_in[7];
  const float* rwbias = (const float*)d_in[8];
  const float* rrbias = (const float*)d_in[9];
  const float* w1     = (const float*)d_in[10];
  const float* b1     = (const float*)d_in[11];
  const float* w2     = (const float*)d_in[12];
  const float* b2     = (const float*)d_in[13];
  const float* g1     = (const float*)d_in[14];
  const float* be1    = (const float*)d_in[15];
  const float* g2     = (const float*)d_in[16];
  const float* be2    = (const float*)d_in[17];
  float* out = (float*)d_out;

  char* p = (char*)d_ws;
  auto alloc = [&](size_t bytes) { char* r = p; p += (bytes + 255) & ~(size_t)255; return r; };
  __bf16* qkB   = (__bf16*)alloc(4096ull * 2048 * 2);   // dead after attn
  __bf16* vTB   = (__bf16*)alloc(1024ull * 4096 * 2);   // dead after attn
  __bf16* kposB = (__bf16*)alloc(4100ull * 1024 * 2);   // dead after attn
  __bf16* avB   = (__bf16*)alloc(4096ull * 1024 * 2);   // dead after attn-out
  __bf16* srcB2 = (__bf16*)alloc(4096ull * 1024 * 2);   // dead after proj3
  __bf16* posB  = (__bf16*)alloc(4100ull * 1024 * 2);   // dead after proj3
  float*  xF    = (float*)alloc(4096ull * 1024 * 4);
  __bf16* w2B   = (__bf16*)alloc(4096ull * 1024 * 2);
  __bf16* qkvT  = (__bf16*)alloc(3072ull * 1024 * 2);
  __bf16* rwT   = (__bf16*)alloc(1024ull * 1024 * 2);
  __bf16* owB   = (__bf16*)alloc(1024ull * 1024 * 2);
  __bf16* w1B   = (__bf16*)alloc(4096ull * 1024 * 2);   // dead after FFN1
  __bf16* xB    = (__bf16*)alloc(4096ull * 1024 * 2);   // dead after FFN1
  // aliases (disjoint lifetimes):
  __bf16* gB   = qkB;            // gelu 32MB over qkB+vTB+kposB
  __bf16* aoP0 = srcB2;          // attn-out bf16 partial0 (srcB2 dead after proj3)
  __bf16* aoP1 = posB;           // attn-out bf16 partial1 (posB dead after proj3)
  __bf16* ffP0 = avB;            // ffn2 bf16 partial0 (avB dead after attn-out)
  __bf16* ffP1 = w1B;            // ffn2 bf16 partial1 (w1B dead after FFN1)

  prep_all<<<11521, 256, 0, stream>>>(src, srcB2, pos, posB, ow, owB, w1, w1B,
                                      w2, w2B, qw, kw, vw, rw, qkvT, rwT);
  proj3_kernel<<<2064, 256, 0, stream>>>(srcB2, qkvT, qkvT + 2048 * 1024, posB,
                                         rwT, qkB, vTB, kposB);
  attn8<<<dim3(1024), 256, 0, stream>>>(qkB, vTB, kposB, rwbias, rrbias, avB);
  // attn-out: split-K=2 over K=1024, bf16 partials
  gemm_bt<128, 64, 2><<<dim3(16, 32, 2), 256, 0, stream>>>(avB, owB, nullptr, aoP0, aoP1, nullptr, 4096, 1024, 1024, 512);
  ln_fuse<<<4096, 256, 0, stream>>>(src, aoP0, aoP1, nullptr, g1, be1, xF, xB);
  gemm_bt<128, 64, 1><<<dim3(64, 32), 256, 0, stream>>>(xB, w1B, nullptr, gB, nullptr, b1, 4096, 4096, 1024, 1024);
  // FFN2: split-K=2 over K=4096, bf16 partials
  gemm_bt<128, 64, 2><<<dim3(16, 32, 2), 256, 0, stream>>>(gB, w2B, nullptr, ffP0, ffP1, nullptr, 4096, 1024, 4096, 2048);
  ln_fuse<<<4096, 256, 0, stream>>>(xF, ffP0, ffP1, b2, g2, be2, out, nullptr);
  (void)in_sizes; (void)n_in; (void)out_size; (void)ws_size;
}

// Round 11
// 317.853 us; speedup vs baseline: 4.4734x; 1.0011x over previous
//
#include <hip/hip_runtime.h>
#include <math.h>

typedef __bf16 bf16x8 __attribute__((ext_vector_type(8)));
typedef __bf16 bf16x4 __attribute__((ext_vector_type(4)));
typedef float f32x4 __attribute__((ext_vector_type(4)));

__device__ __forceinline__ void gload_lds16(const __bf16* g, __bf16* l) {
  __builtin_amdgcn_global_load_lds((const __attribute__((address_space(1))) void*)g,
                                   (__attribute__((address_space(3))) void*)l, 16, 0, 0);
}

__device__ __forceinline__ float gelu_exact(float v) {
  return 0.5f * v * (1.f + erff(v * 0.70710678118654752f));
}

// ---------------- fused prep: perm-src | 4x cvt | 4x transpose-cvt ----------------
__global__ __launch_bounds__(256) void prep_all(
    const float* __restrict__ src, __bf16* __restrict__ srcB2,
    const float* __restrict__ pos, __bf16* __restrict__ posB,
    const float* __restrict__ ow, __bf16* __restrict__ owB,
    const float* __restrict__ w1, __bf16* __restrict__ w1B,
    const float* __restrict__ w2, __bf16* __restrict__ w2B,
    const float* __restrict__ qw, const float* __restrict__ kw,
    const float* __restrict__ vw, const float* __restrict__ rw,
    __bf16* __restrict__ qkvT, __bf16* __restrict__ rwT) {
  __shared__ float t[32][33];
  int bid = blockIdx.x;
  const int tid = threadIdx.x;
  if (bid < 4096) {                       // src (i,b)-rows -> bf16 (b,i)-rows
    const int i = bid & 1023, b = bid >> 10;
    const float4 v = *(const float4*)(src + ((size_t)(i * 4 + b)) * 1024 + tid * 4);
    bf16x4 o = {(__bf16)v.x, (__bf16)v.y, (__bf16)v.z, (__bf16)v.w};
    *(bf16x4*)(srcB2 + (size_t)bid * 1024 + tid * 4) = o;
    return;
  }
  bid -= 4096;
  if (bid < 3329) {                       // straight converts
    const float* in; __bf16* out;
    if (bid < 1025) { in = pos; out = posB; }
    else if (bid < 1281) { bid -= 1025; in = ow; out = owB; }
    else if (bid < 2305) { bid -= 1281; in = w1; out = w1B; }
    else { bid -= 2305; in = w2; out = w2B; }
    const int base = bid * 4096 + tid * 4;
#pragma unroll
    for (int k2 = 0; k2 < 4; ++k2) {
      const int off = base + k2 * 1024;
      float4 v = *(const float4*)(in + off);
      bf16x4 o = {(__bf16)v.x, (__bf16)v.y, (__bf16)v.z, (__bf16)v.w};
      *(bf16x4*)(out + off) = o;
    }
    return;
  }
  bid -= 3329;                            // transpose-converts (4x 1024x1024)
  const int z = bid >> 10, rem = bid & 1023;
  const float* in; __bf16* out;
  switch (z) {
    case 0: in = qw; out = qkvT; break;
    case 1: in = kw; out = qkvT + 1024 * 1024; break;
    case 2: in = vw; out = qkvT + 2048 * 1024; break;
    default: in = rw; out = rwT; break;
  }
  const int c0 = (rem & 31) * 32, r0 = (rem >> 5) * 32;
  const int tx = tid & 31, ty = tid >> 5;
  for (int yy = ty; yy < 32; yy += 8)
    t[yy][tx] = in[(size_t)(r0 + yy) * 1024 + c0 + tx];
  __syncthreads();
  for (int yy = ty; yy < 32; yy += 8)
    out[(size_t)(c0 + yy) * 1024 + r0 + tx] = (__bf16)t[tx][yy];
}

// ---------------- bf16 MFMA GEMM body (2-phase, 128x64) ----------------
template<int BM, int BN, int MODE>
__device__ __forceinline__ void gemm_body(
    const __bf16* __restrict__ A, const __bf16* __restrict__ BT,
    float* __restrict__ Cf, __bf16* __restrict__ Cb,
    const float* __restrict__ bias, int M, int N, int K,
    int kStart, int kChunk, int mBase, int nBase, char* smemRaw) {
  constexpr int BK = 32;
  constexpr int ALOAD = (BM * BK) / 2048;
  constexpr int BLOAD = (BN * BK) / 2048;
  __bf16* lA = (__bf16*)smemRaw;                       // [2][BM*BK]
  __bf16* lB = (__bf16*)(smemRaw + 4 * BM * BK);       // [2][BN*BK]
  const int tid = threadIdx.x;
  const int w = tid >> 6, l = tid & 63;
  const int lr = l & 15, lk = l >> 4;
  const int srow = tid >> 2;
  const int scol = (tid & 3) * 8;
  const int wbase = w * 512;

  const __bf16* aSrc[ALOAD];
  const __bf16* bSrc[BLOAD];
#pragma unroll
  for (int i = 0; i < ALOAD; ++i) {
    int grow = mBase + srow + i * 64;
    grow = grow < M ? grow : M - 1;
    aSrc[i] = A + (size_t)grow * K + kStart + scol;
  }
#pragma unroll
  for (int i = 0; i < BLOAD; ++i) {
    const int grow = nBase + srow + i * 64;
    bSrc[i] = BT + (size_t)grow * K + kStart + scol;
  }
  auto stage = [&](int buf) {
#pragma unroll
    for (int i = 0; i < ALOAD; ++i) {
      gload_lds16(aSrc[i], &lA[buf * BM * BK + i * 2048 + wbase]);
      aSrc[i] += BK;
    }
#pragma unroll
    for (int i = 0; i < BLOAD; ++i) {
      gload_lds16(bSrc[i], &lB[buf * BN * BK + i * 2048 + wbase]);
      bSrc[i] += BK;
    }
  };

  constexpr int WM = BM / 2, WN = BN / 2;
  constexpr int MF = WM / 16, NF = WN / 16;
  const int wr = w >> 1, wc = w & 1;
  f32x4 acc[MF][NF] = {};

  const int nIter = kChunk / BK;
  stage(0);
  int cur = 0;
#pragma unroll 1
  for (int t = 0; t < nIter; ++t) {
    __syncthreads();
    if (t + 1 < nIter) stage(cur ^ 1);
    bf16x8 af[MF], bfr[NF];
#pragma unroll
    for (int mi = 0; mi < MF; ++mi)
      af[mi] = *(const bf16x8*)&lA[cur * BM * BK + (wr * WM + mi * 16 + lr) * BK + lk * 8];
#pragma unroll
    for (int nj = 0; nj < NF; ++nj)
      bfr[nj] = *(const bf16x8*)&lB[cur * BN * BK + (wc * WN + nj * 16 + lr) * BK + lk * 8];
#pragma unroll
    for (int mi = 0; mi < MF; ++mi)
#pragma unroll
      for (int nj = 0; nj < NF; ++nj)
        acc[mi][nj] = __builtin_amdgcn_mfma_f32_16x16x32_bf16(af[mi], bfr[nj], acc[mi][nj], 0, 0, 0);
    cur ^= 1;
  }
#pragma unroll
  for (int mi = 0; mi < MF; ++mi) {
#pragma unroll
    for (int nj = 0; nj < NF; ++nj) {
      const int col = nBase + wc * WN + nj * 16 + lr;
      const int row0 = mBase + wr * WM + mi * 16 + lk * 4;
#pragma unroll
      for (int j = 0; j < 4; ++j) {
        const int row = row0 + j;
        if (row < M) {
          float v = acc[mi][nj][j];
          if constexpr (MODE == 1) {
            v = gelu_exact(v + bias[col]);
            Cb[(size_t)row * N + col] = (__bf16)v;
          } else if constexpr (MODE == 2) {
            Cb[(size_t)row * N + col] = (__bf16)v;
          } else {
            Cf[(size_t)row * N + col] = v;
          }
        }
      }
    }
  }
}

template<int BM, int BN, int MODE>
__global__ __launch_bounds__(256)
void gemm_bt(const __bf16* __restrict__ A, const __bf16* __restrict__ BT,
             float* __restrict__ Cf, __bf16* __restrict__ Cb,
             __bf16* __restrict__ Cb2, const float* __restrict__ bias,
             int M, int N, int K, int kChunk) {
  __shared__ __align__(16) char smem[4 * (BM + BN) * 32];
  __bf16* cb = (blockIdx.z == 1) ? Cb2 : Cb;
  const int gx = gridDim.x;
  const int G = gx * gridDim.y;
  const int flat = blockIdx.y * gx + blockIdx.x;
  const int band = G >> 3;
  const int x8 = flat & 7, loc = flat >> 3;
  const int rpb = band / gx;
  const int ny = x8 * rpb + loc % rpb;
  const int nx = loc / rpb;
  gemm_body<BM, BN, MODE>(A, BT, Cf, cb, bias, M, N, K, blockIdx.z * kChunk,
                          kChunk, ny * BM, nx * BN, smem);
}

// ---- vT + kpos projections in one launch (1040 blocks, XCD-chunked) ----
__global__ __launch_bounds__(256)
void proj2_kernel(const __bf16* __restrict__ vwT, const __bf16* __restrict__ srcB2,
                  const __bf16* __restrict__ posB, const __bf16* __restrict__ rwT,
                  __bf16* __restrict__ vTB, __bf16* __restrict__ kposB) {
  __shared__ __align__(16) char smem[4 * (128 + 64) * 32];
  const int raw = blockIdx.x;
  int bid = (raw & 7) * 130 + (raw >> 3);   // 1040/8 = 130 per XCD
  if (bid < 512) {
    gemm_body<128, 64, 2>(vwT, srcB2, nullptr, vTB, nullptr, 1024, 4096, 1024,
                          0, 1024, (bid >> 6) * 128, (bid & 63) * 64, smem);
  } else {
    const int t = bid - 512;
    gemm_body<128, 64, 2>(posB, rwT, nullptr, kposB, nullptr, 4100, 1024, 1024,
                          0, 1024, (t >> 4) * 128, (t & 15) * 64, smem);
  }
}

// ---------------- 256x128-tile deep-pipeline GEMM (3-side counted-vmcnt) ----------------
// C[M,N] = A[M,K]*BT[N,K]^T, bf16 out. M%256==0, N%128==0, K%64==0, K/64>=3.
// 512 threads = 8 waves (4M x 2N), wave output 64x64. LDS = 3 sides x (A[256][64]
// + B[128][64]) = 144 KB. kt j lives in side j%3; group j prefetches kt j+2 into
// side (j+2)%3 (dead since group j-1); counted vmcnt(6) keeps kt j+1's 6 loads in
// flight across the raw barrier. XOR-swizzled LDS (slot^(row&7)) -> 2-way-free b128.
template<int MODE>
__global__ __launch_bounds__(512)
void gemm256(const __bf16* __restrict__ A, const __bf16* __restrict__ BT,
             __bf16* __restrict__ Cb, const float* __restrict__ bias,
             int M, int N, int K) {
  __shared__ __align__(16) __bf16 sm[3 * 24576];
  const int tid = threadIdx.x;
  const int wid = tid >> 6, l = tid & 63;
  const int lcol = l & 15, lk = l >> 4;
  const int wm = wid >> 1, wn = wid & 1;
  const int gx = gridDim.x;
  const int G = gx * gridDim.y;
  const int flat = blockIdx.y * gx + blockIdx.x;
  const int band = G >> 3;
  const int x8 = flat & 7, loc = flat >> 3;
  const int rpb = band / gx;
  const int ny = x8 * rpb + loc % rpb;
  const int nx = loc / rpb;
  const int mBase = ny * 256, nBase = nx * 128;

  int rowj[2], gslotj[2];
#pragma unroll
  for (int j = 0; j < 2; ++j) {
    const int u = (wid * 2 + j) * 64 + l;
    rowj[j] = u >> 3;
    gslotj[j] = (u & 7) ^ (rowj[j] & 7);
  }
  // HT 0/1: A rows ht*128..+128 ; HT 2: B rows 0..127.  2 wave-uniform-dest loads/thread.
  auto issueHT = [&](int kt, int ht, int side) {
    __bf16* base = sm + side * 24576 + (ht == 2 ? 16384 : ht * 8192);
#pragma unroll
    for (int j = 0; j < 2; ++j) {
      const __bf16* src = (ht < 2)
        ? A + (size_t)(mBase + ht * 128 + rowj[j]) * K + kt * 64 + gslotj[j] * 8
        : BT + (size_t)(nBase + rowj[j]) * K + kt * 64 + gslotj[j] * 8;
      gload_lds16(src, base + (wid * 2 + j) * 512);
    }
  };

  const int nkt = K >> 6;
  issueHT(0, 0, 0); issueHT(0, 1, 0); issueHT(0, 2, 0);
  issueHT(1, 0, 1); issueHT(1, 1, 1); issueHT(1, 2, 1);

  f32x4 acc[4][4] = {};
#pragma unroll 1
  for (int j = 0; j < nkt; ++j) {
    asm volatile("s_waitcnt vmcnt(6)" ::: "memory");  // kt j retired; kt j+1's 6 stay in flight
    __builtin_amdgcn_s_barrier();                     // raw: no implicit vmcnt(0) drain
    __builtin_amdgcn_sched_barrier(0);
    const int side = j % 3;
    const int sn = (j + 2) % 3;
    const int ktn = (j + 2 < nkt) ? j + 2 : nkt - 1;  // clamped addr; dead side, never read
    const __bf16* Ab = sm + side * 24576;
    const __bf16* Bb = Ab + 16384;
    issueHT(ktn, 0, sn);
    bf16x8 af[4][2];
#pragma unroll
    for (int mi = 0; mi < 4; ++mi)
#pragma unroll
      for (int kk = 0; kk < 2; ++kk) {
        const int row = wm * 64 + mi * 16 + lcol;
        af[mi][kk] = *(const bf16x8*)&Ab[row * 64 + (((kk * 4 + lk) ^ (row & 7)) * 8)];
      }
    issueHT(ktn, 1, sn);
    bf16x8 bfv[4][2];
#pragma unroll
    for (int nj = 0; nj < 4; ++nj)
#pragma unroll
      for (int kk = 0; kk < 2; ++kk) {
        const int row = wn * 64 + nj * 16 + lcol;
        bfv[nj][kk] = *(const bf16x8*)&Bb[row * 64 + (((kk * 4 + lk) ^ (row & 7)) * 8)];
      }
    issueHT(ktn, 2, sn);
    __builtin_amdgcn_s_setprio(1);
#pragma unroll
    for (int mi = 0; mi < 4; ++mi)
#pragma unroll
      for (int nj = 0; nj < 4; ++nj) {
        acc[mi][nj] = __builtin_amdgcn_mfma_f32_16x16x32_bf16(af[mi][0], bfv[nj][0], acc[mi][nj], 0, 0, 0);
        acc[mi][nj] = __builtin_amdgcn_mfma_f32_16x16x32_bf16(af[mi][1], bfv[nj][1], acc[mi][nj], 0, 0, 0);
      }
    __builtin_amdgcn_s_setprio(0);
  }
#pragma unroll
  for (int mi = 0; mi < 4; ++mi)
#pragma unroll
    for (int nj = 0; nj < 4; ++nj) {
      const int col = nBase + wn * 64 + nj * 16 + lcol;
      const int row0 = mBase + wm * 64 + mi * 16 + lk * 4;
#pragma unroll
      for (int jj = 0; jj < 4; ++jj) {
        float v = acc[mi][nj][jj];
        if constexpr (MODE == 1) v = gelu_exact(v + bias[col]);
        Cb[(size_t)(row0 + jj) * N + col] = (__bf16)v;
      }
    }
}

// ---------------- MFMA rel-pos attention v8: Z via ones-MFMA ----------------
__global__ __launch_bounds__(256)
void attn8(const __bf16* __restrict__ qk, const __bf16* __restrict__ vT,
           const __bf16* __restrict__ kpos, const float* __restrict__ rwbias,
           const float* __restrict__ rrbias, __bf16* __restrict__ av) {
  constexpr float ALPHA = 0.125f * 1.44269504088896f;
  constexpr int PB = 132;
  __shared__ __align__(16) char smem[74240];
  __bf16* sP  = (__bf16*)(smem + 49152);
  __bf16* sbd = (__bf16*)(smem + 57344);

  const int flat = blockIdx.x;
  const int xcd = flat & 7, rr_ = flat >> 3;
  const int bn = xcd * 8 + (rr_ >> 4);
  const int it = rr_ & 15;
  const int b = bn >> 4, n = bn & 15;
  const int i0 = it * 64;
  const int tid = threadIdx.x;
  const int l = tid & 63;
  const int lcol = l & 15, lk = l >> 4;
  const int strip = (tid >> 6) * 16;
  const int wbase = tid & 192;
  const int nh64 = n * 64;
  const int q = strip + lcol;

  const int rB = tid >> 3;
  const int cs8 = ((tid & 7) ^ (rB & 7)) * 8;

  bf16x8 onesf;
#pragma unroll
  for (int u = 0; u < 8; ++u) onesf[u] = (__bf16)1.0f;

  bf16x8 qac[2], qlo[2], qhi[2];
  {
    const __bf16* qrow = qk + ((size_t)(b * 1024 + i0 + q)) * 2048 + nh64;
    int gH = i0 + q + 1; gH = gH < 1024 ? gH : 1023;
    const __bf16* qrowH = qk + ((size_t)(b * 1024 + gH)) * 2048 + nh64;
#pragma unroll
    for (int kk = 0; kk < 2; ++kk) {
      bf16x8 qv = *(const bf16x8*)(qrow + kk * 32 + lk * 8);
      bf16x8 qh = *(const bf16x8*)(qrowH + kk * 32 + lk * 8);
      const int dbase = nh64 + kk * 32 + lk * 8;
#pragma unroll
      for (int u = 0; u < 8; ++u) {
        const float rb = rrbias[dbase + u];
        qac[kk][u] = (__bf16)(((float)qv[u] + rwbias[dbase + u]) * ALPHA);
        qlo[kk][u] = (__bf16)(((float)qv[u] + rb) * ALPHA);
        qhi[kk][u] = (__bf16)(((float)qh[u] + rb) * ALPHA);
      }
    }
  }

#pragma unroll
  for (int kq = 0; kq < 2; ++kq) {
    const int r = kq * 32 + rB;
    const int dst = (kq * 256 + wbase) * 8;
    gload_lds16(kpos + ((size_t)((960 - i0 + r) * 4 + b)) * 1024 + nh64 + cs8,
                (__bf16*)(smem + 40960) + dst);
    gload_lds16(qk + ((size_t)(b * 1024 + r)) * 2048 + 1024 + nh64 + cs8,
                (__bf16*)(smem) + dst);
    const int rrel = r - i0;
    const int idx = (rrel <= 0) ? (1024 + rrel) : (rrel - 1);
    gload_lds16(kpos + ((size_t)(idx * 4 + b)) * 1024 + nh64 + cs8,
                (__bf16*)(smem + 16384) + dst);
    gload_lds16(vT + ((size_t)(nh64 + r)) * 4096 + b * 1024 + cs8,
                (__bf16*)(smem + 32768) + dst);
  }
  __syncthreads();
  {
    __bf16* kpl = (__bf16*)(smem + 40960);
    const int colb0 = (-i0 - 64) & 127;
#pragma unroll
    for (int fb = 0; fb < 4; ++fb) {
      const int row = fb * 16 + lcol;
      f32x4 g = {};
#pragma unroll
      for (int kk = 0; kk < 2; ++kk) {
        bf16x8 a = *(const bf16x8*)&kpl[row * 64 + (((kk * 4 + lk) ^ (lcol & 7)) * 8)];
        g = __builtin_amdgcn_mfma_f32_16x16x32_bf16(a, qlo[kk], g, 0, 0, 0);
      }
      bf16x4 gw = {(__bf16)g[0], (__bf16)g[1], (__bf16)g[2], (__bf16)g[3]};
      *(bf16x4*)&sbd[q * PB + ((colb0 + fb * 16 + lk * 4) & 127)] = gw;
    }
  }
  __syncthreads();

  f32x4 oacc[4] = {};
  f32x4 zq = {};
  size_t kS = (size_t)(b * 1024 + 64 + rB) * 2048 + 1024 + nh64 + cs8;
  size_t vS = (size_t)(nh64 + rB) * 4096 + b * 1024 + 64 + cs8;

#pragma unroll 1
  for (int jt = 0; jt < 16; ++jt) {
    const int cur = jt & 1, nxt = cur ^ 1;
    const int d0 = jt * 64 - i0;
    __bf16* sK   = (__bf16*)(smem + cur * 8192);
    __bf16* sKn  = (__bf16*)(smem + nxt * 8192);
    __bf16* sKP  = (__bf16*)(smem + 16384 + cur * 8192);
    __bf16* sKPn = (__bf16*)(smem + 16384 + nxt * 8192);
    __bf16* sVT  = (__bf16*)(smem + 32768 + cur * 8192);
    __bf16* sVTn = (__bf16*)(smem + 32768 + nxt * 8192);
#pragma unroll
    for (int kq = 0; kq < 2; ++kq) {
      const int dst = (kq * 256 + wbase) * 8;
      gload_lds16(qk + kS + kq * 65536, sKn + dst);
      gload_lds16(vT + vS + kq * 131072, sVTn + dst);
      const int rreln = d0 + 64 + kq * 32 + rB;
      const int idx = (rreln <= 0) ? (1024 + rreln) : (rreln - 1);
      gload_lds16(kpos + ((size_t)(idx * 4 + b)) * 1024 + nh64 + cs8, sKPn + dst);
    }
    kS += 131072; vS += 64;
    {
      const bf16x8 qg0 = (d0 >= 0) ? qhi[0] : qlo[0];
      const bf16x8 qg1 = (d0 >= 0) ? qhi[1] : qlo[1];
#pragma unroll
      for (int fb = 0; fb < 4; ++fb) {
        const int row = fb * 16 + lcol;
        f32x4 g = {};
        g = __builtin_amdgcn_mfma_f32_16x16x32_bf16(
            *(const bf16x8*)&sKP[row * 64 + ((lk ^ (lcol & 7)) * 8)], qg0, g, 0, 0, 0);
        g = __builtin_amdgcn_mfma_f32_16x16x32_bf16(
            *(const bf16x8*)&sKP[row * 64 + (((4 + lk) ^ (lcol & 7)) * 8)], qg1, g, 0, 0, 0);
        bf16x4 gw = {(__bf16)g[0], (__bf16)g[1], (__bf16)g[2], (__bf16)g[3]};
        *(bf16x4*)&sbd[q * PB + ((d0 + fb * 16 + lk * 4) & 127)] = gw;
      }
      if (d0 == 0) {
        const int cl = tid >> 2, part = tid & 3;
        const __bf16* qs = qk + ((size_t)(b * 1024 + i0 + cl)) * 2048 + nh64 + part * 16;
        bf16x8 a0 = *(const bf16x8*)qs;
        bf16x8 a1 = *(const bf16x8*)(qs + 8);
        bf16x8 k0 = *(const bf16x8*)&sKP[(2 * part) * 8];
        bf16x8 k1 = *(const bf16x8*)&sKP[(2 * part + 1) * 8];
        float s64 = 0.f;
#pragma unroll
        for (int u = 0; u < 8; ++u)
          s64 += ((float)a0[u] + rrbias[nh64 + part * 16 + u]) * (float)k0[u]
               + ((float)a1[u] + rrbias[nh64 + part * 16 + 8 + u]) * (float)k1[u];
        s64 += __shfl_xor(s64, 1, 64);
        s64 += __shfl_xor(s64, 2, 64);
        if (part == 0) sbd[cl * PB] = (__bf16)(s64 * ALPHA);
      }
    }
    f32x4 sc[4];
#pragma unroll
    for (int fk = 0; fk < 4; ++fk) {
      const int row = fk * 16 + lcol;
      f32x4 a = {};
#pragma unroll
      for (int kk = 0; kk < 2; ++kk) {
        bf16x8 kf = *(const bf16x8*)&sK[row * 64 + (((kk * 4 + lk) ^ (lcol & 7)) * 8)];
        a = __builtin_amdgcn_mfma_f32_16x16x32_bf16(kf, qac[kk], a, 0, 0, 0);
      }
      sc[fk] = a;
    }
    {
      const int rowb = q * PB;
      const int sb = d0 - q;
#pragma unroll
      for (int fk = 0; fk < 4; ++fk) {
        const int cb = sb + fk * 16 + lk * 4;
        float e0 = exp2f(sc[fk][0] + (float)sbd[rowb + ((cb) & 127)]);
        float e1 = exp2f(sc[fk][1] + (float)sbd[rowb + ((cb + 1) & 127)]);
        float e2 = exp2f(sc[fk][2] + (float)sbd[rowb + ((cb + 2) & 127)]);
        float e3 = exp2f(sc[fk][3] + (float)sbd[rowb + ((cb + 3) & 127)]);
        bf16x4 pw = {(__bf16)e0, (__bf16)e1, (__bf16)e2, (__bf16)e3};
        *(bf16x4*)&sP[q * 64 + (((fk * 2 + (lk >> 1)) ^ (q & 7)) * 8) + (lk & 1) * 4] = pw;
      }
    }
#pragma unroll
    for (int kk = 0; kk < 2; ++kk) {
      bf16x8 pa = *(const bf16x8*)&sP[q * 64 + (((kk * 4 + lk) ^ (q & 7)) * 8)];
      zq = __builtin_amdgcn_mfma_f32_16x16x32_bf16(pa, onesf, zq, 0, 0, 0);
#pragma unroll
      for (int fd = 0; fd < 4; ++fd) {
        const int vrow = fd * 16 + lcol;
        bf16x8 bv = *(const bf16x8*)&sVT[vrow * 64 + (((kk * 4 + lk) ^ (lcol & 7)) * 8)];
        oacc[fd] = __builtin_amdgcn_mfma_f32_16x16x32_bf16(pa, bv, oacc[fd], 0, 0, 0);
      }
    }
    __syncthreads();
  }
#pragma unroll
  for (int jj = 0; jj < 4; ++jj) {
    const float rz = 1.f / zq[jj];
    const int ig = i0 + strip + lk * 4 + jj;
    __bf16* dst = av + ((size_t)(ig * 4 + b)) * 1024 + nh64;
#pragma unroll
    for (int fd = 0; fd < 4; ++fd)
      dst[fd * 16 + lcol] = (__bf16)(oacc[fd][jj] * rz);
  }
}

// ---------------- fused residual + LayerNorm (two bf16 partial addends) ----------------
__global__ __launch_bounds__(256)
void ln_fuse(const float* __restrict__ A, const __bf16* __restrict__ P0,
             const __bf16* __restrict__ P1, const float* __restrict__ cb,
             const float* __restrict__ g, const float* __restrict__ be,
             float* __restrict__ oF, __bf16* __restrict__ oB) {
  const int row = blockIdx.x, t = threadIdx.x;
  const size_t base = (size_t)row * 1024 + t * 4;
  const float4 a = *(const float4*)(A + base);
  const bf16x4 p0 = *(const bf16x4*)(P0 + base);
  const bf16x4 p1 = *(const bf16x4*)(P1 + base);
  float x0 = a.x + (float)p0[0] + (float)p1[0];
  float x1 = a.y + (float)p0[1] + (float)p1[1];
  float x2 = a.z + (float)p0[2] + (float)p1[2];
  float x3 = a.w + (float)p0[3] + (float)p1[3];
  if (cb) {
    const float4 c = *(const float4*)(cb + t * 4);
    x0 += c.x; x1 += c.y; x2 += c.z; x3 += c.w;
  }
  float s = x0 + x1 + x2 + x3;
  float qq = x0 * x0 + x1 * x1 + x2 * x2 + x3 * x3;
#pragma unroll
  for (int o = 1; o < 64; o <<= 1) { s += __shfl_xor(s, o, 64); qq += __shfl_xor(qq, o, 64); }
  __shared__ float ss[4], qs[4];
  if ((t & 63) == 0) { ss[t >> 6] = s; qs[t >> 6] = qq; }
  __syncthreads();
  s = ss[0] + ss[1] + ss[2] + ss[3];
  qq = qs[0] + qs[1] + qs[2] + qs[3];
  const float mean = s * (1.f / 1024.f);
  const float var = qq * (1.f / 1024.f) - mean * mean;
  const float rstd = rsqrtf(var + 1e-5f);
  const float4 gv = *(const float4*)(g + t * 4);
  const float4 bev = *(const float4*)(be + t * 4);
  const float y0 = (x0 - mean) * rstd * gv.x + bev.x;
  const float y1 = (x1 - mean) * rstd * gv.y + bev.y;
  const float y2 = (x2 - mean) * rstd * gv.z + bev.z;
  const float y3 = (x3 - mean) * rstd * gv.w + bev.w;
  if (oF) {
    float4 r = {y0, y1, y2, y3};
    *(float4*)(oF + base) = r;
  }
  if (oB) {
    bf16x4 o4 = {(__bf16)y0, (__bf16)y1, (__bf16)y2, (__bf16)y3};
    *(bf16x4*)(oB + base) = o4;
  }
}

extern "C" void kernel_launch(void* const* d_in, const int* in_sizes, int n_in,
                              void* d_out, int out_size, void* d_ws, size_t ws_size,
                              hipStream_t stream) {
  const float* src    = (const float*)d_in[0];
  const float* pos    = (const float*)d_in[1];
  const float* qw     = (const float*)d_in[3];
  const float* kw     = (const float*)d_in[4];
  const float* vw     = (const float*)d_in[5];
  const float* rw     = (const float*)d_in[6];
  const float* ow     = (const float*)d_in[7];
  const float* rwbias = (const float*)d_in[8];
  const float* rrbias = (const float*)d_in[9];
  const float* w1     = (const float*)d_in[10];
  const float* b1     = (const float*)d_in[11];
  const float* w2     = (const float*)d_in[12];
  const float* b2     = (const float*)d_in[13];
  const float* g1     = (const float*)d_in[14];
  const float* be1    = (const float*)d_in[15];
  const float* g2     = (const float*)d_in[16];
  const float* be2    = (const float*)d_in[17];
  float* out = (float*)d_out;

  char* p = (char*)d_ws;
  auto alloc = [&](size_t bytes) { char* r = p; p += (bytes + 255) & ~(size_t)255; return r; };
  __bf16* qkB   = (__bf16*)alloc(4096ull * 2048 * 2);   // dead after attn
  __bf16* vTB   = (__bf16*)alloc(1024ull * 4096 * 2);   // dead after attn
  __bf16* kposB = (__bf16*)alloc(4100ull * 1024 * 2);   // dead after attn
  __bf16* avB   = (__bf16*)alloc(4096ull * 1024 * 2);   // dead after attn-out
  __bf16* srcB2 = (__bf16*)alloc(4096ull * 1024 * 2);   // dead after projections
  __bf16* posB  = (__bf16*)alloc(4100ull * 1024 * 2);   // dead after proj2
  float*  xF    = (float*)alloc(4096ull * 1024 * 4);
  __bf16* w2B   = (__bf16*)alloc(4096ull * 1024 * 2);
  __bf16* qkvT  = (__bf16*)alloc(3072ull * 1024 * 2);
  __bf16* rwT   = (__bf16*)alloc(1024ull * 1024 * 2);
  __bf16* owB   = (__bf16*)alloc(1024ull * 1024 * 2);
  __bf16* w1B   = (__bf16*)alloc(4096ull * 1024 * 2);   // dead after FFN1
  __bf16* xB    = (__bf16*)alloc(4096ull * 1024 * 2);   // dead after FFN1
  // aliases (disjoint lifetimes):
  __bf16* gB   = qkB;            // gelu 32MB over qkB+vTB+kposB
  __bf16* aoP0 = srcB2;          // attn-out bf16 partial0
  __bf16* aoP1 = posB;           // attn-out bf16 partial1
  __bf16* ffP0 = avB;            // ffn2 bf16 partial0
  __bf16* ffP1 = w1B;            // ffn2 bf16 partial1

  prep_all<<<11521, 256, 0, stream>>>(src, srcB2, pos, posB, ow, owB, w1, w1B,
                                      w2, w2B, qw, kw, vw, rw, qkvT, rwT);
  gemm256<2><<<dim3(16, 16), 512, 0, stream>>>(srcB2, qkvT, qkB, nullptr, 4096, 2048, 1024);
  proj2_kernel<<<1040, 256, 0, stream>>>(qkvT + 2048 * 1024, srcB2, posB, rwT, vTB, kposB);
  attn8<<<dim3(1024), 256, 0, stream>>>(qkB, vTB, kposB, rwbias, rrbias, avB);
  gemm_bt<128, 64, 2><<<dim3(16, 32, 2), 256, 0, stream>>>(avB, owB, nullptr, aoP0, aoP1, nullptr, 4096, 1024, 1024, 512);
  ln_fuse<<<4096, 256, 0, stream>>>(src, aoP0, aoP1, nullptr, g1, be1, xF, xB);
  gemm256<1><<<dim3(32, 16), 512, 0, stream>>>(xB, w1B, gB, b1, 4096, 4096, 1024);
  gemm_bt<128, 64, 2><<<dim3(16, 32, 2), 256, 0, stream>>>(gB, w2B, nullptr, ffP0, ffP1, nullptr, 4096, 1024, 4096, 2048);
  ln_fuse<<<4096, 256, 0, stream>>>(xF, ffP0, ffP1, b2, g2, be2, out, nullptr);
  (void)in_sizes; (void)n_in; (void)out_size; (void)ws_size;
}